// Round 2
// baseline (1528.329 us; speedup 1.0000x reference)
//
#include <hip/hip_runtime.h>
#include <math.h>

#define THRESH 0.1f
#define NSLOPE 0.2f

// =====================================================================
// Generic fp32 GEMM: C[M,N] = A[M,K] @ W[K,N] (+bias) (+=C) (relu)
// BM=64, BN=64, BK=32, 256 threads, 4x4 micro-tile. M % 64 == 0 assumed.
// =====================================================================
template<int BIAS, int ACCUM, int RELU>
__global__ __launch_bounds__(256)
void gemm_k(const float* __restrict__ A, const float* __restrict__ W,
            const float* __restrict__ bias, float* __restrict__ C,
            int M, int K, int N) {
  __shared__ float At[32][68];   // A-tile transposed [k][m]
  __shared__ float Wl[32][68];   // W-tile [k][n]
  const int t  = threadIdx.x;
  const int tx = t & 15, ty = t >> 4;
  const int i0 = blockIdx.x * 64, n0 = blockIdx.y * 64;
  float acc[4][4] = {};
  for (int k0 = 0; k0 < K; k0 += 32) {
#pragma unroll
    for (int l = 0; l < 8; ++l) {
      int idx = t + l * 256; int r = idx >> 5, c = idx & 31;
      At[c][r] = (k0 + c < K) ? A[(size_t)(i0 + r) * K + (k0 + c)] : 0.f;
    }
#pragma unroll
    for (int l = 0; l < 8; ++l) {
      int idx = t + l * 256; int r = idx >> 6, c = idx & 63;
      Wl[r][c] = (k0 + r < K) ? W[(size_t)(k0 + r) * N + (n0 + c)] : 0.f;
    }
    __syncthreads();
#pragma unroll
    for (int k = 0; k < 32; ++k) {
      float4 a4 = *(float4*)&At[k][ty * 4];
      float4 w4 = *(float4*)&Wl[k][tx * 4];
      float av[4] = {a4.x, a4.y, a4.z, a4.w};
      float wv[4] = {w4.x, w4.y, w4.z, w4.w};
#pragma unroll
      for (int rr = 0; rr < 4; ++rr)
#pragma unroll
        for (int cc = 0; cc < 4; ++cc)
          acc[rr][cc] = fmaf(av[rr], wv[cc], acc[rr][cc]);
    }
    __syncthreads();
  }
#pragma unroll
  for (int rr = 0; rr < 4; ++rr) {
    size_t row = (size_t)(i0 + ty * 4 + rr);
    float* cp = &C[row * N + n0 + tx * 4];
    float o0 = acc[rr][0], o1 = acc[rr][1], o2 = acc[rr][2], o3 = acc[rr][3];
    if (BIAS) {
      const float* bp = &bias[n0 + tx * 4];
      o0 += bp[0]; o1 += bp[1]; o2 += bp[2]; o3 += bp[3];
    }
    if (ACCUM) { o0 += cp[0]; o1 += cp[1]; o2 += cp[2]; o3 += cp[3]; }
    if (RELU) {
      o0 = fmaxf(o0, 0.f); o1 = fmaxf(o1, 0.f);
      o2 = fmaxf(o2, 0.f); o3 = fmaxf(o3, 0.f);
    }
    *(float4*)cp = make_float4(o0, o1, o2, o3);
  }
}

// =====================================================================
// wdvec[t] = Wd[t] @ a_d[t], wsvec[t] = Ws[t] @ a_s[t]   (tiny)
// =====================================================================
__global__ void wvec_k(const float* __restrict__ Wd, const float* __restrict__ ad,
                       const float* __restrict__ Ws, const float* __restrict__ as_,
                       float* __restrict__ wdv, float* __restrict__ wsv) {
  int b = blockIdx.x, k = threadIdx.x;           // b 0..5, k 0..127
  const float* Wm = (b < 3) ? Wd + (size_t)b * 16384 : Ws + (size_t)(b - 3) * 16384;
  const float* av = (b < 3) ? ad + b * 128 : as_ + (b - 3) * 128;
  float* o = (b < 3) ? wdv + b * 128 : wsv + (b - 3) * 128;
  float s = 0.f;
  for (int c = 0; c < 128; ++c) s = fmaf(Wm[(size_t)k * 128 + c], av[c], s);
  o[k] = s;
}

// =====================================================================
// Row stats: XN = X / max(||row||,1e-12); al_out[v][i] = row . avec[v]
// One wave per row (128-dim rows). XN may alias X (per-thread reads
// precede writes) -> no __restrict__ on X/XN.
// =====================================================================
__global__ __launch_bounds__(256)
void rownorm_k(const float* X, float* XN,
               const float* __restrict__ avecs, int navec,
               float* __restrict__ al_out, int N) {
  int lane = threadIdx.x & 63, wv = threadIdx.x >> 6;
  int i = blockIdx.x * 4 + wv;
  float x0 = X[(size_t)i * 128 + lane];
  float x1 = X[(size_t)i * 128 + 64 + lane];
  float ss = x0 * x0 + x1 * x1;
#pragma unroll
  for (int o = 1; o < 64; o <<= 1) ss += __shfl_xor(ss, o);
  float inv = 1.f / fmaxf(sqrtf(ss), 1e-12f);
  for (int v = 0; v < navec; ++v) {
    float d = x0 * avecs[v * 128 + lane] + x1 * avecs[v * 128 + 64 + lane];
#pragma unroll
    for (int o = 1; o < 64; o <<= 1) d += __shfl_xor(d, o);
    if (lane == 0) al_out[(size_t)v * N + i] = d;
  }
  XN[(size_t)i * 128 + lane] = x0 * inv;
  XN[(size_t)i * 128 + 64 + lane] = x1 * inv;
}

// =====================================================================
// Fused flash-GAT over the thresholded cosine-sim graph.
// Block = 64 author rows x one 2048-wide j-chunk (uniform work).
// chunk-globals: paper 0..3, term 4..5, conf 6  -> grid 7*64 = 448.
// Writes flash-decoding partials (unnormalized acc, running m, l).
// =====================================================================
struct GatP {
  const float* qn;        // normalized h_author [4096,128]
  const float* kn[3];     // normalized h_src
  const float* vs[3];     // hs = h_src @ Ws
  const float* als[3];    // al_s per source node
  const float* ald;       // [3][4096]
  float* pacc;            // [7][4096][128]
  float* pm;              // [7][4096]
  float* pl;              // [7][4096]
};

__global__ __launch_bounds__(256, 2)
void gat_k(GatP P) {
  const int b = blockIdx.x;
  const int cg = b >> 6;                 // chunk-global 0..6
  const int rb = b & 63;                 // row-block
  const int type = (cg < 4) ? 0 : (cg < 6 ? 1 : 2);
  const int chunk = cg - (type == 0 ? 0 : (type == 1 ? 4 : 6));
  const float* KN   = P.kn[type];
  const float* VS   = P.vs[type];
  const float* alsg = P.als[type];
  const float* ALD  = P.ald + (size_t)type * 4096;
  const int i0  = rb * 64;
  const int cj0 = chunk * 2048;

  __shared__ float Qs[64][132];
  __shared__ float Ks[32][132];
  __shared__ float Wt[64][36];
  __shared__ float AlsS[32];

  const int t = threadIdx.x;
  const int tx = t & 15, tyi = t >> 4;

  // stage Q tile (normalized author rows)
#pragma unroll
  for (int l = 0; l < 8; ++l) {
    int idx = t + l * 256; int r = idx >> 5, c4 = idx & 31;
    *(float4*)&Qs[r][c4 * 4] = *(const float4*)&P.qn[(size_t)(i0 + r) * 128 + c4 * 4];
  }
  float ald_r[4], m[4], lsum[4];
#pragma unroll
  for (int rr = 0; rr < 4; ++rr) {
    ald_r[rr] = ALD[i0 + tyi * 4 + rr];
    m[rr] = -1e30f; lsum[rr] = 0.f;
  }
  float acc[4][8] = {};

  // prefetch first K tile + al_s into registers
  float4 kreg[4]; float alreg = 0.f;
#pragma unroll
  for (int l = 0; l < 4; ++l) {
    int idx = t + l * 256; int r = idx >> 5, c4 = idx & 31;
    kreg[l] = *(const float4*)&KN[(size_t)(cj0 + r) * 128 + c4 * 4];
  }
  if (t < 32) alreg = alsg[cj0 + t];

  for (int jt = 0; jt < 64; ++jt) {
    const int j0 = cj0 + jt * 32;
    // commit staged regs to LDS
#pragma unroll
    for (int l = 0; l < 4; ++l) {
      int idx = t + l * 256; int r = idx >> 5, c4 = idx & 31;
      *(float4*)&Ks[r][c4 * 4] = kreg[l];
    }
    if (t < 32) AlsS[t] = alreg;
    __syncthreads();                                    // (A)
    // prefetch next tile (latency hidden under S + PV)
    if (jt < 63) {
      const int jn = j0 + 32;
#pragma unroll
      for (int l = 0; l < 4; ++l) {
        int idx = t + l * 256; int r = idx >> 5, c4 = idx & 31;
        kreg[l] = *(const float4*)&KN[(size_t)(jn + r) * 128 + c4 * 4];
      }
      if (t < 32) alreg = alsg[jn + t];
    }
    // ---- S = cos-sim tile (4 rows x 2 cols per thread) ----
    float s[4][2] = {};
#pragma unroll 4
    for (int k4 = 0; k4 < 32; ++k4) {
      float4 k0v = *(float4*)&Ks[tx][k4 * 4];
      float4 k1v = *(float4*)&Ks[tx + 16][k4 * 4];
#pragma unroll
      for (int rr = 0; rr < 4; ++rr) {
        float4 q = *(float4*)&Qs[tyi * 4 + rr][k4 * 4];
        s[rr][0] = fmaf(q.x, k0v.x, s[rr][0]); s[rr][0] = fmaf(q.y, k0v.y, s[rr][0]);
        s[rr][0] = fmaf(q.z, k0v.z, s[rr][0]); s[rr][0] = fmaf(q.w, k0v.w, s[rr][0]);
        s[rr][1] = fmaf(q.x, k1v.x, s[rr][1]); s[rr][1] = fmaf(q.y, k1v.y, s[rr][1]);
        s[rr][1] = fmaf(q.z, k1v.z, s[rr][1]); s[rr][1] = fmaf(q.w, k1v.w, s[rr][1]);
      }
    }
    // ---- mask + e + online softmax ----
    float als0 = AlsS[tx], als1 = AlsS[tx + 16];
    float e[4][2], wvl[4][2], rmax[4], rsum[4], scale[4];
#pragma unroll
    for (int rr = 0; rr < 4; ++rr) {
      int gr = i0 + tyi * 4 + rr;
      float z0 = ald_r[rr] + als0; z0 = (z0 >= 0.f) ? z0 : NSLOPE * z0;
      float z1 = ald_r[rr] + als1; z1 = (z1 >= 0.f) ? z1 : NSLOPE * z1;
      bool a0 = (s[rr][0] > THRESH) && (j0 + tx != gr);
      bool a1 = (s[rr][1] > THRESH) && (j0 + tx + 16 != gr);
      e[rr][0] = a0 ? z0 : -1e30f;
      e[rr][1] = a1 ? z1 : -1e30f;
      rmax[rr] = fmaxf(e[rr][0], e[rr][1]);
    }
#pragma unroll
    for (int o = 1; o < 16; o <<= 1)
#pragma unroll
      for (int rr = 0; rr < 4; ++rr)
        rmax[rr] = fmaxf(rmax[rr], __shfl_xor(rmax[rr], o));
#pragma unroll
    for (int rr = 0; rr < 4; ++rr) {
      float mn = fmaxf(m[rr], rmax[rr]);
      scale[rr] = __expf(m[rr] - mn);      // m==mn==-1e30 -> exp(0)=1, acc=0 anyway
      m[rr] = mn;
      wvl[rr][0] = (e[rr][0] > -1e29f) ? __expf(e[rr][0] - mn) : 0.f;
      wvl[rr][1] = (e[rr][1] > -1e29f) ? __expf(e[rr][1] - mn) : 0.f;
      rsum[rr] = wvl[rr][0] + wvl[rr][1];
    }
#pragma unroll
    for (int o = 1; o < 16; o <<= 1)
#pragma unroll
      for (int rr = 0; rr < 4; ++rr)
        rsum[rr] += __shfl_xor(rsum[rr], o);
#pragma unroll
    for (int rr = 0; rr < 4; ++rr) {
      lsum[rr] = lsum[rr] * scale[rr] + rsum[rr];
      Wt[tyi * 4 + rr][tx]      = wvl[rr][0];
      Wt[tyi * 4 + rr][tx + 16] = wvl[rr][1];
    }
    __syncthreads();                                    // (B)
    // ---- PV: acc += w @ hs (V streamed from L2) ----
#pragma unroll
    for (int rr = 0; rr < 4; ++rr)
#pragma unroll
      for (int c = 0; c < 8; ++c) acc[rr][c] *= scale[rr];
    const float* vbase = VS + (size_t)j0 * 128 + tx * 8;
#pragma unroll 2
    for (int j4 = 0; j4 < 8; ++j4) {
      float4 w0 = *(float4*)&Wt[tyi * 4 + 0][j4 * 4];
      float4 w1 = *(float4*)&Wt[tyi * 4 + 1][j4 * 4];
      float4 w2 = *(float4*)&Wt[tyi * 4 + 2][j4 * 4];
      float4 w3 = *(float4*)&Wt[tyi * 4 + 3][j4 * 4];
      float w0a[4] = {w0.x, w0.y, w0.z, w0.w};
      float w1a[4] = {w1.x, w1.y, w1.z, w1.w};
      float w2a[4] = {w2.x, w2.y, w2.z, w2.w};
      float w3a[4] = {w3.x, w3.y, w3.z, w3.w};
#pragma unroll
      for (int jj = 0; jj < 4; ++jj) {
        int j = j4 * 4 + jj;
        float4 va = *(const float4*)&vbase[(size_t)j * 128];
        float4 vb = *(const float4*)&vbase[(size_t)j * 128 + 4];
        float wj[4] = {w0a[jj], w1a[jj], w2a[jj], w3a[jj]};
#pragma unroll
        for (int rr = 0; rr < 4; ++rr) {
          acc[rr][0] = fmaf(wj[rr], va.x, acc[rr][0]);
          acc[rr][1] = fmaf(wj[rr], va.y, acc[rr][1]);
          acc[rr][2] = fmaf(wj[rr], va.z, acc[rr][2]);
          acc[rr][3] = fmaf(wj[rr], va.w, acc[rr][3]);
          acc[rr][4] = fmaf(wj[rr], vb.x, acc[rr][4]);
          acc[rr][5] = fmaf(wj[rr], vb.y, acc[rr][5]);
          acc[rr][6] = fmaf(wj[rr], vb.z, acc[rr][6]);
          acc[rr][7] = fmaf(wj[rr], vb.w, acc[rr][7]);
        }
      }
    }
    __syncthreads();                                    // (C)
  }
  // ---- write flash-decoding partials ----
#pragma unroll
  for (int rr = 0; rr < 4; ++rr) {
    size_t row = (size_t)(i0 + tyi * 4 + rr);
    float* pa = P.pacc + (size_t)cg * 524288 + row * 128 + tx * 8;
    *(float4*)pa       = make_float4(acc[rr][0], acc[rr][1], acc[rr][2], acc[rr][3]);
    *(float4*)(pa + 4) = make_float4(acc[rr][4], acc[rr][5], acc[rr][6], acc[rr][7]);
    if (tx == 0) {
      P.pm[(size_t)cg * 4096 + row] = m[rr];
      P.pl[(size_t)cg * 4096 + row] = lsum[rr];
    }
  }
}

// =====================================================================
// Merge flash partials: out = sum(acc_ch * e^{m_ch-M}) / sum(l_ch * e^{m_ch-M}) + b
// Empty rows (den == 0) -> bias only (matches reference's isolated-dst zeroing).
// =====================================================================
__global__ __launch_bounds__(256)
void gatmerge_k(const float* __restrict__ pacc, const float* __restrict__ pm,
                const float* __restrict__ pl, const float* __restrict__ gatb,
                float* __restrict__ out0, float* __restrict__ out1, float* __restrict__ out2) {
  int type = blockIdx.y;
  int nc = (type == 0) ? 4 : (type == 1 ? 2 : 1);
  int cb = (type == 0) ? 0 : (type == 1 ? 4 : 6);
  float* OUT = (type == 0) ? out0 : (type == 1 ? out1 : out2);
  int idx = blockIdx.x * 256 + threadIdx.x;   // < 524288
  int i = idx >> 7, c = idx & 127;
  float M = -1e30f;
  for (int ch = 0; ch < nc; ++ch) M = fmaxf(M, pm[(size_t)(cb + ch) * 4096 + i]);
  float num = 0.f, den = 0.f;
  for (int ch = 0; ch < nc; ++ch) {
    float sc = __expf(pm[(size_t)(cb + ch) * 4096 + i] - M);
    den += pl[(size_t)(cb + ch) * 4096 + i] * sc;
    num += pacc[(size_t)(cb + ch) * 524288 + idx] * sc;
  }
  float bv = gatb[(size_t)type * 128 + c];
  OUT[idx] = (den > 0.f) ? num / den + bv : bv;
}

// =====================================================================
// AttentionInfo reduce: scp[v] += sum sigmoid(satt[v]) * atts[v][c]
// =====================================================================
__global__ __launch_bounds__(256)
void attred_k(const float* __restrict__ satt, const float* __restrict__ atts,
              float* __restrict__ scp) {
  int v = blockIdx.y;
  const float* S = satt + (size_t)v * 262144;
  const float* av = atts + v * 64;
  float local = 0.f;
  for (int idx = blockIdx.x * 256 + threadIdx.x; idx < 262144; idx += 32 * 256) {
    float x = S[idx];
    local += av[idx & 63] / (1.f + __expf(-x));
  }
#pragma unroll
  for (int o = 1; o < 64; o <<= 1) local += __shfl_xor(local, o);
  __shared__ float red[4];
  if ((threadIdx.x & 63) == 0) red[threadIdx.x >> 6] = local;
  __syncthreads();
  if (threadIdx.x == 0) atomicAdd(&scp[v], red[0] + red[1] + red[2] + red[3]);
}

__global__ void alpha_k(const float* __restrict__ scp, float* __restrict__ alp) {
  if (threadIdx.x == 0) {
    float s0 = scp[0] * (1.f / 4096.f), s1 = scp[1] * (1.f / 4096.f);
    float s2 = scp[2] * (1.f / 4096.f), s3 = scp[3] * (1.f / 4096.f);
    float mx = fmaxf(fmaxf(s0, s1), fmaxf(s2, s3));
    float e0 = __expf(s0 - mx), e1 = __expf(s1 - mx);
    float e2 = __expf(s2 - mx), e3 = __expf(s3 - mx);
    float d = e0 + e1 + e2 + e3;
    alp[0] = e0 / d; alp[1] = e1 / d; alp[2] = e2 / d; alp[3] = e3 / d;
  }
}

__global__ __launch_bounds__(256)
void xatt_k(const float* __restrict__ h0, const float* __restrict__ h1,
            const float* __restrict__ h2, const float* __restrict__ xt,
            const float* __restrict__ alp, float* __restrict__ out) {
  int idx = blockIdx.x * 256 + threadIdx.x;   // < 524288
  out[idx] = alp[0] * h0[idx] + alp[1] * h1[idx] + alp[2] * h2[idx] + alp[3] * xt[idx];
}

// =====================================================================
// GraphSAGE pieces
// =====================================================================
__global__ __launch_bounds__(256)
void scatter_deg_k(const int* __restrict__ dst, float* __restrict__ deg, int E) {
  int e = blockIdx.x * 256 + threadIdx.x;
  if (e < E) atomicAdd(&deg[dst[e]], 1.0f);
}

__global__ __launch_bounds__(256)
void scatter_add_k(const float* __restrict__ H, const int* __restrict__ src,
                   const int* __restrict__ dst, float* __restrict__ agg,
                   int E, int F, int fshift) {
  int idx = blockIdx.x * 256 + threadIdx.x;
  int e = idx >> fshift;
  int f = idx & (F - 1);
  if (e < E) atomicAdd(&agg[(size_t)dst[e] * F + f], H[(size_t)src[e] * F + f]);
}

__global__ __launch_bounds__(256)
void aggnorm_k(float* __restrict__ agg, const float* __restrict__ deg) {
  int idx = blockIdx.x * 256 + threadIdx.x;   // over 4096*128
  agg[idx] *= 1.f / fmaxf(deg[idx >> 7], 1.f);
}

__global__ __launch_bounds__(256)
void finaladd_k(float* __restrict__ out, const float* __restrict__ agg2,
                const float* __restrict__ deg) {
  int idx = blockIdx.x * 256 + threadIdx.x;   // over 4096*64
  out[idx] += agg2[idx] / fmaxf(deg[idx >> 6], 1.f);
}

// =====================================================================
// Launch
// =====================================================================
extern "C" void kernel_launch(void* const* d_in, const int* in_sizes, int n_in,
                              void* d_out, int out_size, void* d_ws, size_t ws_size,
                              hipStream_t stream) {
  const float* xma = (const float*)d_in[0];
  const float* xmp = (const float*)d_in[1];
  const float* xmt = (const float*)d_in[2];
  const float* xmc = (const float*)d_in[3];
  const float* xia = (const float*)d_in[4];
  const int*   ei  = (const int*)  d_in[5];
  const float* Wla = (const float*)d_in[6];  const float* bla = (const float*)d_in[7];
  const float* Wlp = (const float*)d_in[8];  const float* blp = (const float*)d_in[9];
  const float* Wlt = (const float*)d_in[10]; const float* blt = (const float*)d_in[11];
  const float* Wlc = (const float*)d_in[12]; const float* blc = (const float*)d_in[13];
  const float* Wtg = (const float*)d_in[14]; const float* btg = (const float*)d_in[15];
  const float* gWs = (const float*)d_in[16];
  const float* gWd = (const float*)d_in[17];
  const float* gas = (const float*)d_in[18];
  const float* gad = (const float*)d_in[19];
  const float* gb  = (const float*)d_in[20];
  const float* Watt = (const float*)d_in[21];
  const float* atts = (const float*)d_in[22];
  const float* W1l = (const float*)d_in[23]; const float* b1 = (const float*)d_in[24];
  const float* W1r = (const float*)d_in[25];
  const float* W2l = (const float*)d_in[26]; const float* b2 = (const float*)d_in[27];
  const float* W2r = (const float*)d_in[28];
  (void)in_sizes; (void)n_in; (void)out_size; (void)ws_size;

  float* ws = (float*)d_ws;
  size_t off = 0;
  auto alloc = [&](size_t n) { float* p = ws + off; off += n; return p; };
  float* h_a  = alloc(4096 * 128);
  float* h_p  = alloc(8192 * 128);
  float* h_t  = alloc(4096 * 128);
  float* h_c  = alloc(2048 * 128);
  float* x_t  = alloc(4096 * 128);
  float* hs_p = alloc(8192 * 128);
  float* hs_t = alloc(4096 * 128);
  float* hs_c = alloc(2048 * 128);
  float* qn   = alloc(4096 * 128);
  float* ald  = alloc(3 * 4096);
  float* als_p = alloc(8192);
  float* als_t = alloc(4096);
  float* als_c = alloc(2048);
  float* wdv  = alloc(3 * 128);
  float* wsv  = alloc(3 * 128);
  float* het0 = alloc(4096 * 128);
  float* het1 = alloc(4096 * 128);
  float* het2 = alloc(4096 * 128);
  // zero-init block (one contiguous memset)
  float* zbase = ws + off;
  float* deg  = alloc(4096);
  float* agg1 = alloc(4096 * 128);
  float* agg2 = alloc(4096 * 64);
  float* scp  = alloc(16);
  float* alp  = alloc(16);
  size_t zcount = (size_t)(4096 + 4096 * 128 + 4096 * 64 + 32);
  // GAT partials; region reused later (disjoint lifetimes)
  float* pacc = alloc((size_t)7 * 4096 * 128);
  float* pm   = alloc(7 * 4096);
  float* pl   = alloc(7 * 4096);
  float* satt = pacc;                       //  4*4096*64  (after gatmerge)
  float* h1   = pacc + 4 * 4096 * 64;       //  4096*256
  float* p2   = h1 + 4096 * 256;            //  4096*64

  hipMemsetAsync(zbase, 0, zcount * sizeof(float), stream);

  dim3 blk(256);
  // ---- dimension transforms ----
  gemm_k<1, 0, 0><<<dim3(64, 2),  blk, 0, stream>>>(xma, Wla, bla, h_a, 4096, 668, 128);
  gemm_k<1, 0, 0><<<dim3(128, 2), blk, 0, stream>>>(xmp, Wlp, blp, h_p, 8192, 1024, 128);
  gemm_k<1, 0, 0><<<dim3(64, 2),  blk, 0, stream>>>(xmt, Wlt, blt, h_t, 4096, 256, 128);
  gemm_k<1, 0, 0><<<dim3(32, 2),  blk, 0, stream>>>(xmc, Wlc, blc, h_c, 2048, 128, 128);
  gemm_k<1, 0, 0><<<dim3(64, 2),  blk, 0, stream>>>(xia, Wtg, btg, x_t, 4096, 334, 128);
  // ---- GAT precompute: hs = h_src @ Ws; attention vectors; norms ----
  gemm_k<0, 0, 0><<<dim3(128, 2), blk, 0, stream>>>(h_p, gWs + 0 * 16384, nullptr, hs_p, 8192, 128, 128);
  gemm_k<0, 0, 0><<<dim3(64, 2),  blk, 0, stream>>>(h_t, gWs + 1 * 16384, nullptr, hs_t, 4096, 128, 128);
  gemm_k<0, 0, 0><<<dim3(32, 2),  blk, 0, stream>>>(h_c, gWs + 2 * 16384, nullptr, hs_c, 2048, 128, 128);
  wvec_k<<<dim3(6), dim3(128), 0, stream>>>(gWd, gad, gWs, gas, wdv, wsv);
  rownorm_k<<<dim3(1024), blk, 0, stream>>>(h_a, qn, wdv, 3, ald, 4096);
  rownorm_k<<<dim3(2048), blk, 0, stream>>>(h_p, h_p, wsv + 0,   1, als_p, 8192);
  rownorm_k<<<dim3(1024), blk, 0, stream>>>(h_t, h_t, wsv + 128, 1, als_t, 4096);
  rownorm_k<<<dim3(512),  blk, 0, stream>>>(h_c, h_c, wsv + 256, 1, als_c, 2048);
  // ---- fused flash-GAT + merge ----
  GatP gp;
  gp.qn = qn;
  gp.kn[0] = h_p;  gp.kn[1] = h_t;  gp.kn[2] = h_c;
  gp.vs[0] = hs_p; gp.vs[1] = hs_t; gp.vs[2] = hs_c;
  gp.als[0] = als_p; gp.als[1] = als_t; gp.als[2] = als_c;
  gp.ald = ald; gp.pacc = pacc; gp.pm = pm; gp.pl = pl;
  gat_k<<<dim3(448), blk, 0, stream>>>(gp);
  gatmerge_k<<<dim3(2048, 3), blk, 0, stream>>>(pacc, pm, pl, gb, het0, het1, het2);
  // ---- AttentionInfo ----
  gemm_k<0, 0, 0><<<dim3(64, 1), blk, 0, stream>>>(het0, Watt, nullptr, satt + 0 * 262144, 4096, 128, 64);
  gemm_k<0, 0, 0><<<dim3(64, 1), blk, 0, stream>>>(het1, Watt, nullptr, satt + 1 * 262144, 4096, 128, 64);
  gemm_k<0, 0, 0><<<dim3(64, 1), blk, 0, stream>>>(het2, Watt, nullptr, satt + 2 * 262144, 4096, 128, 64);
  gemm_k<0, 0, 0><<<dim3(64, 1), blk, 0, stream>>>(x_t,  Watt, nullptr, satt + 3 * 262144, 4096, 128, 64);
  attred_k<<<dim3(32, 4), blk, 0, stream>>>(satt, atts, scp);
  alpha_k<<<dim3(1), dim3(64), 0, stream>>>(scp, alp);
  xatt_k<<<dim3(2048), blk, 0, stream>>>(het0, het1, het2, x_t, alp, (float*)d_out + 262144);
  // ---- GraphSAGE (layer2 uses matmul-then-aggregate: 64-wide atomics) ----
  const int E = 131072;
  const int* esrc = ei;
  const int* edst = ei + E;
  scatter_deg_k<<<dim3(512), blk, 0, stream>>>(edst, deg, E);
  scatter_add_k<<<dim3(65536), blk, 0, stream>>>(h_a, esrc, edst, agg1, E, 128, 7);
  aggnorm_k<<<dim3(2048), blk, 0, stream>>>(agg1, deg);
  gemm_k<1, 0, 0><<<dim3(64, 4), blk, 0, stream>>>(agg1, W1l, b1, h1, 4096, 128, 256);
  gemm_k<0, 1, 1><<<dim3(64, 4), blk, 0, stream>>>(h_a, W1r, nullptr, h1, 4096, 128, 256);
  gemm_k<0, 0, 0><<<dim3(64, 1), blk, 0, stream>>>(h1, W2l, nullptr, p2, 4096, 256, 64);
  scatter_add_k<<<dim3(32768), blk, 0, stream>>>(p2, esrc, edst, agg2, E, 64, 6);
  gemm_k<1, 0, 0><<<dim3(64, 1), blk, 0, stream>>>(h1, W2r, b2, (float*)d_out, 4096, 256, 64);
  finaladd_k<<<dim3(1024), blk, 0, stream>>>((float*)d_out, agg2, deg);
}

// Round 4
// 1318.713 us; speedup vs baseline: 1.1590x; 1.1590x over previous
//
#include <hip/hip_runtime.h>
#include <math.h>

#define THRESH 0.1f
#define NSLOPE 0.2f

typedef __attribute__((ext_vector_type(8))) short short8;
typedef __attribute__((ext_vector_type(4))) float f32x4;
typedef unsigned short u16;
typedef unsigned int u32;

#define MFMA16(a, b, c) __builtin_amdgcn_mfma_f32_16x16x32_bf16(a, b, c, 0, 0, 0)

__device__ inline u16 f2bf(float x) {
  u32 u = __float_as_uint(x);
  u += 0x7FFF + ((u >> 16) & 1);
  return (u16)(u >> 16);
}
__device__ inline float bf2f(u16 h) { return __uint_as_float((u32)h << 16); }

// =====================================================================
// Generic fp32 GEMM: C[M,N] = A[M,K] @ W[K,N] (+bias) (+=C) (relu)
// (verified correct in round 0)
// =====================================================================
template<int BIAS, int ACCUM, int RELU>
__global__ __launch_bounds__(256)
void gemm_k(const float* __restrict__ A, const float* __restrict__ W,
            const float* __restrict__ bias, float* __restrict__ C,
            int M, int K, int N) {
  __shared__ float At[32][68];
  __shared__ float Wl[32][68];
  const int t  = threadIdx.x;
  const int tx = t & 15, ty = t >> 4;
  const int i0 = blockIdx.x * 64, n0 = blockIdx.y * 64;
  float acc[4][4] = {};
  for (int k0 = 0; k0 < K; k0 += 32) {
#pragma unroll
    for (int l = 0; l < 8; ++l) {
      int idx = t + l * 256; int r = idx >> 5, c = idx & 31;
      At[c][r] = (k0 + c < K) ? A[(size_t)(i0 + r) * K + (k0 + c)] : 0.f;
    }
#pragma unroll
    for (int l = 0; l < 8; ++l) {
      int idx = t + l * 256; int r = idx >> 6, c = idx & 63;
      Wl[r][c] = (k0 + r < K) ? W[(size_t)(k0 + r) * N + (n0 + c)] : 0.f;
    }
    __syncthreads();
#pragma unroll
    for (int k = 0; k < 32; ++k) {
      float4 a4 = *(float4*)&At[k][ty * 4];
      float4 w4 = *(float4*)&Wl[k][tx * 4];
      float av[4] = {a4.x, a4.y, a4.z, a4.w};
      float wv[4] = {w4.x, w4.y, w4.z, w4.w};
#pragma unroll
      for (int rr = 0; rr < 4; ++rr)
#pragma unroll
        for (int cc = 0; cc < 4; ++cc)
          acc[rr][cc] = fmaf(av[rr], wv[cc], acc[rr][cc]);
    }
    __syncthreads();
  }
#pragma unroll
  for (int rr = 0; rr < 4; ++rr) {
    size_t row = (size_t)(i0 + ty * 4 + rr);
    float* cp = &C[row * N + n0 + tx * 4];
    float o0 = acc[rr][0], o1 = acc[rr][1], o2 = acc[rr][2], o3 = acc[rr][3];
    if (BIAS) {
      const float* bp = &bias[n0 + tx * 4];
      o0 += bp[0]; o1 += bp[1]; o2 += bp[2]; o3 += bp[3];
    }
    if (ACCUM) { o0 += cp[0]; o1 += cp[1]; o2 += cp[2]; o3 += cp[3]; }
    if (RELU) {
      o0 = fmaxf(o0, 0.f); o1 = fmaxf(o1, 0.f);
      o2 = fmaxf(o2, 0.f); o3 = fmaxf(o3, 0.f);
    }
    *(float4*)cp = make_float4(o0, o1, o2, o3);
  }
}

// =====================================================================
// wdvec[t] = Wd[t] @ a_d[t], wsvec[t] = Ws[t] @ a_s[t]
// =====================================================================
__global__ void wvec_k(const float* __restrict__ Wd, const float* __restrict__ ad,
                       const float* __restrict__ Ws, const float* __restrict__ as_,
                       float* __restrict__ wdv, float* __restrict__ wsv) {
  int b = blockIdx.x, k = threadIdx.x;
  const float* Wm = (b < 3) ? Wd + (size_t)b * 16384 : Ws + (size_t)(b - 3) * 16384;
  const float* av = (b < 3) ? ad + b * 128 : as_ + (b - 3) * 128;
  float* o = (b < 3) ? wdv + b * 128 : wsv + (b - 3) * 128;
  float s = 0.f;
  for (int c = 0; c < 128; ++c) s = fmaf(Wm[(size_t)k * 128 + c], av[c], s);
  o[k] = s;
}

// =====================================================================
// Row stats: normalized row -> bf16 hi/lo split; al_out[v][i] = row . avec[v]
// (al computed on UNnormalized row, matching reference)
// =====================================================================
__global__ __launch_bounds__(256)
void rownorm2_k(const float* __restrict__ X, u16* __restrict__ XH, u16* __restrict__ XL,
                const float* __restrict__ avecs, int navec,
                float* __restrict__ al_out, int N) {
  int lane = threadIdx.x & 63, wv = threadIdx.x >> 6;
  int i = blockIdx.x * 4 + wv;
  float x0 = X[(size_t)i * 128 + lane];
  float x1 = X[(size_t)i * 128 + 64 + lane];
  float ss = x0 * x0 + x1 * x1;
#pragma unroll
  for (int o = 1; o < 64; o <<= 1) ss += __shfl_xor(ss, o);
  float inv = 1.f / fmaxf(sqrtf(ss), 1e-12f);
  for (int v = 0; v < navec; ++v) {
    float d = x0 * avecs[v * 128 + lane] + x1 * avecs[v * 128 + 64 + lane];
#pragma unroll
    for (int o = 1; o < 64; o <<= 1) d += __shfl_xor(d, o);
    if (lane == 0) al_out[(size_t)v * N + i] = d;
  }
  float n0 = x0 * inv, n1 = x1 * inv;
  u16 h0 = f2bf(n0), h1 = f2bf(n1);
  XH[(size_t)i * 128 + lane]      = h0;
  XH[(size_t)i * 128 + 64 + lane] = h1;
  XL[(size_t)i * 128 + lane]      = f2bf(n0 - bf2f(h0));
  XL[(size_t)i * 128 + 64 + lane] = f2bf(n1 - bf2f(h1));
}

// =====================================================================
// Transpose-convert: hs fp32 [N][128] -> Vt_hi/Vt_lo bf16 [128][N]
// grid (N/64, 2); 64x64 tile through LDS.
// =====================================================================
__global__ __launch_bounds__(256)
void tconv_k(const float* __restrict__ src, u16* __restrict__ dh, u16* __restrict__ dl, int N) {
  __shared__ float tl[64][65];
  const int t = threadIdx.x;
  const int sb = blockIdx.x, fb = blockIdx.y;
#pragma unroll
  for (int l = 0; l < 4; ++l) {
    int i = t + l * 256; int r = i >> 4; int c4 = i & 15;
    *(float4*)&tl[r][c4 * 4] = *(const float4*)&src[(size_t)(sb * 64 + r) * 128 + fb * 64 + c4 * 4];
  }
  __syncthreads();
#pragma unroll
  for (int l = 0; l < 2; ++l) {
    int g = t + l * 256; int f = g >> 3; int s8 = (g & 7) * 8;
    u32 ph[4], pl[4];
#pragma unroll
    for (int k = 0; k < 4; ++k) {
      float a = tl[s8 + 2 * k][f], b = tl[s8 + 2 * k + 1][f];
      u16 ha = f2bf(a), hb = f2bf(b);
      u16 la = f2bf(a - bf2f(ha)), lb = f2bf(b - bf2f(hb));
      ph[k] = (u32)ha | ((u32)hb << 16);
      pl[k] = (u32)la | ((u32)lb << 16);
    }
    size_t o = (size_t)(fb * 64 + f) * N + sb * 64 + s8;
    *(uint4*)&dh[o] = make_uint4(ph[0], ph[1], ph[2], ph[3]);
    *(uint4*)&dl[o] = make_uint4(pl[0], pl[1], pl[2], pl[3]);
  }
}

// =====================================================================
// MFMA flash-GAT. 7 chunk-globals of 2048 srcs (paper 0..3, term 4..5,
// conf 6) x 64 author-blocks -> 448 blocks, 4 independent waves each
// (16 authors/wave). No __syncthreads (per-wave LDS slices only).
// Split-bf16 (hi/lo), 3 MFMA terms for S and PV (~fp32 accuracy).
// B-fragments load straight from L1/L2.
// =====================================================================
struct GatP {
  const u16 *qh, *ql;          // normalized author [4096][128]
  const u16 *kh[3], *kl[3];    // normalized src [N][128]
  const u16 *vh[3], *vl[3];    // hs transposed [128][N]
  const float *als[3];
  const float *ald;            // [3][4096]
  float *pacc;                 // [7][4096][128]
  float *pm;                   // [7][4096]
  float *pl;                   // [7][4096]
};

__global__ __launch_bounds__(256)
void gat_k(GatP P) {
  __shared__ u16 wh[4][16][40];   // per-wave P (hi), padded stride 40
  __shared__ u16 wl_[4][16][40];  // per-wave P (lo)

  // XCD-contiguous remap: each XCD owns 56 consecutive work-ids
  const int b = ((blockIdx.x & 7) * 56) + (blockIdx.x >> 3);
  const int cg = b >> 6;
  const int rb = b & 63;
  const int type = (cg < 4) ? 0 : (cg < 6 ? 1 : 2);
  const int chunk = cg - (type == 0 ? 0 : (type == 1 ? 4 : 6));
  const int srcN = (type == 0) ? 8192 : (type == 1 ? 4096 : 2048);
  const u16* KH = P.kh[type]; const u16* KL = P.kl[type];
  const u16* VH = P.vh[type]; const u16* VL = P.vl[type];
  const float* alsg = P.als[type];
  const float* ALD = P.ald + (size_t)type * 4096;
  const int i0 = rb * 64;
  const int cj0 = chunk * 2048;

  const int t = threadIdx.x;
  const int wm = t >> 6;        // wave 0..3
  const int ln = t & 63;
  const int lg = ln >> 4;       // k-group 0..3
  const int lc = ln & 15;       // col-in-tile / A-row
  const int arow0 = i0 + wm * 16;

  // A-operand Q fragments (row = lc), held for all 64 jt iterations
  short8 qhf[4], qlf[4];
#pragma unroll
  for (int ks = 0; ks < 4; ++ks) {
    size_t qo = (size_t)(arow0 + lc) * 128 + ks * 32 + lg * 8;
    qhf[ks] = *(const short8*)(P.qh + qo);
    qlf[ks] = *(const short8*)(P.ql + qo);
  }
  float ald_r[4], m[4], lsum[4];
#pragma unroll
  for (int r = 0; r < 4; ++r) {
    ald_r[r] = ALD[arow0 + lg * 4 + r];
    m[r] = -1e30f; lsum[r] = 0.f;
  }
  f32x4 pacc[8];
#pragma unroll
  for (int n = 0; n < 8; ++n) pacc[n] = (f32x4)0.f;

  for (int jt = 0; jt < 64; ++jt) {
    const int j0 = cj0 + jt * 32;
    // ---- K B-frag loads (S operands) ----
    short8 kbh[2][4], kbl[2][4];
#pragma unroll
    for (int tn = 0; tn < 2; ++tn)
#pragma unroll
      for (int ks = 0; ks < 4; ++ks) {
        size_t ko = (size_t)(j0 + tn * 16 + lc) * 128 + ks * 32 + lg * 8;
        kbh[tn][ks] = *(const short8*)(KH + ko);
        kbl[tn][ks] = *(const short8*)(KL + ko);
      }
    float als0 = alsg[j0 + lc], als1 = alsg[j0 + 16 + lc];
    // ---- S = cos-sim tile: 3-term split-bf16 MFMA ----
    f32x4 sacc[2];
    sacc[0] = (f32x4)0.f; sacc[1] = (f32x4)0.f;
#pragma unroll
    for (int ks = 0; ks < 4; ++ks)
#pragma unroll
      for (int tn = 0; tn < 2; ++tn) {
        sacc[tn] = MFMA16(qhf[ks], kbh[tn][ks], sacc[tn]);
        sacc[tn] = MFMA16(qhf[ks], kbl[tn][ks], sacc[tn]);
        sacc[tn] = MFMA16(qlf[ks], kbh[tn][ks], sacc[tn]);
      }
    // ---- V B-frag loads (consumed by PV; latency hides under softmax) ----
    short8 vbh[8], vbl[8];
#pragma unroll
    for (int tn = 0; tn < 8; ++tn) {
      size_t vo = (size_t)(tn * 16 + lc) * srcN + j0 + lg * 8;
      vbh[tn] = *(const short8*)(VH + vo);
      vbl[tn] = *(const short8*)(VL + vo);
    }
    // ---- mask + leaky + online softmax (rows spread over 16-lane groups) ----
    float w0s[4], w1s[4], scl[4];
#pragma unroll
    for (int r = 0; r < 4; ++r) {
      int ag = arow0 + lg * 4 + r;         // global author row (C-layout)
      float z0 = ald_r[r] + als0; z0 = (z0 >= 0.f) ? z0 : NSLOPE * z0;
      float z1 = ald_r[r] + als1; z1 = (z1 >= 0.f) ? z1 : NSLOPE * z1;
      bool a0 = (sacc[0][r] > THRESH) && (j0 + lc != ag);
      bool a1 = (sacc[1][r] > THRESH) && (j0 + 16 + lc != ag);
      float e0 = a0 ? z0 : -1e30f;
      float e1 = a1 ? z1 : -1e30f;
      float rm = fmaxf(e0, e1);
#pragma unroll
      for (int o = 1; o < 16; o <<= 1) rm = fmaxf(rm, __shfl_xor(rm, o));
      float mn = fmaxf(m[r], rm);
      scl[r] = __expf(m[r] - mn);
      m[r] = mn;
      float w0 = (e0 > -1e29f) ? __expf(e0 - mn) : 0.f;
      float w1 = (e1 > -1e29f) ? __expf(e1 - mn) : 0.f;
      float rs = w0 + w1;
#pragma unroll
      for (int o = 1; o < 16; o <<= 1) rs += __shfl_xor(rs, o);
      lsum[r] = lsum[r] * scl[r] + rs;
      w0s[r] = w0; w1s[r] = w1;
    }
    // ---- transpose P into A-operand layout via per-wave LDS slice.
    //      No barrier needed: producer & consumer are the same wave and
    //      same-wave DS ops complete in order (compiler can't disambiguate
    //      the array -> preserves program order). ----
#pragma unroll
    for (int r = 0; r < 4; ++r) {
      u16 h0 = f2bf(w0s[r]);
      u16 h1 = f2bf(w1s[r]);
      wh[wm][lg * 4 + r][lc]      = h0;
      wh[wm][lg * 4 + r][16 + lc] = h1;
      wl_[wm][lg * 4 + r][lc]      = f2bf(w0s[r] - bf2f(h0));
      wl_[wm][lg * 4 + r][16 + lc] = f2bf(w1s[r] - bf2f(h1));
    }
    // ---- rescale running PV accumulator ----
#pragma unroll
    for (int n = 0; n < 8; ++n)
#pragma unroll
      for (int r = 0; r < 4; ++r) pacc[n][r] *= scl[r];
    short8 wfh = *(const short8*)&wh[wm][lc][lg * 8];
    short8 wfl = *(const short8*)&wl_[wm][lc][lg * 8];
    // ---- PV: 3-term split-bf16 MFMA (8 independent chains) ----
#pragma unroll
    for (int n = 0; n < 8; ++n) {
      pacc[n] = MFMA16(wfh, vbh[n], pacc[n]);
      pacc[n] = MFMA16(wfh, vbl[n], pacc[n]);
      pacc[n] = MFMA16(wfl, vbh[n], pacc[n]);
    }
  }
  // ---- write flash-decoding partials ----
#pragma unroll
  for (int n = 0; n < 8; ++n)
#pragma unroll
    for (int r = 0; r < 4; ++r) {
      size_t row = (size_t)(arow0 + lg * 4 + r);
      P.pacc[(size_t)cg * 524288 + row * 128 + n * 16 + lc] = pacc[n][r];
    }
  if (lc == 0) {
#pragma unroll
    for (int r = 0; r < 4; ++r) {
      size_t row = (size_t)(arow0 + lg * 4 + r);
      P.pm[(size_t)cg * 4096 + row] = m[r];
      P.pl[(size_t)cg * 4096 + row] = lsum[r];
    }
  }
}

// =====================================================================
// Merge flash partials (7 chunks: paper 4, term 2, conf 1)
// =====================================================================
__global__ __launch_bounds__(256)
void gatmerge_k(const float* __restrict__ pacc, const float* __restrict__ pm,
                const float* __restrict__ pl, const float* __restrict__ gatb,
                float* __restrict__ out0, float* __restrict__ out1, float* __restrict__ out2) {
  int type = blockIdx.y;
  int nc = (type == 0) ? 4 : (type == 1 ? 2 : 1);
  int cb = (type == 0) ? 0 : (type == 1 ? 4 : 6);
  float* OUT = (type == 0) ? out0 : (type == 1 ? out1 : out2);
  int idx = blockIdx.x * 256 + threadIdx.x;
  int i = idx >> 7, c = idx & 127;
  float M = -1e30f;
  for (int ch = 0; ch < nc; ++ch) M = fmaxf(M, pm[(size_t)(cb + ch) * 4096 + i]);
  float num = 0.f, den = 0.f;
  for (int ch = 0; ch < nc; ++ch) {
    float sc = __expf(pm[(size_t)(cb + ch) * 4096 + i] - M);
    den += pl[(size_t)(cb + ch) * 4096 + i] * sc;
    num += pacc[(size_t)(cb + ch) * 524288 + idx] * sc;
  }
  float bv = gatb[(size_t)type * 128 + c];
  OUT[idx] = (den > 0.f) ? num / den + bv : bv;
}

// =====================================================================
// AttentionInfo + SAGE pieces (verified in round 0)
// =====================================================================
__global__ __launch_bounds__(256)
void attred_k(const float* __restrict__ satt, const float* __restrict__ atts,
              float* __restrict__ scp) {
  int v = blockIdx.y;
  const float* S = satt + (size_t)v * 262144;
  const float* av = atts + v * 64;
  float local = 0.f;
  for (int idx = blockIdx.x * 256 + threadIdx.x; idx < 262144; idx += 32 * 256) {
    float x = S[idx];
    local += av[idx & 63] / (1.f + __expf(-x));
  }
#pragma unroll
  for (int o = 1; o < 64; o <<= 1) local += __shfl_xor(local, o);
  __shared__ float red[4];
  if ((threadIdx.x & 63) == 0) red[threadIdx.x >> 6] = local;
  __syncthreads();
  if (threadIdx.x == 0) atomicAdd(&scp[v], red[0] + red[1] + red[2] + red[3]);
}

__global__ void alpha_k(const float* __restrict__ scp, float* __restrict__ alp) {
  if (threadIdx.x == 0) {
    float s0 = scp[0] * (1.f / 4096.f), s1 = scp[1] * (1.f / 4096.f);
    float s2 = scp[2] * (1.f / 4096.f), s3 = scp[3] * (1.f / 4096.f);
    float mx = fmaxf(fmaxf(s0, s1), fmaxf(s2, s3));
    float e0 = __expf(s0 - mx), e1 = __expf(s1 - mx);
    float e2 = __expf(s2 - mx), e3 = __expf(s3 - mx);
    float d = e0 + e1 + e2 + e3;
    alp[0] = e0 / d; alp[1] = e1 / d; alp[2] = e2 / d; alp[3] = e3 / d;
  }
}

__global__ __launch_bounds__(256)
void xatt_k(const float* __restrict__ h0, const float* __restrict__ h1,
            const float* __restrict__ h2, const float* __restrict__ xt,
            const float* __restrict__ alp, float* __restrict__ out) {
  int idx = blockIdx.x * 256 + threadIdx.x;
  out[idx] = alp[0] * h0[idx] + alp[1] * h1[idx] + alp[2] * h2[idx] + alp[3] * xt[idx];
}

__global__ __launch_bounds__(256)
void scatter_deg_k(const int* __restrict__ dst, float* __restrict__ deg, int E) {
  int e = blockIdx.x * 256 + threadIdx.x;
  if (e < E) atomicAdd(&deg[dst[e]], 1.0f);
}

__global__ __launch_bounds__(256)
void scatter_add_k(const float* __restrict__ H, const int* __restrict__ src,
                   const int* __restrict__ dst, float* __restrict__ agg,
                   int E, int F, int fshift) {
  int idx = blockIdx.x * 256 + threadIdx.x;
  int e = idx >> fshift;
  int f = idx & (F - 1);
  if (e < E) atomicAdd(&agg[(size_t)dst[e] * F + f], H[(size_t)src[e] * F + f]);
}

__global__ __launch_bounds__(256)
void aggnorm_k(float* __restrict__ agg, const float* __restrict__ deg) {
  int idx = blockIdx.x * 256 + threadIdx.x;
  agg[idx] *= 1.f / fmaxf(deg[idx >> 7], 1.f);
}

__global__ __launch_bounds__(256)
void finaladd_k(float* __restrict__ out, const float* __restrict__ agg2,
                const float* __restrict__ deg) {
  int idx = blockIdx.x * 256 + threadIdx.x;
  out[idx] += agg2[idx] / fmaxf(deg[idx >> 6], 1.f);
}

// =====================================================================
// Launch. Workspace 42.3 MB (< 45.4 MB empirical bound from round 0).
// Region P (3,670,016 floats) is triple-used with disjoint lifetimes:
//   early: h_p,h_t,h_c,hs_p,hs_t,hs_c (dead after rownorm2/tconv)
//   mid:   pacc[7][4096][128]         (gat_k .. gatmerge)
//   late:  satt | h1 | p2 | deg,agg1,agg2 (memset after gatmerge)
// =====================================================================
extern "C" void kernel_launch(void* const* d_in, const int* in_sizes, int n_in,
                              void* d_out, int out_size, void* d_ws, size_t ws_size,
                              hipStream_t stream) {
  const float* xma = (const float*)d_in[0];
  const float* xmp = (const float*)d_in[1];
  const float* xmt = (const float*)d_in[2];
  const float* xmc = (const float*)d_in[3];
  const float* xia = (const float*)d_in[4];
  const int*   ei  = (const int*)  d_in[5];
  const float* Wla = (const float*)d_in[6];  const float* bla = (const float*)d_in[7];
  const float* Wlp = (const float*)d_in[8];  const float* blp = (const float*)d_in[9];
  const float* Wlt = (const float*)d_in[10]; const float* blt = (const float*)d_in[11];
  const float* Wlc = (const float*)d_in[12]; const float* blc = (const float*)d_in[13];
  const float* Wtg = (const float*)d_in[14]; const float* btg = (const float*)d_in[15];
  const float* gWs = (const float*)d_in[16];
  const float* gWd = (const float*)d_in[17];
  const float* gas = (const float*)d_in[18];
  const float* gad = (const float*)d_in[19];
  const float* gb  = (const float*)d_in[20];
  const float* Watt = (const float*)d_in[21];
  const float* atts = (const float*)d_in[22];
  const float* W1l = (const float*)d_in[23]; const float* b1 = (const float*)d_in[24];
  const float* W1r = (const float*)d_in[25];
  const float* W2l = (const float*)d_in[26]; const float* b2 = (const float*)d_in[27];
  const float* W2r = (const float*)d_in[28];
  (void)in_sizes; (void)n_in; (void)out_size; (void)ws_size;

  float* ws = (float*)d_ws;
  size_t off = 0;
  auto alloc = [&](size_t n) { float* p = ws + off; off += n; return p; };
  float* h_a = alloc(524288);
  float* x_t = alloc(524288);
  float* Pr  = alloc(3670016);            // the multi-life region
  // early aliases
  float* h_p  = Pr;
  float* h_t  = Pr + 1048576;
  float* h_c  = Pr + 1572864;
  float* hs_p = Pr + 1835008;
  float* hs_t = Pr + 2883584;
  float* hs_c = Pr + 3407872;
  // mid alias
  float* pacc = Pr;
  // late aliases
  float* satt = Pr;
  float* h1   = Pr + 1048576;
  float* p2   = Pr + 2097152;
  float* deg  = Pr + 2359296;
  float* agg1 = Pr + 2363392;
  float* agg2 = Pr + 2887680;             // ends at 3,149,824 < 3,670,016
  // bf16 hi/lo buffers (float units = u16 count / 2)
  u16* qn_h   = (u16*)alloc(4096 * 64);
  u16* qn_l   = (u16*)alloc(4096 * 64);
  u16* kn_p_h = (u16*)alloc(8192 * 64);
  u16* kn_p_l = (u16*)alloc(8192 * 64);
  u16* kn_t_h = (u16*)alloc(4096 * 64);
  u16* kn_t_l = (u16*)alloc(4096 * 64);
  u16* kn_c_h = (u16*)alloc(2048 * 64);
  u16* kn_c_l = (u16*)alloc(2048 * 64);
  u16* vt_p_h = (u16*)alloc(8192 * 64);
  u16* vt_p_l = (u16*)alloc(8192 * 64);
  u16* vt_t_h = (u16*)alloc(4096 * 64);
  u16* vt_t_l = (u16*)alloc(4096 * 64);
  u16* vt_c_h = (u16*)alloc(2048 * 64);
  u16* vt_c_l = (u16*)alloc(2048 * 64);
  float* ald   = alloc(3 * 4096);
  float* als_p = alloc(8192);
  float* als_t = alloc(4096);
  float* als_c = alloc(2048);
  float* wdv   = alloc(3 * 128);
  float* wsv   = alloc(3 * 128);
  float* het0  = alloc(524288);
  float* het1  = alloc(524288);
  float* het2  = alloc(524288);
  float* pm    = alloc(7 * 4096);
  float* pl    = alloc(7 * 4096);
  float* scp   = alloc(16);
  float* alp   = alloc(16);

  hipMemsetAsync(scp, 0, 32 * sizeof(float), stream);   // scp + alp

  dim3 blk(256);
  // ---- dimension transforms ----
  gemm_k<1, 0, 0><<<dim3(64, 2),  blk, 0, stream>>>(xma, Wla, bla, h_a, 4096, 668, 128);
  gemm_k<1, 0, 0><<<dim3(128, 2), blk, 0, stream>>>(xmp, Wlp, blp, h_p, 8192, 1024, 128);
  gemm_k<1, 0, 0><<<dim3(64, 2),  blk, 0, stream>>>(xmt, Wlt, blt, h_t, 4096, 256, 128);
  gemm_k<1, 0, 0><<<dim3(32, 2),  blk, 0, stream>>>(xmc, Wlc, blc, h_c, 2048, 128, 128);
  gemm_k<1, 0, 0><<<dim3(64, 2),  blk, 0, stream>>>(xia, Wtg, btg, x_t, 4096, 334, 128);
  // ---- GAT precompute ----
  gemm_k<0, 0, 0><<<dim3(128, 2), blk, 0, stream>>>(h_p, gWs + 0 * 16384, nullptr, hs_p, 8192, 128, 128);
  gemm_k<0, 0, 0><<<dim3(64, 2),  blk, 0, stream>>>(h_t, gWs + 1 * 16384, nullptr, hs_t, 4096, 128, 128);
  gemm_k<0, 0, 0><<<dim3(32, 2),  blk, 0, stream>>>(h_c, gWs + 2 * 16384, nullptr, hs_c, 2048, 128, 128);
  wvec_k<<<dim3(6), dim3(128), 0, stream>>>(gWd, gad, gWs, gas, wdv, wsv);
  rownorm2_k<<<dim3(1024), blk, 0, stream>>>(h_a, qn_h, qn_l, wdv, 3, ald, 4096);
  rownorm2_k<<<dim3(2048), blk, 0, stream>>>(h_p, kn_p_h, kn_p_l, wsv + 0,   1, als_p, 8192);
  rownorm2_k<<<dim3(1024), blk, 0, stream>>>(h_t, kn_t_h, kn_t_l, wsv + 128, 1, als_t, 4096);
  rownorm2_k<<<dim3(512),  blk, 0, stream>>>(h_c, kn_c_h, kn_c_l, wsv + 256, 1, als_c, 2048);
  tconv_k<<<dim3(128, 2), blk, 0, stream>>>(hs_p, vt_p_h, vt_p_l, 8192);
  tconv_k<<<dim3(64, 2),  blk, 0, stream>>>(hs_t, vt_t_h, vt_t_l, 4096);
  tconv_k<<<dim3(32, 2),  blk, 0, stream>>>(hs_c, vt_c_h, vt_c_l, 2048);
  // ---- MFMA flash-GAT + merge (pacc overwrites dead h_*/hs_*) ----
  GatP gp;
  gp.qh = qn_h; gp.ql = qn_l;
  gp.kh[0] = kn_p_h; gp.kh[1] = kn_t_h; gp.kh[2] = kn_c_h;
  gp.kl[0] = kn_p_l; gp.kl[1] = kn_t_l; gp.kl[2] = kn_c_l;
  gp.vh[0] = vt_p_h; gp.vh[1] = vt_t_h; gp.vh[2] = vt_c_h;
  gp.vl[0] = vt_p_l; gp.vl[1] = vt_t_l; gp.vl[2] = vt_c_l;
  gp.als[0] = als_p; gp.als[1] = als_t; gp.als[2] = als_c;
  gp.ald = ald; gp.pacc = pacc; gp.pm = pm; gp.pl = pl;
  gat_k<<<dim3(448), blk, 0, stream>>>(gp);
  gatmerge_k<<<dim3(2048, 3), blk, 0, stream>>>(pacc, pm, pl, gb, het0, het1, het2);
  // pacc now dead -> zero the late-alias SAGE buffers (deg,agg1,agg2)
  hipMemsetAsync(deg, 0, (size_t)790528 * sizeof(float), stream);
  // ---- AttentionInfo ----
  gemm_k<0, 0, 0><<<dim3(64, 1), blk, 0, stream>>>(het0, Watt, nullptr, satt + 0 * 262144, 4096, 128, 64);
  gemm_k<0, 0, 0><<<dim3(64, 1), blk, 0, stream>>>(het1, Watt, nullptr, satt + 1 * 262144, 4096, 128, 64);
  gemm_k<0, 0, 0><<<dim3(64, 1), blk, 0, stream>>>(het2, Watt, nullptr, satt + 2 * 262144, 4096, 128, 64);
  gemm_k<0, 0, 0><<<dim3(64, 1), blk, 0, stream>>>(x_t,  Watt, nullptr, satt + 3 * 262144, 4096, 128, 64);
  attred_k<<<dim3(32, 4), blk, 0, stream>>>(satt, atts, scp);
  alpha_k<<<dim3(1), dim3(64), 0, stream>>>(scp, alp);
  xatt_k<<<dim3(2048), blk, 0, stream>>>(het0, het1, het2, x_t, alp, (float*)d_out + 262144);
  // ---- GraphSAGE (layer2 = matmul-then-aggregate: 64-wide atomics) ----
  const int E = 131072;
  const int* esrc = ei;
  const int* edst = ei + E;
  scatter_deg_k<<<dim3(512), blk, 0, stream>>>(edst, deg, E);
  scatter_add_k<<<dim3(65536), blk, 0, stream>>>(h_a, esrc, edst, agg1, E, 128, 7);
  aggnorm_k<<<dim3(2048), blk, 0, stream>>>(agg1, deg);
  gemm_k<1, 0, 0><<<dim3(64, 4), blk, 0, stream>>>(agg1, W1l, b1, h1, 4096, 128, 256);
  gemm_k<0, 1, 1><<<dim3(64, 4), blk, 0, stream>>>(h_a, W1r, nullptr, h1, 4096, 128, 256);
  gemm_k<0, 0, 0><<<dim3(64, 1), blk, 0, stream>>>(h1, W2l, nullptr, p2, 4096, 256, 64);
  scatter_add_k<<<dim3(32768), blk, 0, stream>>>(p2, esrc, edst, agg2, E, 64, 6);
  gemm_k<1, 0, 0><<<dim3(64, 1), blk, 0, stream>>>(h1, W2r, b2, (float*)d_out, 4096, 256, 64);
  finaladd_k<<<dim3(1024), blk, 0, stream>>>((float*)d_out, agg2, deg);
}

// Round 5
// 1278.208 us; speedup vs baseline: 1.1957x; 1.0317x over previous
//
#include <hip/hip_runtime.h>
#include <math.h>

#define THRESH 0.1f
#define NSLOPE 0.2f

typedef __attribute__((ext_vector_type(8))) short short8;
typedef __attribute__((ext_vector_type(4))) float f32x4;
typedef unsigned short u16;
typedef unsigned int u32;

#define MFMA16(a, b, c) __builtin_amdgcn_mfma_f32_16x16x32_bf16(a, b, c, 0, 0, 0)

__device__ inline u16 f2bf(float x) {
  u32 u = __float_as_uint(x);
  u += 0x7FFF + ((u >> 16) & 1);
  return (u16)(u >> 16);
}
__device__ inline float bf2f(u16 h) { return __uint_as_float((u32)h << 16); }

// =====================================================================
// Weight transpose-convert: W [K][N] fp32 -> WtH/WtL [N][Kpad] bf16 hi/lo
// (zeros for k in [K, Kpad)). grid (ceil(Kpad/64), N/64).
// =====================================================================
__global__ __launch_bounds__(256)
void wconv_k(const float* __restrict__ W, u16* __restrict__ dh, u16* __restrict__ dl,
             int K, int Kpad, int N) {
  __shared__ float tl[64][65];
  const int t = threadIdx.x;
  const int k0 = blockIdx.x * 64, n0 = blockIdx.y * 64;
#pragma unroll
  for (int l = 0; l < 4; ++l) {
    int i = t + l * 256; int r = i >> 4; int c4 = i & 15;
    float4 v = make_float4(0.f, 0.f, 0.f, 0.f);
    if (k0 + r < K) v = *(const float4*)&W[(size_t)(k0 + r) * N + n0 + c4 * 4];
    *(float4*)&tl[r][c4 * 4] = v;
  }
  __syncthreads();
#pragma unroll
  for (int l = 0; l < 2; ++l) {
    int g = t + l * 256; int f = g >> 3; int s8 = (g & 7) * 8;
    if (k0 + s8 >= Kpad) continue;
    u32 ph[4], pl[4];
#pragma unroll
    for (int k = 0; k < 4; ++k) {
      float a = tl[s8 + 2 * k][f], b = tl[s8 + 2 * k + 1][f];
      u16 ha = f2bf(a), hb = f2bf(b);
      u16 la = f2bf(a - bf2f(ha)), lb = f2bf(b - bf2f(hb));
      ph[k] = (u32)ha | ((u32)hb << 16);
      pl[k] = (u32)la | ((u32)lb << 16);
    }
    size_t o = (size_t)(n0 + f) * Kpad + k0 + s8;
    *(uint4*)&dh[o] = make_uint4(ph[0], ph[1], ph[2], ph[3]);
    *(uint4*)&dl[o] = make_uint4(pl[0], pl[1], pl[2], pl[3]);
  }
}

// =====================================================================
// Split-bf16 MFMA GEMM: C[M,N] = A[M,K](fp32) @ W + bias / += / relu.
// W preconverted as WtH/WtL [N][Kpad]. A loaded per-lane (8 contig fp32)
// and converted in-register -> no LDS. Block 256 = 4 waves; each wave
// 16 rows x 64 cols. grid (M/64, N/64). K even; Kpad = ceil32(K).
// 3-term split product ~= fp32 accuracy.
// =====================================================================
template<int BIAS, int ACCUM, int RELU>
__global__ __launch_bounds__(256)
void mgemm_k(const float* __restrict__ A, const u16* __restrict__ WtH,
             const u16* __restrict__ WtL, const float* __restrict__ bias,
             float* C, int M, int K, int Kpad, int N) {
  const int t = threadIdx.x, wm = t >> 6, ln = t & 63;
  const int lg = ln >> 4, lc = ln & 15;
  const int i0 = blockIdx.x * 64, n0 = blockIdx.y * 64;
  const int arow = i0 + wm * 16 + lc;
  f32x4 acc[4];
#pragma unroll
  for (int tn = 0; tn < 4; ++tn) acc[tn] = (f32x4)0.f;

  for (int k0 = 0; k0 < K; k0 += 32) {
    // ---- A fragment: 8 contiguous fp32 -> hi/lo bf16 ----
    float av[8];
    const float* ap = A + (size_t)arow * K + k0 + lg * 8;
    if (k0 + 32 <= K) {
#pragma unroll
      for (int q = 0; q < 4; ++q) {
        float2 v = *(const float2*)(ap + q * 2);
        av[q * 2] = v.x; av[q * 2 + 1] = v.y;
      }
    } else {
#pragma unroll
      for (int kk = 0; kk < 8; ++kk) {
        int k = k0 + lg * 8 + kk;
        av[kk] = (k < K) ? ap[kk] : 0.f;
      }
    }
    short8 ah, al;
#pragma unroll
    for (int kk = 0; kk < 8; ++kk) {
      u16 h = f2bf(av[kk]);
      ah[kk] = (short)h;
      al[kk] = (short)f2bf(av[kk] - bf2f(h));
    }
    // ---- B fragments (4 col-tiles) ----
    short8 bh[4], bl[4];
#pragma unroll
    for (int tn = 0; tn < 4; ++tn) {
      size_t o = (size_t)(n0 + tn * 16 + lc) * Kpad + k0 + lg * 8;
      bh[tn] = *(const short8*)(WtH + o);
      bl[tn] = *(const short8*)(WtL + o);
    }
#pragma unroll
    for (int tn = 0; tn < 4; ++tn) {
      acc[tn] = MFMA16(ah, bh[tn], acc[tn]);
      acc[tn] = MFMA16(ah, bl[tn], acc[tn]);
      acc[tn] = MFMA16(al, bh[tn], acc[tn]);
    }
  }
#pragma unroll
  for (int tn = 0; tn < 4; ++tn)
#pragma unroll
    for (int r = 0; r < 4; ++r) {
      size_t row = (size_t)(i0 + wm * 16 + lg * 4 + r);
      float* cp = &C[row * N + n0 + tn * 16 + lc];
      float o = acc[tn][r];
      if (BIAS) o += bias[n0 + tn * 16 + lc];
      if (ACCUM) o += *cp;
      if (RELU) o = fmaxf(o, 0.f);
      *cp = o;
    }
}

// =====================================================================
// wdvec[t] = Wd[t] @ a_d[t], wsvec[t] = Ws[t] @ a_s[t]
// =====================================================================
__global__ void wvec_k(const float* __restrict__ Wd, const float* __restrict__ ad,
                       const float* __restrict__ Ws, const float* __restrict__ as_,
                       float* __restrict__ wdv, float* __restrict__ wsv) {
  int b = blockIdx.x, k = threadIdx.x;
  const float* Wm = (b < 3) ? Wd + (size_t)b * 16384 : Ws + (size_t)(b - 3) * 16384;
  const float* av = (b < 3) ? ad + b * 128 : as_ + (b - 3) * 128;
  float* o = (b < 3) ? wdv + b * 128 : wsv + (b - 3) * 128;
  float s = 0.f;
  for (int c = 0; c < 128; ++c) s = fmaf(Wm[(size_t)k * 128 + c], av[c], s);
  o[k] = s;
}

// =====================================================================
// Row stats: normalized row -> bf16 hi/lo; al_out[v][i] = row . avec[v]
// =====================================================================
__global__ __launch_bounds__(256)
void rownorm2_k(const float* __restrict__ X, u16* __restrict__ XH, u16* __restrict__ XL,
                const float* __restrict__ avecs, int navec,
                float* __restrict__ al_out, int N) {
  int lane = threadIdx.x & 63, wv = threadIdx.x >> 6;
  int i = blockIdx.x * 4 + wv;
  float x0 = X[(size_t)i * 128 + lane];
  float x1 = X[(size_t)i * 128 + 64 + lane];
  float ss = x0 * x0 + x1 * x1;
#pragma unroll
  for (int o = 1; o < 64; o <<= 1) ss += __shfl_xor(ss, o);
  float inv = 1.f / fmaxf(sqrtf(ss), 1e-12f);
  for (int v = 0; v < navec; ++v) {
    float d = x0 * avecs[v * 128 + lane] + x1 * avecs[v * 128 + 64 + lane];
#pragma unroll
    for (int o = 1; o < 64; o <<= 1) d += __shfl_xor(d, o);
    if (lane == 0) al_out[(size_t)v * N + i] = d;
  }
  float n0 = x0 * inv, n1 = x1 * inv;
  u16 h0 = f2bf(n0), h1 = f2bf(n1);
  XH[(size_t)i * 128 + lane]      = h0;
  XH[(size_t)i * 128 + 64 + lane] = h1;
  XL[(size_t)i * 128 + lane]      = f2bf(n0 - bf2f(h0));
  XL[(size_t)i * 128 + 64 + lane] = f2bf(n1 - bf2f(h1));
}

// =====================================================================
// Transpose-convert: hs fp32 [N][128] -> Vt_hi/Vt_lo bf16 [128][N]
// =====================================================================
__global__ __launch_bounds__(256)
void tconv_k(const float* __restrict__ src, u16* __restrict__ dh, u16* __restrict__ dl, int N) {
  __shared__ float tl[64][65];
  const int t = threadIdx.x;
  const int sb = blockIdx.x, fb = blockIdx.y;
#pragma unroll
  for (int l = 0; l < 4; ++l) {
    int i = t + l * 256; int r = i >> 4; int c4 = i & 15;
    *(float4*)&tl[r][c4 * 4] = *(const float4*)&src[(size_t)(sb * 64 + r) * 128 + fb * 64 + c4 * 4];
  }
  __syncthreads();
#pragma unroll
  for (int l = 0; l < 2; ++l) {
    int g = t + l * 256; int f = g >> 3; int s8 = (g & 7) * 8;
    u32 ph[4], pl[4];
#pragma unroll
    for (int k = 0; k < 4; ++k) {
      float a = tl[s8 + 2 * k][f], b = tl[s8 + 2 * k + 1][f];
      u16 ha = f2bf(a), hb = f2bf(b);
      u16 la = f2bf(a - bf2f(ha)), lb = f2bf(b - bf2f(hb));
      ph[k] = (u32)ha | ((u32)hb << 16);
      pl[k] = (u32)la | ((u32)lb << 16);
    }
    size_t o = (size_t)(fb * 64 + f) * N + sb * 64 + s8;
    *(uint4*)&dh[o] = make_uint4(ph[0], ph[1], ph[2], ph[3]);
    *(uint4*)&dl[o] = make_uint4(pl[0], pl[1], pl[2], pl[3]);
  }
}

// =====================================================================
// MFMA flash-GAT, 8-wave blocks with in-block j-split flash merge.
// 7 chunk-globals of 2048 srcs x 64 author-blocks -> 448 blocks x 512 thr.
// Waves 0-3: srcs [0,1024) of chunk; waves 4-7: [1024,2048); 16 authors
// per wave; merge halves via LDS at the end. No barrier in main loop.
// =====================================================================
struct GatP {
  const u16 *qh, *ql;
  const u16 *kh[3], *kl[3];
  const u16 *vh[3], *vl[3];
  const float *als[3];
  const float *ald;            // [3][4096]
  float *pacc;                 // [7][4096][128]
  float *pm;                   // [7][4096]
  float *pl;                   // [7][4096]
};

__global__ __launch_bounds__(512, 4)
void gat_k(GatP P) {
  __shared__ u16 wh[8][16][40];     // per-wave P (hi), padded stride 40
  __shared__ u16 wl_[8][16][40];    // per-wave P (lo)
  __shared__ float mrg[4][16][132]; // merge acc (upper halves)
  __shared__ float mml[4][2][16];   // merge m/l

  // XCD-contiguous remap: each XCD owns 56 consecutive work-ids
  const int b = ((blockIdx.x & 7) * 56) + (blockIdx.x >> 3);
  const int cg = b >> 6;
  const int rb = b & 63;
  const int type = (cg < 4) ? 0 : (cg < 6 ? 1 : 2);
  const int chunk = cg - (type == 0 ? 0 : (type == 1 ? 4 : 6));
  const int srcN = (type == 0) ? 8192 : (type == 1 ? 4096 : 2048);
  const u16* KH = P.kh[type]; const u16* KL = P.kl[type];
  const u16* VH = P.vh[type]; const u16* VL = P.vl[type];
  const float* alsg = P.als[type];
  const float* ALD = P.ald + (size_t)type * 4096;
  const int i0 = rb * 64;

  const int t = threadIdx.x;
  const int wm = t >> 6;          // wave 0..7
  const int jhalf = wm >> 2;      // 0 or 1
  const int wq = wm & 3;          // author quarter
  const int ln = t & 63;
  const int lg = ln >> 4;
  const int lc = ln & 15;
  const int arow0 = i0 + wq * 16;
  const int cj0 = chunk * 2048 + jhalf * 1024;

  // Q fragments (held across all iterations)
  short8 qhf[4], qlf[4];
#pragma unroll
  for (int ks = 0; ks < 4; ++ks) {
    size_t qo = (size_t)(arow0 + lc) * 128 + ks * 32 + lg * 8;
    qhf[ks] = *(const short8*)(P.qh + qo);
    qlf[ks] = *(const short8*)(P.ql + qo);
  }
  float ald_r[4], m[4], lsum[4];
#pragma unroll
  for (int r = 0; r < 4; ++r) {
    ald_r[r] = ALD[arow0 + lg * 4 + r];
    m[r] = -1e30f; lsum[r] = 0.f;
  }
  f32x4 pacc[8];
#pragma unroll
  for (int n = 0; n < 8; ++n) pacc[n] = (f32x4)0.f;

  for (int jt = 0; jt < 32; ++jt) {
    const int j0 = cj0 + jt * 32;
    // ---- K B-frag loads ----
    short8 kbh[2][4], kbl[2][4];
#pragma unroll
    for (int tn = 0; tn < 2; ++tn)
#pragma unroll
      for (int ks = 0; ks < 4; ++ks) {
        size_t ko = (size_t)(j0 + tn * 16 + lc) * 128 + ks * 32 + lg * 8;
        kbh[tn][ks] = *(const short8*)(KH + ko);
        kbl[tn][ks] = *(const short8*)(KL + ko);
      }
    float als0 = alsg[j0 + lc], als1 = alsg[j0 + 16 + lc];
    // ---- S = cos-sim: 3-term split-bf16 MFMA ----
    f32x4 sacc[2];
    sacc[0] = (f32x4)0.f; sacc[1] = (f32x4)0.f;
    __builtin_amdgcn_s_setprio(1);
#pragma unroll
    for (int ks = 0; ks < 4; ++ks)
#pragma unroll
      for (int tn = 0; tn < 2; ++tn) {
        sacc[tn] = MFMA16(qhf[ks], kbh[tn][ks], sacc[tn]);
        sacc[tn] = MFMA16(qhf[ks], kbl[tn][ks], sacc[tn]);
        sacc[tn] = MFMA16(qlf[ks], kbh[tn][ks], sacc[tn]);
      }
    __builtin_amdgcn_s_setprio(0);
    // ---- V B-frag loads (latency hides under softmax) ----
    short8 vbh[8], vbl[8];
#pragma unroll
    for (int tn = 0; tn < 8; ++tn) {
      size_t vo = (size_t)(tn * 16 + lc) * srcN + j0 + lg * 8;
      vbh[tn] = *(const short8*)(VH + vo);
      vbl[tn] = *(const short8*)(VL + vo);
    }
    // ---- mask + leaky + online softmax ----
    float w0s[4], w1s[4], scl[4];
#pragma unroll
    for (int r = 0; r < 4; ++r) {
      int ag = arow0 + lg * 4 + r;
      float z0 = ald_r[r] + als0; z0 = (z0 >= 0.f) ? z0 : NSLOPE * z0;
      float z1 = ald_r[r] + als1; z1 = (z1 >= 0.f) ? z1 : NSLOPE * z1;
      bool a0 = (sacc[0][r] > THRESH) && (j0 + lc != ag);
      bool a1 = (sacc[1][r] > THRESH) && (j0 + 16 + lc != ag);
      float e0 = a0 ? z0 : -1e30f;
      float e1 = a1 ? z1 : -1e30f;
      float rm = fmaxf(e0, e1);
#pragma unroll
      for (int o = 1; o < 16; o <<= 1) rm = fmaxf(rm, __shfl_xor(rm, o));
      float mn = fmaxf(m[r], rm);
      scl[r] = __expf(m[r] - mn);
      m[r] = mn;
      float w0 = (e0 > -1e29f) ? __expf(e0 - mn) : 0.f;
      float w1 = (e1 > -1e29f) ? __expf(e1 - mn) : 0.f;
      float rs = w0 + w1;
#pragma unroll
      for (int o = 1; o < 16; o <<= 1) rs += __shfl_xor(rs, o);
      lsum[r] = lsum[r] * scl[r] + rs;
      w0s[r] = w0; w1s[r] = w1;
    }
    // ---- P transpose via per-wave LDS slice (same-wave, no barrier) ----
#pragma unroll
    for (int r = 0; r < 4; ++r) {
      u16 h0 = f2bf(w0s[r]);
      u16 h1 = f2bf(w1s[r]);
      wh[wm][lg * 4 + r][lc]      = h0;
      wh[wm][lg * 4 + r][16 + lc] = h1;
      wl_[wm][lg * 4 + r][lc]      = f2bf(w0s[r] - bf2f(h0));
      wl_[wm][lg * 4 + r][16 + lc] = f2bf(w1s[r] - bf2f(h1));
    }
#pragma unroll
    for (int n = 0; n < 8; ++n)
#pragma unroll
      for (int r = 0; r < 4; ++r) pacc[n][r] *= scl[r];
    short8 wfh = *(const short8*)&wh[wm][lc][lg * 8];
    short8 wfl = *(const short8*)&wl_[wm][lc][lg * 8];
    // ---- PV: 3-term split-bf16 MFMA ----
    __builtin_amdgcn_s_setprio(1);
#pragma unroll
    for (int n = 0; n < 8; ++n) {
      pacc[n] = MFMA16(wfh, vbh[n], pacc[n]);
      pacc[n] = MFMA16(wfh, vbl[n], pacc[n]);
      pacc[n] = MFMA16(wfl, vbh[n], pacc[n]);
    }
    __builtin_amdgcn_s_setprio(0);
  }
  // ---- in-block flash merge of the two j-halves ----
  if (wm >= 4) {
#pragma unroll
    for (int n = 0; n < 8; ++n)
#pragma unroll
      for (int r = 0; r < 4; ++r)
        mrg[wq][lg * 4 + r][n * 16 + lc] = pacc[n][r];
    if (lc == 0) {
#pragma unroll
      for (int r = 0; r < 4; ++r) {
        mml[wq][0][lg * 4 + r] = m[r];
        mml[wq][1][lg * 4 + r] = lsum[r];
      }
    }
  }
  __syncthreads();
  if (wm < 4) {
#pragma unroll
    for (int r = 0; r < 4; ++r) {
      float mu = mml[wq][0][lg * 4 + r];
      float lu = mml[wq][1][lg * 4 + r];
      float M = fmaxf(m[r], mu);
      float sA = __expf(m[r] - M);
      float sB = __expf(mu - M);
      lsum[r] = lsum[r] * sA + lu * sB;
      m[r] = M;
#pragma unroll
      for (int n = 0; n < 8; ++n)
        pacc[n][r] = pacc[n][r] * sA + mrg[wq][lg * 4 + r][n * 16 + lc] * sB;
    }
#pragma unroll
    for (int n = 0; n < 8; ++n)
#pragma unroll
      for (int r = 0; r < 4; ++r) {
        size_t row = (size_t)(arow0 + lg * 4 + r);
        P.pacc[(size_t)cg * 524288 + row * 128 + n * 16 + lc] = pacc[n][r];
      }
    if (lc == 0) {
#pragma unroll
      for (int r = 0; r < 4; ++r) {
        size_t row = (size_t)(arow0 + lg * 4 + r);
        P.pm[(size_t)cg * 4096 + row] = m[r];
        P.pl[(size_t)cg * 4096 + row] = lsum[r];
      }
    }
  }
}

// =====================================================================
// Merge flash partials (7 chunks: paper 4, term 2, conf 1)
// =====================================================================
__global__ __launch_bounds__(256)
void gatmerge_k(const float* __restrict__ pacc, const float* __restrict__ pm,
                const float* __restrict__ pl, const float* __restrict__ gatb,
                float* __restrict__ out0, float* __restrict__ out1, float* __restrict__ out2) {
  int type = blockIdx.y;
  int nc = (type == 0) ? 4 : (type == 1 ? 2 : 1);
  int cb = (type == 0) ? 0 : (type == 1 ? 4 : 6);
  float* OUT = (type == 0) ? out0 : (type == 1 ? out1 : out2);
  int idx = blockIdx.x * 256 + threadIdx.x;
  int i = idx >> 7, c = idx & 127;
  float M = -1e30f;
  for (int ch = 0; ch < nc; ++ch) M = fmaxf(M, pm[(size_t)(cb + ch) * 4096 + i]);
  float num = 0.f, den = 0.f;
  for (int ch = 0; ch < nc; ++ch) {
    float sc = __expf(pm[(size_t)(cb + ch) * 4096 + i] - M);
    den += pl[(size_t)(cb + ch) * 4096 + i] * sc;
    num += pacc[(size_t)(cb + ch) * 524288 + idx] * sc;
  }
  float bv = gatb[(size_t)type * 128 + c];
  OUT[idx] = (den > 0.f) ? num / den + bv : bv;
}

// =====================================================================
// AttentionInfo + SAGE pieces
// =====================================================================
__global__ __launch_bounds__(256)
void attred_k(const float* __restrict__ satt, const float* __restrict__ atts,
              float* __restrict__ scp) {
  int v = blockIdx.y;
  const float* S = satt + (size_t)v * 262144;
  const float* av = atts + v * 64;
  float local = 0.f;
  for (int idx = blockIdx.x * 256 + threadIdx.x; idx < 262144; idx += 32 * 256) {
    float x = S[idx];
    local += av[idx & 63] / (1.f + __expf(-x));
  }
#pragma unroll
  for (int o = 1; o < 64; o <<= 1) local += __shfl_xor(local, o);
  __shared__ float red[4];
  if ((threadIdx.x & 63) == 0) red[threadIdx.x >> 6] = local;
  __syncthreads();
  if (threadIdx.x == 0) atomicAdd(&scp[v], red[0] + red[1] + red[2] + red[3]);
}

__global__ void alpha_k(const float* __restrict__ scp, float* __restrict__ alp) {
  if (threadIdx.x == 0) {
    float s0 = scp[0] * (1.f / 4096.f), s1 = scp[1] * (1.f / 4096.f);
    float s2 = scp[2] * (1.f / 4096.f), s3 = scp[3] * (1.f / 4096.f);
    float mx = fmaxf(fmaxf(s0, s1), fmaxf(s2, s3));
    float e0 = __expf(s0 - mx), e1 = __expf(s1 - mx);
    float e2 = __expf(s2 - mx), e3 = __expf(s3 - mx);
    float d = e0 + e1 + e2 + e3;
    alp[0] = e0 / d; alp[1] = e1 / d; alp[2] = e2 / d; alp[3] = e3 / d;
  }
}

__global__ __launch_bounds__(256)
void xatt_k(const float* __restrict__ h0, const float* __restrict__ h1,
            const float* __restrict__ h2, const float* __restrict__ xt,
            const float* __restrict__ alp, float* __restrict__ out) {
  int idx = blockIdx.x * 256 + threadIdx.x;
  out[idx] = alp[0] * h0[idx] + alp[1] * h1[idx] + alp[2] * h2[idx] + alp[3] * xt[idx];
}

__global__ __launch_bounds__(256)
void scatter_deg_k(const int* __restrict__ dst, float* __restrict__ deg, int E) {
  int e = blockIdx.x * 256 + threadIdx.x;
  if (e < E) atomicAdd(&deg[dst[e]], 1.0f);
}

__global__ __launch_bounds__(256)
void scatter_add_k(const float* __restrict__ H, const int* __restrict__ src,
                   const int* __restrict__ dst, float* __restrict__ agg,
                   int E, int F, int fshift) {
  int idx = blockIdx.x * 256 + threadIdx.x;
  int e = idx >> fshift;
  int f = idx & (F - 1);
  if (e < E) atomicAdd(&agg[(size_t)dst[e] * F + f], H[(size_t)src[e] * F + f]);
}

__global__ __launch_bounds__(256)
void aggnorm_k(float* __restrict__ agg, const float* __restrict__ deg) {
  int idx = blockIdx.x * 256 + threadIdx.x;
  agg[idx] *= 1.f / fmaxf(deg[idx >> 7], 1.f);
}

__global__ __launch_bounds__(256)
void finaladd_k(float* __restrict__ out, const float* __restrict__ agg2,
                const float* __restrict__ deg) {
  int idx = blockIdx.x * 256 + threadIdx.x;
  out[idx] += agg2[idx] / fmaxf(deg[idx >> 6], 1.f);
}

// =====================================================================
// Launch. Workspace ~44.1 MB (< 45.4 MB empirical bound).
// Region Pr (3,670,016 floats) triple-used with disjoint lifetimes.
// =====================================================================
extern "C" void kernel_launch(void* const* d_in, const int* in_sizes, int n_in,
                              void* d_out, int out_size, void* d_ws, size_t ws_size,
                              hipStream_t stream) {
  const float* xma = (const float*)d_in[0];
  const float* xmp = (const float*)d_in[1];
  const float* xmt = (const float*)d_in[2];
  const float* xmc = (const float*)d_in[3];
  const float* xia = (const float*)d_in[4];
  const int*   ei  = (const int*)  d_in[5];
  const float* Wla = (const float*)d_in[6];  const float* bla = (const float*)d_in[7];
  const float* Wlp = (const float*)d_in[8];  const float* blp = (const float*)d_in[9];
  const float* Wlt = (const float*)d_in[10]; const float* blt = (const float*)d_in[11];
  const float* Wlc = (const float*)d_in[12]; const float* blc = (const float*)d_in[13];
  const float* Wtg = (const float*)d_in[14]; const float* btg = (const float*)d_in[15];
  const float* gWs = (const float*)d_in[16];
  const float* gWd = (const float*)d_in[17];
  const float* gas = (const float*)d_in[18];
  const float* gad = (const float*)d_in[19];
  const float* gb  = (const float*)d_in[20];
  const float* Watt = (const float*)d_in[21];
  const float* atts = (const float*)d_in[22];
  const float* W1l = (const float*)d_in[23]; const float* b1 = (const float*)d_in[24];
  const float* W1r = (const float*)d_in[25];
  const float* W2l = (const float*)d_in[26]; const float* b2 = (const float*)d_in[27];
  const float* W2r = (const float*)d_in[28];
  (void)in_sizes; (void)n_in; (void)out_size; (void)ws_size;

  float* ws = (float*)d_ws;
  size_t off = 0;
  auto alloc = [&](size_t n) { float* p = ws + off; off += n; return p; };
  float* h_a = alloc(524288);
  float* x_t = alloc(524288);
  float* Pr  = alloc(3670016);            // multi-life region
  // early aliases
  float* h_p  = Pr;
  float* h_t  = Pr + 1048576;
  float* h_c  = Pr + 1572864;
  float* hs_p = Pr + 1835008;
  float* hs_t = Pr + 2883584;
  float* hs_c = Pr + 3407872;
  // mid alias
  float* pacc = Pr;
  // late aliases
  float* satt = Pr;
  float* h1   = Pr + 1048576;
  float* p2   = Pr + 2097152;
  float* deg  = Pr + 2359296;
  float* agg1 = Pr + 2363392;
  float* agg2 = Pr + 2887680;
  // bf16 hi/lo K/V buffers
  u16* qn_h   = (u16*)alloc(4096 * 64);
  u16* qn_l   = (u16*)alloc(4096 * 64);
  u16* kn_p_h = (u16*)alloc(8192 * 64);
  u16* kn_p_l = (u16*)alloc(8192 * 64);
  u16* kn_t_h = (u16*)alloc(4096 * 64);
  u16* kn_t_l = (u16*)alloc(4096 * 64);
  u16* kn_c_h = (u16*)alloc(2048 * 64);
  u16* kn_c_l = (u16*)alloc(2048 * 64);
  u16* vt_p_h = (u16*)alloc(8192 * 64);
  u16* vt_p_l = (u16*)alloc(8192 * 64);
  u16* vt_t_h = (u16*)alloc(4096 * 64);
  u16* vt_t_l = (u16*)alloc(4096 * 64);
  u16* vt_c_h = (u16*)alloc(2048 * 64);
  u16* vt_c_l = (u16*)alloc(2048 * 64);
  // converted weights [N][Kpad] hi/lo
  u16* wla_h = (u16*)alloc(43008); u16* wla_l = (u16*)alloc(43008);   // 128x672
  u16* wlp_h = (u16*)alloc(65536); u16* wlp_l = (u16*)alloc(65536);   // 128x1024
  u16* wlt_h = (u16*)alloc(16384); u16* wlt_l = (u16*)alloc(16384);   // 128x256
  u16* wlc_h = (u16*)alloc(8192);  u16* wlc_l = (u16*)alloc(8192);    // 128x128
  u16* wtg_h = (u16*)alloc(22528); u16* wtg_l = (u16*)alloc(22528);   // 128x352
  u16* wws_h = (u16*)alloc(24576); u16* wws_l = (u16*)alloc(24576);   // 3x 128x128
  u16* wat_h = (u16*)alloc(4096);  u16* wat_l = (u16*)alloc(4096);    // 64x128
  u16* w1l_h = (u16*)alloc(16384); u16* w1l_l = (u16*)alloc(16384);   // 256x128
  u16* w1r_h = (u16*)alloc(16384); u16* w1r_l = (u16*)alloc(16384);   // 256x128
  u16* w2l_h = (u16*)alloc(8192);  u16* w2l_l = (u16*)alloc(8192);    // 64x256
  u16* w2r_h = (u16*)alloc(8192);  u16* w2r_l = (u16*)alloc(8192);    // 64x256
  float* ald   = alloc(3 * 4096);
  float* als_p = alloc(8192);
  float* als_t = alloc(4096);
  float* als_c = alloc(2048);
  float* wdv   = alloc(3 * 128);
  float* wsv   = alloc(3 * 128);
  float* het0  = alloc(524288);
  float* het1  = alloc(524288);
  float* het2  = alloc(524288);
  float* pm    = alloc(7 * 4096);
  float* pl    = alloc(7 * 4096);
  float* scp   = alloc(16);
  float* alp   = alloc(16);

  hipMemsetAsync(scp, 0, 32 * sizeof(float), stream);   // scp + alp

  dim3 blk(256);
  // ---- weight conversions ----
  wconv_k<<<dim3(11, 2), blk, 0, stream>>>(Wla, wla_h, wla_l, 668, 672, 128);
  wconv_k<<<dim3(16, 2), blk, 0, stream>>>(Wlp, wlp_h, wlp_l, 1024, 1024, 128);
  wconv_k<<<dim3(4, 2),  blk, 0, stream>>>(Wlt, wlt_h, wlt_l, 256, 256, 128);
  wconv_k<<<dim3(2, 2),  blk, 0, stream>>>(Wlc, wlc_h, wlc_l, 128, 128, 128);
  wconv_k<<<dim3(6, 2),  blk, 0, stream>>>(Wtg, wtg_h, wtg_l, 334, 352, 128);
  for (int i = 0; i < 3; ++i)
    wconv_k<<<dim3(2, 2), blk, 0, stream>>>(gWs + (size_t)i * 16384, wws_h + i * 16384, wws_l + i * 16384, 128, 128, 128);
  wconv_k<<<dim3(2, 1), blk, 0, stream>>>(Watt, wat_h, wat_l, 128, 128, 64);
  wconv_k<<<dim3(2, 4), blk, 0, stream>>>(W1l, w1l_h, w1l_l, 128, 128, 256);
  wconv_k<<<dim3(2, 4), blk, 0, stream>>>(W1r, w1r_h, w1r_l, 128, 128, 256);
  wconv_k<<<dim3(4, 1), blk, 0, stream>>>(W2l, w2l_h, w2l_l, 256, 256, 64);
  wconv_k<<<dim3(4, 1), blk, 0, stream>>>(W2r, w2r_h, w2r_l, 256, 256, 64);
  // ---- dimension transforms (MFMA) ----
  mgemm_k<1, 0, 0><<<dim3(64, 2),  blk, 0, stream>>>(xma, wla_h, wla_l, bla, h_a, 4096, 668, 672, 128);
  mgemm_k<1, 0, 0><<<dim3(128, 2), blk, 0, stream>>>(xmp, wlp_h, wlp_l, blp, h_p, 8192, 1024, 1024, 128);
  mgemm_k<1, 0, 0><<<dim3(64, 2),  blk, 0, stream>>>(xmt, wlt_h, wlt_l, blt, h_t, 4096, 256, 256, 128);
  mgemm_k<1, 0, 0><<<dim3(32, 2),  blk, 0, stream>>>(xmc, wlc_h, wlc_l, blc, h_c, 2048, 128, 128, 128);
  mgemm_k<1, 0, 0><<<dim3(64, 2),  blk, 0, stream>>>(xia, wtg_h, wtg_l, btg, x_t, 4096, 334, 352, 128);
  // ---- GAT precompute ----
  mgemm_k<0, 0, 0><<<dim3(128, 2), blk, 0, stream>>>(h_p, wws_h + 0 * 16384, wws_l + 0 * 16384, nullptr, hs_p, 8192, 128, 128, 128);
  mgemm_k<0, 0, 0><<<dim3(64, 2),  blk, 0, stream>>>(h_t, wws_h + 1 * 16384, wws_l + 1 * 16384, nullptr, hs_t, 4096, 128, 128, 128);
  mgemm_k<0, 0, 0><<<dim3(32, 2),  blk, 0, stream>>>(h_c, wws_h + 2 * 16384, wws_l + 2 * 16384, nullptr, hs_c, 2048, 128, 128, 128);
  wvec_k<<<dim3(6), dim3(128), 0, stream>>>(gWd, gad, gWs, gas, wdv, wsv);
  rownorm2_k<<<dim3(1024), blk, 0, stream>>>(h_a, qn_h, qn_l, wdv, 3, ald, 4096);
  rownorm2_k<<<dim3(2048), blk, 0, stream>>>(h_p, kn_p_h, kn_p_l, wsv + 0,   1, als_p, 8192);
  rownorm2_k<<<dim3(1024), blk, 0, stream>>>(h_t, kn_t_h, kn_t_l, wsv + 128, 1, als_t, 4096);
  rownorm2_k<<<dim3(512),  blk, 0, stream>>>(h_c, kn_c_h, kn_c_l, wsv + 256, 1, als_c, 2048);
  tconv_k<<<dim3(128, 2), blk, 0, stream>>>(hs_p, vt_p_h, vt_p_l, 8192);
  tconv_k<<<dim3(64, 2),  blk, 0, stream>>>(hs_t, vt_t_h, vt_t_l, 4096);
  tconv_k<<<dim3(32, 2),  blk, 0, stream>>>(hs_c, vt_c_h, vt_c_l, 2048);
  // ---- MFMA flash-GAT + merge ----
  GatP gp;
  gp.qh = qn_h; gp.ql = qn_l;
  gp.kh[0] = kn_p_h; gp.kh[1] = kn_t_h; gp.kh[2] = kn_c_h;
  gp.kl[0] = kn_p_l; gp.kl[1] = kn_t_l; gp.kl[2] = kn_c_l;
  gp.vh[0] = vt_p_h; gp.vh[1] = vt_t_h; gp.vh[2] = vt_c_h;
  gp.vl[0] = vt_p_l; gp.vl[1] = vt_t_l; gp.vl[2] = vt_c_l;
  gp.als[0] = als_p; gp.als[1] = als_t; gp.als[2] = als_c;
  gp.ald = ald; gp.pacc = pacc; gp.pm = pm; gp.pl = pl;
  gat_k<<<dim3(448), dim3(512), 0, stream>>>(gp);
  gatmerge_k<<<dim3(2048, 3), blk, 0, stream>>>(pacc, pm, pl, gb, het0, het1, het2);
  // pacc dead -> zero late-alias SAGE buffers (deg, agg1, agg2)
  hipMemsetAsync(deg, 0, (size_t)790528 * sizeof(float), stream);
  // ---- AttentionInfo ----
  mgemm_k<0, 0, 0><<<dim3(64, 1), blk, 0, stream>>>(het0, wat_h, wat_l, nullptr, satt + 0 * 262144, 4096, 128, 128, 64);
  mgemm_k<0, 0, 0><<<dim3(64, 1), blk, 0, stream>>>(het1, wat_h, wat_l, nullptr, satt + 1 * 262144, 4096, 128, 128, 64);
  mgemm_k<0, 0, 0><<<dim3(64, 1), blk, 0, stream>>>(het2, wat_h, wat_l, nullptr, satt + 2 * 262144, 4096, 128, 128, 64);
  mgemm_k<0, 0, 0><<<dim3(64, 1), blk, 0, stream>>>(x_t,  wat_h, wat_l, nullptr, satt + 3 * 262144, 4096, 128, 128, 64);
  attred_k<<<dim3(32, 4), blk, 0, stream>>>(satt, atts, scp);
  alpha_k<<<dim3(1), dim3(64), 0, stream>>>(scp, alp);
  xatt_k<<<dim3(2048), blk, 0, stream>>>(het0, het1, het2, x_t, alp, (float*)d_out + 262144);
  // ---- GraphSAGE ----
  const int E = 131072;
  const int* esrc = ei;
  const int* edst = ei + E;
  scatter_deg_k<<<dim3(512), blk, 0, stream>>>(edst, deg, E);
  scatter_add_k<<<dim3(65536), blk, 0, stream>>>(h_a, esrc, edst, agg1, E, 128, 7);
  aggnorm_k<<<dim3(2048), blk, 0, stream>>>(agg1, deg);
  mgemm_k<1, 0, 0><<<dim3(64, 4), blk, 0, stream>>>(agg1, w1l_h, w1l_l, b1, h1, 4096, 128, 128, 256);
  mgemm_k<0, 1, 1><<<dim3(64, 4), blk, 0, stream>>>(h_a, w1r_h, w1r_l, nullptr, h1, 4096, 128, 128, 256);
  mgemm_k<0, 0, 0><<<dim3(64, 1), blk, 0, stream>>>(h1, w2l_h, w2l_l, nullptr, p2, 4096, 256, 256, 64);
  scatter_add_k<<<dim3(32768), blk, 0, stream>>>(p2, esrc, edst, agg2, E, 64, 6);
  mgemm_k<1, 0, 0><<<dim3(64, 1), blk, 0, stream>>>(h1, w2r_h, w2r_l, b2, (float*)d_out, 4096, 256, 256, 64);
  finaladd_k<<<dim3(1024), blk, 0, stream>>>((float*)d_out, agg2, deg);
}

// Round 6
// 1273.161 us; speedup vs baseline: 1.2004x; 1.0040x over previous
//
#include <hip/hip_runtime.h>
#include <math.h>

#define THRESH 0.1f
#define NSLOPE 0.2f

typedef __attribute__((ext_vector_type(8))) short short8;
typedef __attribute__((ext_vector_type(4))) float f32x4;
typedef unsigned short u16;
typedef unsigned int u32;

#define MFMA16(a, b, c) __builtin_amdgcn_mfma_f32_16x16x32_bf16(a, b, c, 0, 0, 0)

__device__ inline u16 f2bf(float x) {
  u32 u = __float_as_uint(x);
  u += 0x7FFF + ((u >> 16) & 1);
  return (u16)(u >> 16);
}
__device__ inline float bf2f(u16 h) { return __uint_as_float((u32)h << 16); }

// =====================================================================
// Weight transpose-convert: W [K][N] fp32 -> WtH/WtL [N][Kpad] bf16 hi/lo
// =====================================================================
__global__ __launch_bounds__(256)
void wconv_k(const float* __restrict__ W, u16* __restrict__ dh, u16* __restrict__ dl,
             int K, int Kpad, int N) {
  __shared__ float tl[64][65];
  const int t = threadIdx.x;
  const int k0 = blockIdx.x * 64, n0 = blockIdx.y * 64;
#pragma unroll
  for (int l = 0; l < 4; ++l) {
    int i = t + l * 256; int r = i >> 4; int c4 = i & 15;
    float4 v = make_float4(0.f, 0.f, 0.f, 0.f);
    if (k0 + r < K) v = *(const float4*)&W[(size_t)(k0 + r) * N + n0 + c4 * 4];
    *(float4*)&tl[r][c4 * 4] = v;
  }
  __syncthreads();
#pragma unroll
  for (int l = 0; l < 2; ++l) {
    int g = t + l * 256; int f = g >> 3; int s8 = (g & 7) * 8;
    if (k0 + s8 >= Kpad) continue;
    u32 ph[4], pl[4];
#pragma unroll
    for (int k = 0; k < 4; ++k) {
      float a = tl[s8 + 2 * k][f], b = tl[s8 + 2 * k + 1][f];
      u16 ha = f2bf(a), hb = f2bf(b);
      u16 la = f2bf(a - bf2f(ha)), lb = f2bf(b - bf2f(hb));
      ph[k] = (u32)ha | ((u32)hb << 16);
      pl[k] = (u32)la | ((u32)lb << 16);
    }
    size_t o = (size_t)(n0 + f) * Kpad + k0 + s8;
    *(uint4*)&dh[o] = make_uint4(ph[0], ph[1], ph[2], ph[3]);
    *(uint4*)&dl[o] = make_uint4(pl[0], pl[1], pl[2], pl[3]);
  }
}

// =====================================================================
// Split-bf16 MFMA GEMM (verified round 5)
// =====================================================================
template<int BIAS, int ACCUM, int RELU>
__global__ __launch_bounds__(256)
void mgemm_k(const float* __restrict__ A, const u16* __restrict__ WtH,
             const u16* __restrict__ WtL, const float* __restrict__ bias,
             float* C, int M, int K, int Kpad, int N) {
  const int t = threadIdx.x, wm = t >> 6, ln = t & 63;
  const int lg = ln >> 4, lc = ln & 15;
  const int i0 = blockIdx.x * 64, n0 = blockIdx.y * 64;
  const int arow = i0 + wm * 16 + lc;
  f32x4 acc[4];
#pragma unroll
  for (int tn = 0; tn < 4; ++tn) acc[tn] = (f32x4)0.f;

  for (int k0 = 0; k0 < K; k0 += 32) {
    float av[8];
    const float* ap = A + (size_t)arow * K + k0 + lg * 8;
    if (k0 + 32 <= K) {
#pragma unroll
      for (int q = 0; q < 4; ++q) {
        float2 v = *(const float2*)(ap + q * 2);
        av[q * 2] = v.x; av[q * 2 + 1] = v.y;
      }
    } else {
#pragma unroll
      for (int kk = 0; kk < 8; ++kk) {
        int k = k0 + lg * 8 + kk;
        av[kk] = (k < K) ? ap[kk] : 0.f;
      }
    }
    short8 ah, al;
#pragma unroll
    for (int kk = 0; kk < 8; ++kk) {
      u16 h = f2bf(av[kk]);
      ah[kk] = (short)h;
      al[kk] = (short)f2bf(av[kk] - bf2f(h));
    }
    short8 bh[4], bl[4];
#pragma unroll
    for (int tn = 0; tn < 4; ++tn) {
      size_t o = (size_t)(n0 + tn * 16 + lc) * Kpad + k0 + lg * 8;
      bh[tn] = *(const short8*)(WtH + o);
      bl[tn] = *(const short8*)(WtL + o);
    }
#pragma unroll
    for (int tn = 0; tn < 4; ++tn) {
      acc[tn] = MFMA16(ah, bh[tn], acc[tn]);
      acc[tn] = MFMA16(ah, bl[tn], acc[tn]);
      acc[tn] = MFMA16(al, bh[tn], acc[tn]);
    }
  }
#pragma unroll
  for (int tn = 0; tn < 4; ++tn)
#pragma unroll
    for (int r = 0; r < 4; ++r) {
      size_t row = (size_t)(i0 + wm * 16 + lg * 4 + r);
      float* cp = &C[row * N + n0 + tn * 16 + lc];
      float o = acc[tn][r];
      if (BIAS) o += bias[n0 + tn * 16 + lc];
      if (ACCUM) o += *cp;
      if (RELU) o = fmaxf(o, 0.f);
      *cp = o;
    }
}

// =====================================================================
// wdvec[t] = Wd[t] @ a_d[t], wsvec[t] = Ws[t] @ a_s[t]
// =====================================================================
__global__ void wvec_k(const float* __restrict__ Wd, const float* __restrict__ ad,
                       const float* __restrict__ Ws, const float* __restrict__ as_,
                       float* __restrict__ wdv, float* __restrict__ wsv) {
  int b = blockIdx.x, k = threadIdx.x;
  const float* Wm = (b < 3) ? Wd + (size_t)b * 16384 : Ws + (size_t)(b - 3) * 16384;
  const float* av = (b < 3) ? ad + b * 128 : as_ + (b - 3) * 128;
  float* o = (b < 3) ? wdv + b * 128 : wsv + (b - 3) * 128;
  float s = 0.f;
  for (int c = 0; c < 128; ++c) s = fmaf(Wm[(size_t)k * 128 + c], av[c], s);
  o[k] = s;
}

// =====================================================================
// Row stats: normalized row -> bf16 hi/lo; al_out[v][i] = row . avec[v]
// =====================================================================
__global__ __launch_bounds__(256)
void rownorm2_k(const float* __restrict__ X, u16* __restrict__ XH, u16* __restrict__ XL,
                const float* __restrict__ avecs, int navec,
                float* __restrict__ al_out, int N) {
  int lane = threadIdx.x & 63, wv = threadIdx.x >> 6;
  int i = blockIdx.x * 4 + wv;
  float x0 = X[(size_t)i * 128 + lane];
  float x1 = X[(size_t)i * 128 + 64 + lane];
  float ss = x0 * x0 + x1 * x1;
#pragma unroll
  for (int o = 1; o < 64; o <<= 1) ss += __shfl_xor(ss, o);
  float inv = 1.f / fmaxf(sqrtf(ss), 1e-12f);
  for (int v = 0; v < navec; ++v) {
    float d = x0 * avecs[v * 128 + lane] + x1 * avecs[v * 128 + 64 + lane];
#pragma unroll
    for (int o = 1; o < 64; o <<= 1) d += __shfl_xor(d, o);
    if (lane == 0) al_out[(size_t)v * N + i] = d;
  }
  float n0 = x0 * inv, n1 = x1 * inv;
  u16 h0 = f2bf(n0), h1 = f2bf(n1);
  XH[(size_t)i * 128 + lane]      = h0;
  XH[(size_t)i * 128 + 64 + lane] = h1;
  XL[(size_t)i * 128 + lane]      = f2bf(n0 - bf2f(h0));
  XL[(size_t)i * 128 + 64 + lane] = f2bf(n1 - bf2f(h1));
}

// =====================================================================
// Transpose-convert: hs fp32 [N][128] -> Vt_hi/Vt_lo bf16 [128][N]
// =====================================================================
__global__ __launch_bounds__(256)
void tconv_k(const float* __restrict__ src, u16* __restrict__ dh, u16* __restrict__ dl, int N) {
  __shared__ float tl[64][65];
  const int t = threadIdx.x;
  const int sb = blockIdx.x, fb = blockIdx.y;
#pragma unroll
  for (int l = 0; l < 4; ++l) {
    int i = t + l * 256; int r = i >> 4; int c4 = i & 15;
    *(float4*)&tl[r][c4 * 4] = *(const float4*)&src[(size_t)(sb * 64 + r) * 128 + fb * 64 + c4 * 4];
  }
  __syncthreads();
#pragma unroll
  for (int l = 0; l < 2; ++l) {
    int g = t + l * 256; int f = g >> 3; int s8 = (g & 7) * 8;
    u32 ph[4], pl[4];
#pragma unroll
    for (int k = 0; k < 4; ++k) {
      float a = tl[s8 + 2 * k][f], b = tl[s8 + 2 * k + 1][f];
      u16 ha = f2bf(a), hb = f2bf(b);
      u16 la = f2bf(a - bf2f(ha)), lb = f2bf(b - bf2f(hb));
      ph[k] = (u32)ha | ((u32)hb << 16);
      pl[k] = (u32)la | ((u32)lb << 16);
    }
    size_t o = (size_t)(fb * 64 + f) * N + sb * 64 + s8;
    *(uint4*)&dh[o] = make_uint4(ph[0], ph[1], ph[2], ph[3]);
    *(uint4*)&dl[o] = make_uint4(pl[0], pl[1], pl[2], pl[3]);
  }
}

// =====================================================================
// MFMA flash-GAT v3: 256-thread / 4-wave blocks, 32 authors, in-block
// j-split. wave wm: author-group wm&1 (16 rows), j-half wm>>1 (1024 srcs).
// Grid: 7 chunk-globals x 128 row-blocks = 896 blocks -> 3584 waves.
// Per-wave body identical to the verified round-4 kernel (VGPR=128, no
// spill). __launch_bounds__(256,4): both toolchain interpretations of
// arg2 (waves/EU | blocks/CU) give the same 128-VGPR cap.
// =====================================================================
struct GatP {
  const u16 *qh, *ql;
  const u16 *kh[3], *kl[3];
  const u16 *vh[3], *vl[3];
  const float *als[3];
  const float *ald;            // [3][4096]
  float *pacc;                 // [7][4096][128]
  float *pm;                   // [7][4096]
  float *pl;                   // [7][4096]
};

__global__ __launch_bounds__(256, 4)
void gat_k(GatP P) {
  __shared__ u16 wh[4][16][40];     // per-wave P (hi), padded stride 40
  __shared__ u16 wl_[4][16][40];    // per-wave P (lo)
  __shared__ float mrg[2][16][132]; // j-half-1 acc for merge
  __shared__ float mml[2][2][16];   // j-half-1 m/l

  // XCD-contiguous remap: each XCD owns 112 consecutive work-ids
  const int b = ((blockIdx.x & 7) * 112) + (blockIdx.x >> 3);
  const int cg = b >> 7;            // 0..6
  const int rb = b & 127;           // 32-author row-block
  const int type = (cg < 4) ? 0 : (cg < 6 ? 1 : 2);
  const int chunk = cg - (type == 0 ? 0 : (type == 1 ? 4 : 6));
  const int srcN = (type == 0) ? 8192 : (type == 1 ? 4096 : 2048);
  const u16* KH = P.kh[type]; const u16* KL = P.kl[type];
  const u16* VH = P.vh[type]; const u16* VL = P.vl[type];
  const float* alsg = P.als[type];
  const float* ALD = P.ald + (size_t)type * 4096;
  const int i0 = rb * 32;

  const int t = threadIdx.x;
  const int wm = t >> 6;          // wave 0..3
  const int wq = wm & 1;          // author 16-group
  const int jhalf = wm >> 1;      // 0 or 1
  const int ln = t & 63;
  const int lg = ln >> 4;
  const int lc = ln & 15;
  const int arow0 = i0 + wq * 16;
  const int cj0 = chunk * 2048 + jhalf * 1024;

  // Q fragments (held across all iterations)
  short8 qhf[4], qlf[4];
#pragma unroll
  for (int ks = 0; ks < 4; ++ks) {
    size_t qo = (size_t)(arow0 + lc) * 128 + ks * 32 + lg * 8;
    qhf[ks] = *(const short8*)(P.qh + qo);
    qlf[ks] = *(const short8*)(P.ql + qo);
  }
  float ald_r[4], m[4], lsum[4];
#pragma unroll
  for (int r = 0; r < 4; ++r) {
    ald_r[r] = ALD[arow0 + lg * 4 + r];
    m[r] = -1e30f; lsum[r] = 0.f;
  }
  f32x4 pacc[8];
#pragma unroll
  for (int n = 0; n < 8; ++n) pacc[n] = (f32x4)0.f;

  for (int jt = 0; jt < 32; ++jt) {
    const int j0 = cj0 + jt * 32;
    // ---- K B-frag loads ----
    short8 kbh[2][4], kbl[2][4];
#pragma unroll
    for (int tn = 0; tn < 2; ++tn)
#pragma unroll
      for (int ks = 0; ks < 4; ++ks) {
        size_t ko = (size_t)(j0 + tn * 16 + lc) * 128 + ks * 32 + lg * 8;
        kbh[tn][ks] = *(const short8*)(KH + ko);
        kbl[tn][ks] = *(const short8*)(KL + ko);
      }
    float als0 = alsg[j0 + lc], als1 = alsg[j0 + 16 + lc];
    // ---- S = cos-sim: 3-term split-bf16 MFMA ----
    f32x4 sacc[2];
    sacc[0] = (f32x4)0.f; sacc[1] = (f32x4)0.f;
    __builtin_amdgcn_s_setprio(1);
#pragma unroll
    for (int ks = 0; ks < 4; ++ks)
#pragma unroll
      for (int tn = 0; tn < 2; ++tn) {
        sacc[tn] = MFMA16(qhf[ks], kbh[tn][ks], sacc[tn]);
        sacc[tn] = MFMA16(qhf[ks], kbl[tn][ks], sacc[tn]);
        sacc[tn] = MFMA16(qlf[ks], kbh[tn][ks], sacc[tn]);
      }
    __builtin_amdgcn_s_setprio(0);
    // ---- V B-frag loads (latency hides under softmax) ----
    short8 vbh[8], vbl[8];
#pragma unroll
    for (int tn = 0; tn < 8; ++tn) {
      size_t vo = (size_t)(tn * 16 + lc) * srcN + j0 + lg * 8;
      vbh[tn] = *(const short8*)(VH + vo);
      vbl[tn] = *(const short8*)(VL + vo);
    }
    // ---- mask + leaky + online softmax ----
    float w0s[4], w1s[4], scl[4];
#pragma unroll
    for (int r = 0; r < 4; ++r) {
      int ag = arow0 + lg * 4 + r;
      float z0 = ald_r[r] + als0; z0 = (z0 >= 0.f) ? z0 : NSLOPE * z0;
      float z1 = ald_r[r] + als1; z1 = (z1 >= 0.f) ? z1 : NSLOPE * z1;
      bool a0 = (sacc[0][r] > THRESH) && (j0 + lc != ag);
      bool a1 = (sacc[1][r] > THRESH) && (j0 + 16 + lc != ag);
      float e0 = a0 ? z0 : -1e30f;
      float e1 = a1 ? z1 : -1e30f;
      float rm = fmaxf(e0, e1);
#pragma unroll
      for (int o = 1; o < 16; o <<= 1) rm = fmaxf(rm, __shfl_xor(rm, o));
      float mn = fmaxf(m[r], rm);
      scl[r] = __expf(m[r] - mn);
      m[r] = mn;
      float w0 = (e0 > -1e29f) ? __expf(e0 - mn) : 0.f;
      float w1 = (e1 > -1e29f) ? __expf(e1 - mn) : 0.f;
      float rs = w0 + w1;
#pragma unroll
      for (int o = 1; o < 16; o <<= 1) rs += __shfl_xor(rs, o);
      lsum[r] = lsum[r] * scl[r] + rs;
      w0s[r] = w0; w1s[r] = w1;
    }
    // ---- P transpose via per-wave LDS slice (same-wave, no barrier) ----
#pragma unroll
    for (int r = 0; r < 4; ++r) {
      u16 h0 = f2bf(w0s[r]);
      u16 h1 = f2bf(w1s[r]);
      wh[wm][lg * 4 + r][lc]      = h0;
      wh[wm][lg * 4 + r][16 + lc] = h1;
      wl_[wm][lg * 4 + r][lc]      = f2bf(w0s[r] - bf2f(h0));
      wl_[wm][lg * 4 + r][16 + lc] = f2bf(w1s[r] - bf2f(h1));
    }
#pragma unroll
    for (int n = 0; n < 8; ++n)
#pragma unroll
      for (int r = 0; r < 4; ++r) pacc[n][r] *= scl[r];
    short8 wfh = *(const short8*)&wh[wm][lc][lg * 8];
    short8 wfl = *(const short8*)&wl_[wm][lc][lg * 8];
    // ---- PV: 3-term split-bf16 MFMA ----
    __builtin_amdgcn_s_setprio(1);
#pragma unroll
    for (int n = 0; n < 8; ++n) {
      pacc[n] = MFMA16(wfh, vbh[n], pacc[n]);
      pacc[n] = MFMA16(wfh, vbl[n], pacc[n]);
      pacc[n] = MFMA16(wfl, vbh[n], pacc[n]);
    }
    __builtin_amdgcn_s_setprio(0);
  }
  // ---- in-block flash merge of the two j-halves ----
  if (jhalf == 1) {
#pragma unroll
    for (int n = 0; n < 8; ++n)
#pragma unroll
      for (int r = 0; r < 4; ++r)
        mrg[wq][lg * 4 + r][n * 16 + lc] = pacc[n][r];
    if (lc == 0) {
#pragma unroll
      for (int r = 0; r < 4; ++r) {
        mml[wq][0][lg * 4 + r] = m[r];
        mml[wq][1][lg * 4 + r] = lsum[r];
      }
    }
  }
  __syncthreads();
  if (jhalf == 0) {
#pragma unroll
    for (int r = 0; r < 4; ++r) {
      float mu = mml[wq][0][lg * 4 + r];
      float lu = mml[wq][1][lg * 4 + r];
      float M = fmaxf(m[r], mu);
      float sA = __expf(m[r] - M);
      float sB = __expf(mu - M);
      lsum[r] = lsum[r] * sA + lu * sB;
      m[r] = M;
#pragma unroll
      for (int n = 0; n < 8; ++n)
        pacc[n][r] = pacc[n][r] * sA + mrg[wq][lg * 4 + r][n * 16 + lc] * sB;
    }
#pragma unroll
    for (int n = 0; n < 8; ++n)
#pragma unroll
      for (int r = 0; r < 4; ++r) {
        size_t row = (size_t)(arow0 + lg * 4 + r);
        P.pacc[(size_t)cg * 524288 + row * 128 + n * 16 + lc] = pacc[n][r];
      }
    if (lc == 0) {
#pragma unroll
      for (int r = 0; r < 4; ++r) {
        size_t row = (size_t)(arow0 + lg * 4 + r);
        P.pm[(size_t)cg * 4096 + row] = m[r];
        P.pl[(size_t)cg * 4096 + row] = lsum[r];
      }
    }
  }
}

// =====================================================================
// Merge flash partials (7 chunks: paper 4, term 2, conf 1)
// =====================================================================
__global__ __launch_bounds__(256)
void gatmerge_k(const float* __restrict__ pacc, const float* __restrict__ pm,
                const float* __restrict__ pl, const float* __restrict__ gatb,
                float* __restrict__ out0, float* __restrict__ out1, float* __restrict__ out2) {
  int type = blockIdx.y;
  int nc = (type == 0) ? 4 : (type == 1 ? 2 : 1);
  int cb = (type == 0) ? 0 : (type == 1 ? 4 : 6);
  float* OUT = (type == 0) ? out0 : (type == 1 ? out1 : out2);
  int idx = blockIdx.x * 256 + threadIdx.x;
  int i = idx >> 7, c = idx & 127;
  float M = -1e30f;
  for (int ch = 0; ch < nc; ++ch) M = fmaxf(M, pm[(size_t)(cb + ch) * 4096 + i]);
  float num = 0.f, den = 0.f;
  for (int ch = 0; ch < nc; ++ch) {
    float sc = __expf(pm[(size_t)(cb + ch) * 4096 + i] - M);
    den += pl[(size_t)(cb + ch) * 4096 + i] * sc;
    num += pacc[(size_t)(cb + ch) * 524288 + idx] * sc;
  }
  float bv = gatb[(size_t)type * 128 + c];
  OUT[idx] = (den > 0.f) ? num / den + bv : bv;
}

// =====================================================================
// AttentionInfo + SAGE pieces
// =====================================================================
__global__ __launch_bounds__(256)
void attred_k(const float* __restrict__ satt, const float* __restrict__ atts,
              float* __restrict__ scp) {
  int v = blockIdx.y;
  const float* S = satt + (size_t)v * 262144;
  const float* av = atts + v * 64;
  float local = 0.f;
  for (int idx = blockIdx.x * 256 + threadIdx.x; idx < 262144; idx += 32 * 256) {
    float x = S[idx];
    local += av[idx & 63] / (1.f + __expf(-x));
  }
#pragma unroll
  for (int o = 1; o < 64; o <<= 1) local += __shfl_xor(local, o);
  __shared__ float red[4];
  if ((threadIdx.x & 63) == 0) red[threadIdx.x >> 6] = local;
  __syncthreads();
  if (threadIdx.x == 0) atomicAdd(&scp[v], red[0] + red[1] + red[2] + red[3]);
}

__global__ void alpha_k(const float* __restrict__ scp, float* __restrict__ alp) {
  if (threadIdx.x == 0) {
    float s0 = scp[0] * (1.f / 4096.f), s1 = scp[1] * (1.f / 4096.f);
    float s2 = scp[2] * (1.f / 4096.f), s3 = scp[3] * (1.f / 4096.f);
    float mx = fmaxf(fmaxf(s0, s1), fmaxf(s2, s3));
    float e0 = __expf(s0 - mx), e1 = __expf(s1 - mx);
    float e2 = __expf(s2 - mx), e3 = __expf(s3 - mx);
    float d = e0 + e1 + e2 + e3;
    alp[0] = e0 / d; alp[1] = e1 / d; alp[2] = e2 / d; alp[3] = e3 / d;
  }
}

__global__ __launch_bounds__(256)
void xatt_k(const float* __restrict__ h0, const float* __restrict__ h1,
            const float* __restrict__ h2, const float* __restrict__ xt,
            const float* __restrict__ alp, float* __restrict__ out) {
  int idx = blockIdx.x * 256 + threadIdx.x;
  out[idx] = alp[0] * h0[idx] + alp[1] * h1[idx] + alp[2] * h2[idx] + alp[3] * xt[idx];
}

__global__ __launch_bounds__(256)
void scatter_deg_k(const int* __restrict__ dst, float* __restrict__ deg, int E) {
  int e = blockIdx.x * 256 + threadIdx.x;
  if (e < E) atomicAdd(&deg[dst[e]], 1.0f);
}

__global__ __launch_bounds__(256)
void scatter_add_k(const float* __restrict__ H, const int* __restrict__ src,
                   const int* __restrict__ dst, float* __restrict__ agg,
                   int E, int F, int fshift) {
  int idx = blockIdx.x * 256 + threadIdx.x;
  int e = idx >> fshift;
  int f = idx & (F - 1);
  if (e < E) atomicAdd(&agg[(size_t)dst[e] * F + f], H[(size_t)src[e] * F + f]);
}

__global__ __launch_bounds__(256)
void aggnorm_k(float* __restrict__ agg, const float* __restrict__ deg) {
  int idx = blockIdx.x * 256 + threadIdx.x;
  agg[idx] *= 1.f / fmaxf(deg[idx >> 7], 1.f);
}

__global__ __launch_bounds__(256)
void finaladd_k(float* __restrict__ out, const float* __restrict__ agg2,
                const float* __restrict__ deg) {
  int idx = blockIdx.x * 256 + threadIdx.x;
  out[idx] += agg2[idx] / fmaxf(deg[idx >> 6], 1.f);
}

// =====================================================================
// Launch. Workspace ~44.1 MB (< 45.4 MB empirical bound).
// =====================================================================
extern "C" void kernel_launch(void* const* d_in, const int* in_sizes, int n_in,
                              void* d_out, int out_size, void* d_ws, size_t ws_size,
                              hipStream_t stream) {
  const float* xma = (const float*)d_in[0];
  const float* xmp = (const float*)d_in[1];
  const float* xmt = (const float*)d_in[2];
  const float* xmc = (const float*)d_in[3];
  const float* xia = (const float*)d_in[4];
  const int*   ei  = (const int*)  d_in[5];
  const float* Wla = (const float*)d_in[6];  const float* bla = (const float*)d_in[7];
  const float* Wlp = (const float*)d_in[8];  const float* blp = (const float*)d_in[9];
  const float* Wlt = (const float*)d_in[10]; const float* blt = (const float*)d_in[11];
  const float* Wlc = (const float*)d_in[12]; const float* blc = (const float*)d_in[13];
  const float* Wtg = (const float*)d_in[14]; const float* btg = (const float*)d_in[15];
  const float* gWs = (const float*)d_in[16];
  const float* gWd = (const float*)d_in[17];
  const float* gas = (const float*)d_in[18];
  const float* gad = (const float*)d_in[19];
  const float* gb  = (const float*)d_in[20];
  const float* Watt = (const float*)d_in[21];
  const float* atts = (const float*)d_in[22];
  const float* W1l = (const float*)d_in[23]; const float* b1 = (const float*)d_in[24];
  const float* W1r = (const float*)d_in[25];
  const float* W2l = (const float*)d_in[26]; const float* b2 = (const float*)d_in[27];
  const float* W2r = (const float*)d_in[28];
  (void)in_sizes; (void)n_in; (void)out_size; (void)ws_size;

  float* ws = (float*)d_ws;
  size_t off = 0;
  auto alloc = [&](size_t n) { float* p = ws + off; off += n; return p; };
  float* h_a = alloc(524288);
  float* x_t = alloc(524288);
  float* Pr  = alloc(3670016);            // multi-life region
  // early aliases
  float* h_p  = Pr;
  float* h_t  = Pr + 1048576;
  float* h_c  = Pr + 1572864;
  float* hs_p = Pr + 1835008;
  float* hs_t = Pr + 2883584;
  float* hs_c = Pr + 3407872;
  // mid alias
  float* pacc = Pr;
  // late aliases
  float* satt = Pr;
  float* h1   = Pr + 1048576;
  float* p2   = Pr + 2097152;
  float* deg  = Pr + 2359296;
  float* agg1 = Pr + 2363392;
  float* agg2 = Pr + 2887680;
  // bf16 hi/lo K/V buffers
  u16* qn_h   = (u16*)alloc(4096 * 64);
  u16* qn_l   = (u16*)alloc(4096 * 64);
  u16* kn_p_h = (u16*)alloc(8192 * 64);
  u16* kn_p_l = (u16*)alloc(8192 * 64);
  u16* kn_t_h = (u16*)alloc(4096 * 64);
  u16* kn_t_l = (u16*)alloc(4096 * 64);
  u16* kn_c_h = (u16*)alloc(2048 * 64);
  u16* kn_c_l = (u16*)alloc(2048 * 64);
  u16* vt_p_h = (u16*)alloc(8192 * 64);
  u16* vt_p_l = (u16*)alloc(8192 * 64);
  u16* vt_t_h = (u16*)alloc(4096 * 64);
  u16* vt_t_l = (u16*)alloc(4096 * 64);
  u16* vt_c_h = (u16*)alloc(2048 * 64);
  u16* vt_c_l = (u16*)alloc(2048 * 64);
  // converted weights [N][Kpad] hi/lo
  u16* wla_h = (u16*)alloc(43008); u16* wla_l = (u16*)alloc(43008);
  u16* wlp_h = (u16*)alloc(65536); u16* wlp_l = (u16*)alloc(65536);
  u16* wlt_h = (u16*)alloc(16384); u16* wlt_l = (u16*)alloc(16384);
  u16* wlc_h = (u16*)alloc(8192);  u16* wlc_l = (u16*)alloc(8192);
  u16* wtg_h = (u16*)alloc(22528); u16* wtg_l = (u16*)alloc(22528);
  u16* wws_h = (u16*)alloc(24576); u16* wws_l = (u16*)alloc(24576);
  u16* wat_h = (u16*)alloc(4096);  u16* wat_l = (u16*)alloc(4096);
  u16* w1l_h = (u16*)alloc(16384); u16* w1l_l = (u16*)alloc(16384);
  u16* w1r_h = (u16*)alloc(16384); u16* w1r_l = (u16*)alloc(16384);
  u16* w2l_h = (u16*)alloc(8192);  u16* w2l_l = (u16*)alloc(8192);
  u16* w2r_h = (u16*)alloc(8192);  u16* w2r_l = (u16*)alloc(8192);
  float* ald   = alloc(3 * 4096);
  float* als_p = alloc(8192);
  float* als_t = alloc(4096);
  float* als_c = alloc(2048);
  float* wdv   = alloc(3 * 128);
  float* wsv   = alloc(3 * 128);
  float* het0  = alloc(524288);
  float* het1  = alloc(524288);
  float* het2  = alloc(524288);
  float* pm    = alloc(7 * 4096);
  float* pl    = alloc(7 * 4096);
  float* scp   = alloc(16);
  float* alp   = alloc(16);

  hipMemsetAsync(scp, 0, 32 * sizeof(float), stream);   // scp + alp

  dim3 blk(256);
  // ---- weight conversions ----
  wconv_k<<<dim3(11, 2), blk, 0, stream>>>(Wla, wla_h, wla_l, 668, 672, 128);
  wconv_k<<<dim3(16, 2), blk, 0, stream>>>(Wlp, wlp_h, wlp_l, 1024, 1024, 128);
  wconv_k<<<dim3(4, 2),  blk, 0, stream>>>(Wlt, wlt_h, wlt_l, 256, 256, 128);
  wconv_k<<<dim3(2, 2),  blk, 0, stream>>>(Wlc, wlc_h, wlc_l, 128, 128, 128);
  wconv_k<<<dim3(6, 2),  blk, 0, stream>>>(Wtg, wtg_h, wtg_l, 334, 352, 128);
  for (int i = 0; i < 3; ++i)
    wconv_k<<<dim3(2, 2), blk, 0, stream>>>(gWs + (size_t)i * 16384, wws_h + i * 16384, wws_l + i * 16384, 128, 128, 128);
  wconv_k<<<dim3(2, 1), blk, 0, stream>>>(Watt, wat_h, wat_l, 128, 128, 64);
  wconv_k<<<dim3(2, 4), blk, 0, stream>>>(W1l, w1l_h, w1l_l, 128, 128, 256);
  wconv_k<<<dim3(2, 4), blk, 0, stream>>>(W1r, w1r_h, w1r_l, 128, 128, 256);
  wconv_k<<<dim3(4, 1), blk, 0, stream>>>(W2l, w2l_h, w2l_l, 256, 256, 64);
  wconv_k<<<dim3(4, 1), blk, 0, stream>>>(W2r, w2r_h, w2r_l, 256, 256, 64);
  // ---- dimension transforms (MFMA) ----
  mgemm_k<1, 0, 0><<<dim3(64, 2),  blk, 0, stream>>>(xma, wla_h, wla_l, bla, h_a, 4096, 668, 672, 128);
  mgemm_k<1, 0, 0><<<dim3(128, 2), blk, 0, stream>>>(xmp, wlp_h, wlp_l, blp, h_p, 8192, 1024, 1024, 128);
  mgemm_k<1, 0, 0><<<dim3(64, 2),  blk, 0, stream>>>(xmt, wlt_h, wlt_l, blt, h_t, 4096, 256, 256, 128);
  mgemm_k<1, 0, 0><<<dim3(32, 2),  blk, 0, stream>>>(xmc, wlc_h, wlc_l, blc, h_c, 2048, 128, 128, 128);
  mgemm_k<1, 0, 0><<<dim3(64, 2),  blk, 0, stream>>>(xia, wtg_h, wtg_l, btg, x_t, 4096, 334, 352, 128);
  // ---- GAT precompute ----
  mgemm_k<0, 0, 0><<<dim3(128, 2), blk, 0, stream>>>(h_p, wws_h + 0 * 16384, wws_l + 0 * 16384, nullptr, hs_p, 8192, 128, 128, 128);
  mgemm_k<0, 0, 0><<<dim3(64, 2),  blk, 0, stream>>>(h_t, wws_h + 1 * 16384, wws_l + 1 * 16384, nullptr, hs_t, 4096, 128, 128, 128);
  mgemm_k<0, 0, 0><<<dim3(32, 2),  blk, 0, stream>>>(h_c, wws_h + 2 * 16384, wws_l + 2 * 16384, nullptr, hs_c, 2048, 128, 128, 128);
  wvec_k<<<dim3(6), dim3(128), 0, stream>>>(gWd, gad, gWs, gas, wdv, wsv);
  rownorm2_k<<<dim3(1024), blk, 0, stream>>>(h_a, qn_h, qn_l, wdv, 3, ald, 4096);
  rownorm2_k<<<dim3(2048), blk, 0, stream>>>(h_p, kn_p_h, kn_p_l, wsv + 0,   1, als_p, 8192);
  rownorm2_k<<<dim3(1024), blk, 0, stream>>>(h_t, kn_t_h, kn_t_l, wsv + 128, 1, als_t, 4096);
  rownorm2_k<<<dim3(512),  blk, 0, stream>>>(h_c, kn_c_h, kn_c_l, wsv + 256, 1, als_c, 2048);
  tconv_k<<<dim3(128, 2), blk, 0, stream>>>(hs_p, vt_p_h, vt_p_l, 8192);
  tconv_k<<<dim3(64, 2),  blk, 0, stream>>>(hs_t, vt_t_h, vt_t_l, 4096);
  tconv_k<<<dim3(32, 2),  blk, 0, stream>>>(hs_c, vt_c_h, vt_c_l, 2048);
  // ---- MFMA flash-GAT + merge ----
  GatP gp;
  gp.qh = qn_h; gp.ql = qn_l;
  gp.kh[0] = kn_p_h; gp.kh[1] = kn_t_h; gp.kh[2] = kn_c_h;
  gp.kl[0] = kn_p_l; gp.kl[1] = kn_t_l; gp.kl[2] = kn_c_l;
  gp.vh[0] = vt_p_h; gp.vh[1] = vt_t_h; gp.vh[2] = vt_c_h;
  gp.vl[0] = vt_p_l; gp.vl[1] = vt_t_l; gp.vl[2] = vt_c_l;
  gp.als[0] = als_p; gp.als[1] = als_t; gp.als[2] = als_c;
  gp.ald = ald; gp.pacc = pacc; gp.pm = pm; gp.pl = pl;
  gat_k<<<dim3(896), blk, 0, stream>>>(gp);
  gatmerge_k<<<dim3(2048, 3), blk, 0, stream>>>(pacc, pm, pl, gb, het0, het1, het2);
  // pacc dead -> zero late-alias SAGE buffers (deg, agg1, agg2)
  hipMemsetAsync(deg, 0, (size_t)790528 * sizeof(float), stream);
  // ---- AttentionInfo ----
  mgemm_k<0, 0, 0><<<dim3(64, 1), blk, 0, stream>>>(het0, wat_h, wat_l, nullptr, satt + 0 * 262144, 4096, 128, 128, 64);
  mgemm_k<0, 0, 0><<<dim3(64, 1), blk, 0, stream>>>(het1, wat_h, wat_l, nullptr, satt + 1 * 262144, 4096, 128, 128, 64);
  mgemm_k<0, 0, 0><<<dim3(64, 1), blk, 0, stream>>>(het2, wat_h, wat_l, nullptr, satt + 2 * 262144, 4096, 128, 128, 64);
  mgemm_k<0, 0, 0><<<dim3(64, 1), blk, 0, stream>>>(x_t,  wat_h, wat_l, nullptr, satt + 3 * 262144, 4096, 128, 128, 64);
  attred_k<<<dim3(32, 4), blk, 0, stream>>>(satt, atts, scp);
  alpha_k<<<dim3(1), dim3(64), 0, stream>>>(scp, alp);
  xatt_k<<<dim3(2048), blk, 0, stream>>>(het0, het1, het2, x_t, alp, (float*)d_out + 262144);
  // ---- GraphSAGE ----
  const int E = 131072;
  const int* esrc = ei;
  const int* edst = ei + E;
  scatter_deg_k<<<dim3(512), blk, 0, stream>>>(edst, deg, E);
  scatter_add_k<<<dim3(65536), blk, 0, stream>>>(h_a, esrc, edst, agg1, E, 128, 7);
  aggnorm_k<<<dim3(2048), blk, 0, stream>>>(agg1, deg);
  mgemm_k<1, 0, 0><<<dim3(64, 4), blk, 0, stream>>>(agg1, w1l_h, w1l_l, b1, h1, 4096, 128, 128, 256);
  mgemm_k<0, 1, 1><<<dim3(64, 4), blk, 0, stream>>>(h_a, w1r_h, w1r_l, nullptr, h1, 4096, 128, 128, 256);
  mgemm_k<0, 0, 0><<<dim3(64, 1), blk, 0, stream>>>(h1, w2l_h, w2l_l, nullptr, p2, 4096, 256, 256, 64);
  scatter_add_k<<<dim3(32768), blk, 0, stream>>>(p2, esrc, edst, agg2, E, 64, 6);
  mgemm_k<1, 0, 0><<<dim3(64, 1), blk, 0, stream>>>(h1, w2r_h, w2r_l, b2, (float*)d_out, 4096, 256, 256, 64);
  finaladd_k<<<dim3(1024), blk, 0, stream>>>((float*)d_out, agg2, deg);
}

// Round 7
// 987.374 us; speedup vs baseline: 1.5479x; 1.2894x over previous
//
#include <hip/hip_runtime.h>
#include <math.h>

#define THRESH 0.1f
#define NSLOPE 0.2f

typedef __attribute__((ext_vector_type(8))) short short8;
typedef __attribute__((ext_vector_type(4))) float f32x4;
typedef unsigned short u16;
typedef unsigned int u32;

#define MFMA16(a, b, c) __builtin_amdgcn_mfma_f32_16x16x32_bf16(a, b, c, 0, 0, 0)

__device__ inline u16 f2bf(float x) {
  u32 u = __float_as_uint(x);
  u += 0x7FFF + ((u >> 16) & 1);
  return (u16)(u >> 16);
}
__device__ inline float bf2f(u16 h) { return __uint_as_float((u32)h << 16); }

// =====================================================================
// Weight transpose-convert: W [K][N] fp32 -> WtH/WtL [N][Kpad] bf16 hi/lo
// =====================================================================
__global__ __launch_bounds__(256)
void wconv_k(const float* __restrict__ W, u16* __restrict__ dh, u16* __restrict__ dl,
             int K, int Kpad, int N) {
  __shared__ float tl[64][65];
  const int t = threadIdx.x;
  const int k0 = blockIdx.x * 64, n0 = blockIdx.y * 64;
#pragma unroll
  for (int l = 0; l < 4; ++l) {
    int i = t + l * 256; int r = i >> 4; int c4 = i & 15;
    float4 v = make_float4(0.f, 0.f, 0.f, 0.f);
    if (k0 + r < K) v = *(const float4*)&W[(size_t)(k0 + r) * N + n0 + c4 * 4];
    *(float4*)&tl[r][c4 * 4] = v;
  }
  __syncthreads();
#pragma unroll
  for (int l = 0; l < 2; ++l) {
    int g = t + l * 256; int f = g >> 3; int s8 = (g & 7) * 8;
    if (k0 + s8 >= Kpad) continue;
    u32 ph[4], pl[4];
#pragma unroll
    for (int k = 0; k < 4; ++k) {
      float a = tl[s8 + 2 * k][f], b = tl[s8 + 2 * k + 1][f];
      u16 ha = f2bf(a), hb = f2bf(b);
      u16 la = f2bf(a - bf2f(ha)), lb = f2bf(b - bf2f(hb));
      ph[k] = (u32)ha | ((u32)hb << 16);
      pl[k] = (u32)la | ((u32)lb << 16);
    }
    size_t o = (size_t)(n0 + f) * Kpad + k0 + s8;
    *(uint4*)&dh[o] = make_uint4(ph[0], ph[1], ph[2], ph[3]);
    *(uint4*)&dl[o] = make_uint4(pl[0], pl[1], pl[2], pl[3]);
  }
}

// =====================================================================
// Split-bf16 MFMA GEMM (verified round 5/6)
// =====================================================================
template<int BIAS, int ACCUM, int RELU>
__global__ __launch_bounds__(256)
void mgemm_k(const float* __restrict__ A, const u16* __restrict__ WtH,
             const u16* __restrict__ WtL, const float* __restrict__ bias,
             float* C, int M, int K, int Kpad, int N) {
  const int t = threadIdx.x, wm = t >> 6, ln = t & 63;
  const int lg = ln >> 4, lc = ln & 15;
  const int i0 = blockIdx.x * 64, n0 = blockIdx.y * 64;
  const int arow = i0 + wm * 16 + lc;
  f32x4 acc[4];
#pragma unroll
  for (int tn = 0; tn < 4; ++tn) acc[tn] = (f32x4)0.f;

  for (int k0 = 0; k0 < K; k0 += 32) {
    float av[8];
    const float* ap = A + (size_t)arow * K + k0 + lg * 8;
    if (k0 + 32 <= K) {
#pragma unroll
      for (int q = 0; q < 4; ++q) {
        float2 v = *(const float2*)(ap + q * 2);
        av[q * 2] = v.x; av[q * 2 + 1] = v.y;
      }
    } else {
#pragma unroll
      for (int kk = 0; kk < 8; ++kk) {
        int k = k0 + lg * 8 + kk;
        av[kk] = (k < K) ? ap[kk] : 0.f;
      }
    }
    short8 ah, al;
#pragma unroll
    for (int kk = 0; kk < 8; ++kk) {
      u16 h = f2bf(av[kk]);
      ah[kk] = (short)h;
      al[kk] = (short)f2bf(av[kk] - bf2f(h));
    }
    short8 bh[4], bl[4];
#pragma unroll
    for (int tn = 0; tn < 4; ++tn) {
      size_t o = (size_t)(n0 + tn * 16 + lc) * Kpad + k0 + lg * 8;
      bh[tn] = *(const short8*)(WtH + o);
      bl[tn] = *(const short8*)(WtL + o);
    }
#pragma unroll
    for (int tn = 0; tn < 4; ++tn) {
      acc[tn] = MFMA16(ah, bh[tn], acc[tn]);
      acc[tn] = MFMA16(ah, bl[tn], acc[tn]);
      acc[tn] = MFMA16(al, bh[tn], acc[tn]);
    }
  }
#pragma unroll
  for (int tn = 0; tn < 4; ++tn)
#pragma unroll
    for (int r = 0; r < 4; ++r) {
      size_t row = (size_t)(i0 + wm * 16 + lg * 4 + r);
      float* cp = &C[row * N + n0 + tn * 16 + lc];
      float o = acc[tn][r];
      if (BIAS) o += bias[n0 + tn * 16 + lc];
      if (ACCUM) o += *cp;
      if (RELU) o = fmaxf(o, 0.f);
      *cp = o;
    }
}

// =====================================================================
// wdvec[t] = Wd[t] @ a_d[t], wsvec[t] = Ws[t] @ a_s[t]
// =====================================================================
__global__ void wvec_k(const float* __restrict__ Wd, const float* __restrict__ ad,
                       const float* __restrict__ Ws, const float* __restrict__ as_,
                       float* __restrict__ wdv, float* __restrict__ wsv) {
  int b = blockIdx.x, k = threadIdx.x;
  const float* Wm = (b < 3) ? Wd + (size_t)b * 16384 : Ws + (size_t)(b - 3) * 16384;
  const float* av = (b < 3) ? ad + b * 128 : as_ + (b - 3) * 128;
  float* o = (b < 3) ? wdv + b * 128 : wsv + (b - 3) * 128;
  float s = 0.f;
  for (int c = 0; c < 128; ++c) s = fmaf(Wm[(size_t)k * 128 + c], av[c], s);
  o[k] = s;
}

// =====================================================================
// Row stats: normalized row -> bf16 hi/lo; al_out[v][i] = row . avec[v]
// =====================================================================
__global__ __launch_bounds__(256)
void rownorm2_k(const float* __restrict__ X, u16* __restrict__ XH, u16* __restrict__ XL,
                const float* __restrict__ avecs, int navec,
                float* __restrict__ al_out, int N) {
  int lane = threadIdx.x & 63, wv = threadIdx.x >> 6;
  int i = blockIdx.x * 4 + wv;
  float x0 = X[(size_t)i * 128 + lane];
  float x1 = X[(size_t)i * 128 + 64 + lane];
  float ss = x0 * x0 + x1 * x1;
#pragma unroll
  for (int o = 1; o < 64; o <<= 1) ss += __shfl_xor(ss, o);
  float inv = 1.f / fmaxf(sqrtf(ss), 1e-12f);
  for (int v = 0; v < navec; ++v) {
    float d = x0 * avecs[v * 128 + lane] + x1 * avecs[v * 128 + 64 + lane];
#pragma unroll
    for (int o = 1; o < 64; o <<= 1) d += __shfl_xor(d, o);
    if (lane == 0) al_out[(size_t)v * N + i] = d;
  }
  float n0 = x0 * inv, n1 = x1 * inv;
  u16 h0 = f2bf(n0), h1 = f2bf(n1);
  XH[(size_t)i * 128 + lane]      = h0;
  XH[(size_t)i * 128 + 64 + lane] = h1;
  XL[(size_t)i * 128 + lane]      = f2bf(n0 - bf2f(h0));
  XL[(size_t)i * 128 + 64 + lane] = f2bf(n1 - bf2f(h1));
}

// =====================================================================
// Transpose-convert: hs fp32 [N][128] -> Vt_hi/Vt_lo bf16 [128][N]
// =====================================================================
__global__ __launch_bounds__(256)
void tconv_k(const float* __restrict__ src, u16* __restrict__ dh, u16* __restrict__ dl, int N) {
  __shared__ float tl[64][65];
  const int t = threadIdx.x;
  const int sb = blockIdx.x, fb = blockIdx.y;
#pragma unroll
  for (int l = 0; l < 4; ++l) {
    int i = t + l * 256; int r = i >> 4; int c4 = i & 15;
    *(float4*)&tl[r][c4 * 4] = *(const float4*)&src[(size_t)(sb * 64 + r) * 128 + fb * 64 + c4 * 4];
  }
  __syncthreads();
#pragma unroll
  for (int l = 0; l < 2; ++l) {
    int g = t + l * 256; int f = g >> 3; int s8 = (g & 7) * 8;
    u32 ph[4], pl[4];
#pragma unroll
    for (int k = 0; k < 4; ++k) {
      float a = tl[s8 + 2 * k][f], b = tl[s8 + 2 * k + 1][f];
      u16 ha = f2bf(a), hb = f2bf(b);
      u16 la = f2bf(a - bf2f(ha)), lb = f2bf(b - bf2f(hb));
      ph[k] = (u32)ha | ((u32)hb << 16);
      pl[k] = (u32)la | ((u32)lb << 16);
    }
    size_t o = (size_t)(fb * 64 + f) * N + sb * 64 + s8;
    *(uint4*)&dh[o] = make_uint4(ph[0], ph[1], ph[2], ph[3]);
    *(uint4*)&dl[o] = make_uint4(pl[0], pl[1], pl[2], pl[3]);
  }
}

// =====================================================================
// MFMA flash-GAT v4: identical structure to round 6 (4-wave/32-author
// blocks, in-block j-split flash merge) but with plain
// __launch_bounds__(256). EMPIRICAL TOOLCHAIN LESSON (R4/R5/R6):
//   __launch_bounds__(256)    -> VGPR=128, no spill  (R4: 482us @ 1.75 w/SIMD)
//   __launch_bounds__(*, 4)   -> VGPR=64, 1.4 GB scratch spill (R5/R6: 770us)
// Never pass the second arg for this kernel.
// =====================================================================
struct GatP {
  const u16 *qh, *ql;
  const u16 *kh[3], *kl[3];
  const u16 *vh[3], *vl[3];
  const float *als[3];
  const float *ald;            // [3][4096]
  float *pacc;                 // [7][4096][128]
  float *pm;                   // [7][4096]
  float *pl;                   // [7][4096]
};

__global__ __launch_bounds__(256)
void gat_k(GatP P) {
  __shared__ u16 wh[4][16][40];     // per-wave P (hi), padded stride 40
  __shared__ u16 wl_[4][16][40];    // per-wave P (lo)
  __shared__ float mrg[2][16][132]; // j-half-1 acc for merge
  __shared__ float mml[2][2][16];   // j-half-1 m/l

  // XCD-contiguous remap: each XCD owns 112 consecutive work-ids
  const int b = ((blockIdx.x & 7) * 112) + (blockIdx.x >> 3);
  const int cg = b >> 7;            // 0..6
  const int rb = b & 127;           // 32-author row-block
  const int type = (cg < 4) ? 0 : (cg < 6 ? 1 : 2);
  const int chunk = cg - (type == 0 ? 0 : (type == 1 ? 4 : 6));
  const int srcN = (type == 0) ? 8192 : (type == 1 ? 4096 : 2048);
  const u16* KH = P.kh[type]; const u16* KL = P.kl[type];
  const u16* VH = P.vh[type]; const u16* VL = P.vl[type];
  const float* alsg = P.als[type];
  const float* ALD = P.ald + (size_t)type * 4096;
  const int i0 = rb * 32;

  const int t = threadIdx.x;
  const int wm = t >> 6;          // wave 0..3
  const int wq = wm & 1;          // author 16-group
  const int jhalf = wm >> 1;      // 0 or 1
  const int ln = t & 63;
  const int lg = ln >> 4;
  const int lc = ln & 15;
  const int arow0 = i0 + wq * 16;
  const int cj0 = chunk * 2048 + jhalf * 1024;

  // Q fragments (held across all iterations)
  short8 qhf[4], qlf[4];
#pragma unroll
  for (int ks = 0; ks < 4; ++ks) {
    size_t qo = (size_t)(arow0 + lc) * 128 + ks * 32 + lg * 8;
    qhf[ks] = *(const short8*)(P.qh + qo);
    qlf[ks] = *(const short8*)(P.ql + qo);
  }
  float ald_r[4], m[4], lsum[4];
#pragma unroll
  for (int r = 0; r < 4; ++r) {
    ald_r[r] = ALD[arow0 + lg * 4 + r];
    m[r] = -1e30f; lsum[r] = 0.f;
  }
  f32x4 pacc[8];
#pragma unroll
  for (int n = 0; n < 8; ++n) pacc[n] = (f32x4)0.f;

  for (int jt = 0; jt < 32; ++jt) {
    const int j0 = cj0 + jt * 32;
    // ---- K B-frag loads ----
    short8 kbh[2][4], kbl[2][4];
#pragma unroll
    for (int tn = 0; tn < 2; ++tn)
#pragma unroll
      for (int ks = 0; ks < 4; ++ks) {
        size_t ko = (size_t)(j0 + tn * 16 + lc) * 128 + ks * 32 + lg * 8;
        kbh[tn][ks] = *(const short8*)(KH + ko);
        kbl[tn][ks] = *(const short8*)(KL + ko);
      }
    float als0 = alsg[j0 + lc], als1 = alsg[j0 + 16 + lc];
    // ---- S = cos-sim: 3-term split-bf16 MFMA ----
    f32x4 sacc[2];
    sacc[0] = (f32x4)0.f; sacc[1] = (f32x4)0.f;
    __builtin_amdgcn_s_setprio(1);
#pragma unroll
    for (int ks = 0; ks < 4; ++ks)
#pragma unroll
      for (int tn = 0; tn < 2; ++tn) {
        sacc[tn] = MFMA16(qhf[ks], kbh[tn][ks], sacc[tn]);
        sacc[tn] = MFMA16(qhf[ks], kbl[tn][ks], sacc[tn]);
        sacc[tn] = MFMA16(qlf[ks], kbh[tn][ks], sacc[tn]);
      }
    __builtin_amdgcn_s_setprio(0);
    // ---- V B-frag loads (latency hides under softmax) ----
    short8 vbh[8], vbl[8];
#pragma unroll
    for (int tn = 0; tn < 8; ++tn) {
      size_t vo = (size_t)(tn * 16 + lc) * srcN + j0 + lg * 8;
      vbh[tn] = *(const short8*)(VH + vo);
      vbl[tn] = *(const short8*)(VL + vo);
    }
    // ---- mask + leaky + online softmax ----
    float w0s[4], w1s[4], scl[4];
#pragma unroll
    for (int r = 0; r < 4; ++r) {
      int ag = arow0 + lg * 4 + r;
      float z0 = ald_r[r] + als0; z0 = (z0 >= 0.f) ? z0 : NSLOPE * z0;
      float z1 = ald_r[r] + als1; z1 = (z1 >= 0.f) ? z1 : NSLOPE * z1;
      bool a0 = (sacc[0][r] > THRESH) && (j0 + lc != ag);
      bool a1 = (sacc[1][r] > THRESH) && (j0 + 16 + lc != ag);
      float e0 = a0 ? z0 : -1e30f;
      float e1 = a1 ? z1 : -1e30f;
      float rm = fmaxf(e0, e1);
#pragma unroll
      for (int o = 1; o < 16; o <<= 1) rm = fmaxf(rm, __shfl_xor(rm, o));
      float mn = fmaxf(m[r], rm);
      scl[r] = __expf(m[r] - mn);
      m[r] = mn;
      float w0 = (e0 > -1e29f) ? __expf(e0 - mn) : 0.f;
      float w1 = (e1 > -1e29f) ? __expf(e1 - mn) : 0.f;
      float rs = w0 + w1;
#pragma unroll
      for (int o = 1; o < 16; o <<= 1) rs += __shfl_xor(rs, o);
      lsum[r] = lsum[r] * scl[r] + rs;
      w0s[r] = w0; w1s[r] = w1;
    }
    // ---- P transpose via per-wave LDS slice (same-wave, no barrier) ----
#pragma unroll
    for (int r = 0; r < 4; ++r) {
      u16 h0 = f2bf(w0s[r]);
      u16 h1 = f2bf(w1s[r]);
      wh[wm][lg * 4 + r][lc]      = h0;
      wh[wm][lg * 4 + r][16 + lc] = h1;
      wl_[wm][lg * 4 + r][lc]      = f2bf(w0s[r] - bf2f(h0));
      wl_[wm][lg * 4 + r][16 + lc] = f2bf(w1s[r] - bf2f(h1));
    }
#pragma unroll
    for (int n = 0; n < 8; ++n)
#pragma unroll
      for (int r = 0; r < 4; ++r) pacc[n][r] *= scl[r];
    short8 wfh = *(const short8*)&wh[wm][lc][lg * 8];
    short8 wfl = *(const short8*)&wl_[wm][lc][lg * 8];
    // ---- PV: 3-term split-bf16 MFMA ----
    __builtin_amdgcn_s_setprio(1);
#pragma unroll
    for (int n = 0; n < 8; ++n) {
      pacc[n] = MFMA16(wfh, vbh[n], pacc[n]);
      pacc[n] = MFMA16(wfh, vbl[n], pacc[n]);
      pacc[n] = MFMA16(wfl, vbh[n], pacc[n]);
    }
    __builtin_amdgcn_s_setprio(0);
  }
  // ---- in-block flash merge of the two j-halves ----
  if (jhalf == 1) {
#pragma unroll
    for (int n = 0; n < 8; ++n)
#pragma unroll
      for (int r = 0; r < 4; ++r)
        mrg[wq][lg * 4 + r][n * 16 + lc] = pacc[n][r];
    if (lc == 0) {
#pragma unroll
      for (int r = 0; r < 4; ++r) {
        mml[wq][0][lg * 4 + r] = m[r];
        mml[wq][1][lg * 4 + r] = lsum[r];
      }
    }
  }
  __syncthreads();
  if (jhalf == 0) {
#pragma unroll
    for (int r = 0; r < 4; ++r) {
      float mu = mml[wq][0][lg * 4 + r];
      float lu = mml[wq][1][lg * 4 + r];
      float M = fmaxf(m[r], mu);
      float sA = __expf(m[r] - M);
      float sB = __expf(mu - M);
      lsum[r] = lsum[r] * sA + lu * sB;
      m[r] = M;
#pragma unroll
      for (int n = 0; n < 8; ++n)
        pacc[n][r] = pacc[n][r] * sA + mrg[wq][lg * 4 + r][n * 16 + lc] * sB;
    }
#pragma unroll
    for (int n = 0; n < 8; ++n)
#pragma unroll
      for (int r = 0; r < 4; ++r) {
        size_t row = (size_t)(arow0 + lg * 4 + r);
        P.pacc[(size_t)cg * 524288 + row * 128 + n * 16 + lc] = pacc[n][r];
      }
    if (lc == 0) {
#pragma unroll
      for (int r = 0; r < 4; ++r) {
        size_t row = (size_t)(arow0 + lg * 4 + r);
        P.pm[(size_t)cg * 4096 + row] = m[r];
        P.pl[(size_t)cg * 4096 + row] = lsum[r];
      }
    }
  }
}

// =====================================================================
// Merge flash partials (7 chunks: paper 4, term 2, conf 1)
// =====================================================================
__global__ __launch_bounds__(256)
void gatmerge_k(const float* __restrict__ pacc, const float* __restrict__ pm,
                const float* __restrict__ pl, const float* __restrict__ gatb,
                float* __restrict__ out0, float* __restrict__ out1, float* __restrict__ out2) {
  int type = blockIdx.y;
  int nc = (type == 0) ? 4 : (type == 1 ? 2 : 1);
  int cb = (type == 0) ? 0 : (type == 1 ? 4 : 6);
  float* OUT = (type == 0) ? out0 : (type == 1 ? out1 : out2);
  int idx = blockIdx.x * 256 + threadIdx.x;
  int i = idx >> 7, c = idx & 127;
  float M = -1e30f;
  for (int ch = 0; ch < nc; ++ch) M = fmaxf(M, pm[(size_t)(cb + ch) * 4096 + i]);
  float num = 0.f, den = 0.f;
  for (int ch = 0; ch < nc; ++ch) {
    float sc = __expf(pm[(size_t)(cb + ch) * 4096 + i] - M);
    den += pl[(size_t)(cb + ch) * 4096 + i] * sc;
    num += pacc[(size_t)(cb + ch) * 524288 + idx] * sc;
  }
  float bv = gatb[(size_t)type * 128 + c];
  OUT[idx] = (den > 0.f) ? num / den + bv : bv;
}

// =====================================================================
// AttentionInfo + SAGE pieces
// =====================================================================
__global__ __launch_bounds__(256)
void attred_k(const float* __restrict__ satt, const float* __restrict__ atts,
              float* __restrict__ scp) {
  int v = blockIdx.y;
  const float* S = satt + (size_t)v * 262144;
  const float* av = atts + v * 64;
  float local = 0.f;
  for (int idx = blockIdx.x * 256 + threadIdx.x; idx < 262144; idx += 32 * 256) {
    float x = S[idx];
    local += av[idx & 63] / (1.f + __expf(-x));
  }
#pragma unroll
  for (int o = 1; o < 64; o <<= 1) local += __shfl_xor(local, o);
  __shared__ float red[4];
  if ((threadIdx.x & 63) == 0) red[threadIdx.x >> 6] = local;
  __syncthreads();
  if (threadIdx.x == 0) atomicAdd(&scp[v], red[0] + red[1] + red[2] + red[3]);
}

__global__ void alpha_k(const float* __restrict__ scp, float* __restrict__ alp) {
  if (threadIdx.x == 0) {
    float s0 = scp[0] * (1.f / 4096.f), s1 = scp[1] * (1.f / 4096.f);
    float s2 = scp[2] * (1.f / 4096.f), s3 = scp[3] * (1.f / 4096.f);
    float mx = fmaxf(fmaxf(s0, s1), fmaxf(s2, s3));
    float e0 = __expf(s0 - mx), e1 = __expf(s1 - mx);
    float e2 = __expf(s2 - mx), e3 = __expf(s3 - mx);
    float d = e0 + e1 + e2 + e3;
    alp[0] = e0 / d; alp[1] = e1 / d; alp[2] = e2 / d; alp[3] = e3 / d;
  }
}

__global__ __launch_bounds__(256)
void xatt_k(const float* __restrict__ h0, const float* __restrict__ h1,
            const float* __restrict__ h2, const float* __restrict__ xt,
            const float* __restrict__ alp, float* __restrict__ out) {
  int idx = blockIdx.x * 256 + threadIdx.x;
  out[idx] = alp[0] * h0[idx] + alp[1] * h1[idx] + alp[2] * h2[idx] + alp[3] * xt[idx];
}

__global__ __launch_bounds__(256)
void scatter_deg_k(const int* __restrict__ dst, float* __restrict__ deg, int E) {
  int e = blockIdx.x * 256 + threadIdx.x;
  if (e < E) atomicAdd(&deg[dst[e]], 1.0f);
}

__global__ __launch_bounds__(256)
void scatter_add_k(const float* __restrict__ H, const int* __restrict__ src,
                   const int* __restrict__ dst, float* __restrict__ agg,
                   int E, int F, int fshift) {
  int idx = blockIdx.x * 256 + threadIdx.x;
  int e = idx >> fshift;
  int f = idx & (F - 1);
  if (e < E) atomicAdd(&agg[(size_t)dst[e] * F + f], H[(size_t)src[e] * F + f]);
}

__global__ __launch_bounds__(256)
void aggnorm_k(float* __restrict__ agg, const float* __restrict__ deg) {
  int idx = blockIdx.x * 256 + threadIdx.x;
  agg[idx] *= 1.f / fmaxf(deg[idx >> 7], 1.f);
}

__global__ __launch_bounds__(256)
void finaladd_k(float* __restrict__ out, const float* __restrict__ agg2,
                const float* __restrict__ deg) {
  int idx = blockIdx.x * 256 + threadIdx.x;
  out[idx] += agg2[idx] / fmaxf(deg[idx >> 6], 1.f);
}

// =====================================================================
// Launch. Workspace ~44.1 MB (< 45.4 MB empirical bound).
// =====================================================================
extern "C" void kernel_launch(void* const* d_in, const int* in_sizes, int n_in,
                              void* d_out, int out_size, void* d_ws, size_t ws_size,
                              hipStream_t stream) {
  const float* xma = (const float*)d_in[0];
  const float* xmp = (const float*)d_in[1];
  const float* xmt = (const float*)d_in[2];
  const float* xmc = (const float*)d_in[3];
  const float* xia = (const float*)d_in[4];
  const int*   ei  = (const int*)  d_in[5];
  const float* Wla = (const float*)d_in[6];  const float* bla = (const float*)d_in[7];
  const float* Wlp = (const float*)d_in[8];  const float* blp = (const float*)d_in[9];
  const float* Wlt = (const float*)d_in[10]; const float* blt = (const float*)d_in[11];
  const float* Wlc = (const float*)d_in[12]; const float* blc = (const float*)d_in[13];
  const float* Wtg = (const float*)d_in[14]; const float* btg = (const float*)d_in[15];
  const float* gWs = (const float*)d_in[16];
  const float* gWd = (const float*)d_in[17];
  const float* gas = (const float*)d_in[18];
  const float* gad = (const float*)d_in[19];
  const float* gb  = (const float*)d_in[20];
  const float* Watt = (const float*)d_in[21];
  const float* atts = (const float*)d_in[22];
  const float* W1l = (const float*)d_in[23]; const float* b1 = (const float*)d_in[24];
  const float* W1r = (const float*)d_in[25];
  const float* W2l = (const float*)d_in[26]; const float* b2 = (const float*)d_in[27];
  const float* W2r = (const float*)d_in[28];
  (void)in_sizes; (void)n_in; (void)out_size; (void)ws_size;

  float* ws = (float*)d_ws;
  size_t off = 0;
  auto alloc = [&](size_t n) { float* p = ws + off; off += n; return p; };
  float* h_a = alloc(524288);
  float* x_t = alloc(524288);
  float* Pr  = alloc(3670016);            // multi-life region
  // early aliases
  float* h_p  = Pr;
  float* h_t  = Pr + 1048576;
  float* h_c  = Pr + 1572864;
  float* hs_p = Pr + 1835008;
  float* hs_t = Pr + 2883584;
  float* hs_c = Pr + 3407872;
  // mid alias
  float* pacc = Pr;
  // late aliases
  float* satt = Pr;
  float* h1   = Pr + 1048576;
  float* p2   = Pr + 2097152;
  float* deg  = Pr + 2359296;
  float* agg1 = Pr + 2363392;
  float* agg2 = Pr + 2887680;
  // bf16 hi/lo K/V buffers
  u16* qn_h   = (u16*)alloc(4096 * 64);
  u16* qn_l   = (u16*)alloc(4096 * 64);
  u16* kn_p_h = (u16*)alloc(8192 * 64);
  u16* kn_p_l = (u16*)alloc(8192 * 64);
  u16* kn_t_h = (u16*)alloc(4096 * 64);
  u16* kn_t_l = (u16*)alloc(4096 * 64);
  u16* kn_c_h = (u16*)alloc(2048 * 64);
  u16* kn_c_l = (u16*)alloc(2048 * 64);
  u16* vt_p_h = (u16*)alloc(8192 * 64);
  u16* vt_p_l = (u16*)alloc(8192 * 64);
  u16* vt_t_h = (u16*)alloc(4096 * 64);
  u16* vt_t_l = (u16*)alloc(4096 * 64);
  u16* vt_c_h = (u16*)alloc(2048 * 64);
  u16* vt_c_l = (u16*)alloc(2048 * 64);
  // converted weights [N][Kpad] hi/lo
  u16* wla_h = (u16*)alloc(43008); u16* wla_l = (u16*)alloc(43008);
  u16* wlp_h = (u16*)alloc(65536); u16* wlp_l = (u16*)alloc(65536);
  u16* wlt_h = (u16*)alloc(16384); u16* wlt_l = (u16*)alloc(16384);
  u16* wlc_h = (u16*)alloc(8192);  u16* wlc_l = (u16*)alloc(8192);
  u16* wtg_h = (u16*)alloc(22528); u16* wtg_l = (u16*)alloc(22528);
  u16* wws_h = (u16*)alloc(24576); u16* wws_l = (u16*)alloc(24576);
  u16* wat_h = (u16*)alloc(4096);  u16* wat_l = (u16*)alloc(4096);
  u16* w1l_h = (u16*)alloc(16384); u16* w1l_l = (u16*)alloc(16384);
  u16* w1r_h = (u16*)alloc(16384); u16* w1r_l = (u16*)alloc(16384);
  u16* w2l_h = (u16*)alloc(8192);  u16* w2l_l = (u16*)alloc(8192);
  u16* w2r_h = (u16*)alloc(8192);  u16* w2r_l = (u16*)alloc(8192);
  float* ald   = alloc(3 * 4096);
  float* als_p = alloc(8192);
  float* als_t = alloc(4096);
  float* als_c = alloc(2048);
  float* wdv   = alloc(3 * 128);
  float* wsv   = alloc(3 * 128);
  float* het0  = alloc(524288);
  float* het1  = alloc(524288);
  float* het2  = alloc(524288);
  float* pm    = alloc(7 * 4096);
  float* pl    = alloc(7 * 4096);
  float* scp   = alloc(16);
  float* alp   = alloc(16);

  hipMemsetAsync(scp, 0, 32 * sizeof(float), stream);   // scp + alp

  dim3 blk(256);
  // ---- weight conversions ----
  wconv_k<<<dim3(11, 2), blk, 0, stream>>>(Wla, wla_h, wla_l, 668, 672, 128);
  wconv_k<<<dim3(16, 2), blk, 0, stream>>>(Wlp, wlp_h, wlp_l, 1024, 1024, 128);
  wconv_k<<<dim3(4, 2),  blk, 0, stream>>>(Wlt, wlt_h, wlt_l, 256, 256, 128);
  wconv_k<<<dim3(2, 2),  blk, 0, stream>>>(Wlc, wlc_h, wlc_l, 128, 128, 128);
  wconv_k<<<dim3(6, 2),  blk, 0, stream>>>(Wtg, wtg_h, wtg_l, 334, 352, 128);
  for (int i = 0; i < 3; ++i)
    wconv_k<<<dim3(2, 2), blk, 0, stream>>>(gWs + (size_t)i * 16384, wws_h + i * 16384, wws_l + i * 16384, 128, 128, 128);
  wconv_k<<<dim3(2, 1), blk, 0, stream>>>(Watt, wat_h, wat_l, 128, 128, 64);
  wconv_k<<<dim3(2, 4), blk, 0, stream>>>(W1l, w1l_h, w1l_l, 128, 128, 256);
  wconv_k<<<dim3(2, 4), blk, 0, stream>>>(W1r, w1r_h, w1r_l, 128, 128, 256);
  wconv_k<<<dim3(4, 1), blk, 0, stream>>>(W2l, w2l_h, w2l_l, 256, 256, 64);
  wconv_k<<<dim3(4, 1), blk, 0, stream>>>(W2r, w2r_h, w2r_l, 256, 256, 64);
  // ---- dimension transforms (MFMA) ----
  mgemm_k<1, 0, 0><<<dim3(64, 2),  blk, 0, stream>>>(xma, wla_h, wla_l, bla, h_a, 4096, 668, 672, 128);
  mgemm_k<1, 0, 0><<<dim3(128, 2), blk, 0, stream>>>(xmp, wlp_h, wlp_l, blp, h_p, 8192, 1024, 1024, 128);
  mgemm_k<1, 0, 0><<<dim3(64, 2),  blk, 0, stream>>>(xmt, wlt_h, wlt_l, blt, h_t, 4096, 256, 256, 128);
  mgemm_k<1, 0, 0><<<dim3(32, 2),  blk, 0, stream>>>(xmc, wlc_h, wlc_l, blc, h_c, 2048, 128, 128, 128);
  mgemm_k<1, 0, 0><<<dim3(64, 2),  blk, 0, stream>>>(xia, wtg_h, wtg_l, btg, x_t, 4096, 334, 352, 128);
  // ---- GAT precompute ----
  mgemm_k<0, 0, 0><<<dim3(128, 2), blk, 0, stream>>>(h_p, wws_h + 0 * 16384, wws_l + 0 * 16384, nullptr, hs_p, 8192, 128, 128, 128);
  mgemm_k<0, 0, 0><<<dim3(64, 2),  blk, 0, stream>>>(h_t, wws_h + 1 * 16384, wws_l + 1 * 16384, nullptr, hs_t, 4096, 128, 128, 128);
  mgemm_k<0, 0, 0><<<dim3(32, 2),  blk, 0, stream>>>(h_c, wws_h + 2 * 16384, wws_l + 2 * 16384, nullptr, hs_c, 2048, 128, 128, 128);
  wvec_k<<<dim3(6), dim3(128), 0, stream>>>(gWd, gad, gWs, gas, wdv, wsv);
  rownorm2_k<<<dim3(1024), blk, 0, stream>>>(h_a, qn_h, qn_l, wdv, 3, ald, 4096);
  rownorm2_k<<<dim3(2048), blk, 0, stream>>>(h_p, kn_p_h, kn_p_l, wsv + 0,   1, als_p, 8192);
  rownorm2_k<<<dim3(1024), blk, 0, stream>>>(h_t, kn_t_h, kn_t_l, wsv + 128, 1, als_t, 4096);
  rownorm2_k<<<dim3(512),  blk, 0, stream>>>(h_c, kn_c_h, kn_c_l, wsv + 256, 1, als_c, 2048);
  tconv_k<<<dim3(128, 2), blk, 0, stream>>>(hs_p, vt_p_h, vt_p_l, 8192);
  tconv_k<<<dim3(64, 2),  blk, 0, stream>>>(hs_t, vt_t_h, vt_t_l, 4096);
  tconv_k<<<dim3(32, 2),  blk, 0, stream>>>(hs_c, vt_c_h, vt_c_l, 2048);
  // ---- MFMA flash-GAT + merge ----
  GatP gp;
  gp.qh = qn_h; gp.ql = qn_l;
  gp.kh[0] = kn_p_h; gp.kh[1] = kn_t_h; gp.kh[2] = kn_c_h;
  gp.kl[0] = kn_p_l; gp.kl[1] = kn_t_l; gp.kl[2] = kn_c_l;
  gp.vh[0] = vt_p_h; gp.vh[1] = vt_t_h; gp.vh[2] = vt_c_h;
  gp.vl[0] = vt_p_l; gp.vl[1] = vt_t_l; gp.vl[2] = vt_c_l;
  gp.als[0] = als_p; gp.als[1] = als_t; gp.als[2] = als_c;
  gp.ald = ald; gp.pacc = pacc; gp.pm = pm; gp.pl = pl;
  gat_k<<<dim3(896), blk, 0, stream>>>(gp);
  gatmerge_k<<<dim3(2048, 3), blk, 0, stream>>>(pacc, pm, pl, gb, het0, het1, het2);
  // pacc dead -> zero late-alias SAGE buffers (deg, agg1, agg2)
  hipMemsetAsync(deg, 0, (size_t)790528 * sizeof(float), stream);
  // ---- AttentionInfo ----
  mgemm_k<0, 0, 0><<<dim3(64, 1), blk, 0, stream>>>(het0, wat_h, wat_l, nullptr, satt + 0 * 262144, 4096, 128, 128, 64);
  mgemm_k<0, 0, 0><<<dim3(64, 1), blk, 0, stream>>>(het1, wat_h, wat_l, nullptr, satt + 1 * 262144, 4096, 128, 128, 64);
  mgemm_k<0, 0, 0><<<dim3(64, 1), blk, 0, stream>>>(het2, wat_h, wat_l, nullptr, satt + 2 * 262144, 4096, 128, 128, 64);
  mgemm_k<0, 0, 0><<<dim3(64, 1), blk, 0, stream>>>(x_t,  wat_h, wat_l, nullptr, satt + 3 * 262144, 4096, 128, 128, 64);
  attred_k<<<dim3(32, 4), blk, 0, stream>>>(satt, atts, scp);
  alpha_k<<<dim3(1), dim3(64), 0, stream>>>(scp, alp);
  xatt_k<<<dim3(2048), blk, 0, stream>>>(het0, het1, het2, x_t, alp, (float*)d_out + 262144);
  // ---- GraphSAGE ----
  const int E = 131072;
  const int* esrc = ei;
  const int* edst = ei + E;
  scatter_deg_k<<<dim3(512), blk, 0, stream>>>(edst, deg, E);
  scatter_add_k<<<dim3(65536), blk, 0, stream>>>(h_a, esrc, edst, agg1, E, 128, 7);
  aggnorm_k<<<dim3(2048), blk, 0, stream>>>(agg1, deg);
  mgemm_k<1, 0, 0><<<dim3(64, 4), blk, 0, stream>>>(agg1, w1l_h, w1l_l, b1, h1, 4096, 128, 128, 256);
  mgemm_k<0, 1, 1><<<dim3(64, 4), blk, 0, stream>>>(h_a, w1r_h, w1r_l, nullptr, h1, 4096, 128, 128, 256);
  mgemm_k<0, 0, 0><<<dim3(64, 1), blk, 0, stream>>>(h1, w2l_h, w2l_l, nullptr, p2, 4096, 256, 256, 64);
  scatter_add_k<<<dim3(32768), blk, 0, stream>>>(p2, esrc, edst, agg2, E, 64, 6);
  mgemm_k<1, 0, 0><<<dim3(64, 1), blk, 0, stream>>>(h1, w2r_h, w2r_l, b2, (float*)d_out, 4096, 256, 256, 64);
  finaladd_k<<<dim3(1024), blk, 0, stream>>>((float*)d_out, agg2, deg);
}

// Round 8
// 694.290 us; speedup vs baseline: 2.2013x; 1.4221x over previous
//
#include <hip/hip_runtime.h>
#include <math.h>

#define THRESH 0.1f
#define NSLOPE 0.2f

typedef __attribute__((ext_vector_type(8))) short short8;
typedef __attribute__((ext_vector_type(4))) float f32x4;
typedef unsigned short u16;
typedef unsigned int u32;

#define MFMA16(a, b, c) __builtin_amdgcn_mfma_f32_16x16x32_bf16(a, b, c, 0, 0, 0)

__device__ inline u16 f2bf(float x) {
  u32 u = __float_as_uint(x);
  u += 0x7FFF + ((u >> 16) & 1);
  return (u16)(u >> 16);
}
__device__ inline float bf2f(u16 h) { return __uint_as_float((u32)h << 16); }

// Fragment-major K index: src row s, feature f ->
//   tile t=s>>5, tn=(s>>4)&1, lc=s&15, ks=f>>5, lg=(f>>3)&3, j=f&7
//   addr = ((t*8 + ks*2 + tn)*64 + lg*16 + lc)*8 + j
__device__ inline size_t kfrag_addr(int s, int f) {
  return ((size_t)((s >> 5) * 8 + (f >> 5) * 2 + ((s >> 4) & 1)) * 64
          + ((f >> 3) & 3) * 16 + (s & 15)) * 8 + (f & 7);
}

// =====================================================================
// Weight transpose-convert: W [K][N] fp32 -> WtH/WtL [N][Kpad] bf16 hi/lo
// =====================================================================
__global__ __launch_bounds__(256)
void wconv_k(const float* __restrict__ W, u16* __restrict__ dh, u16* __restrict__ dl,
             int K, int Kpad, int N) {
  __shared__ float tl[64][65];
  const int t = threadIdx.x;
  const int k0 = blockIdx.x * 64, n0 = blockIdx.y * 64;
#pragma unroll
  for (int l = 0; l < 4; ++l) {
    int i = t + l * 256; int r = i >> 4; int c4 = i & 15;
    float4 v = make_float4(0.f, 0.f, 0.f, 0.f);
    if (k0 + r < K) v = *(const float4*)&W[(size_t)(k0 + r) * N + n0 + c4 * 4];
    *(float4*)&tl[r][c4 * 4] = v;
  }
  __syncthreads();
#pragma unroll
  for (int l = 0; l < 2; ++l) {
    int g = t + l * 256; int f = g >> 3; int s8 = (g & 7) * 8;
    if (k0 + s8 >= Kpad) continue;
    u32 ph[4], pl[4];
#pragma unroll
    for (int k = 0; k < 4; ++k) {
      float a = tl[s8 + 2 * k][f], b = tl[s8 + 2 * k + 1][f];
      u16 ha = f2bf(a), hb = f2bf(b);
      u16 la = f2bf(a - bf2f(ha)), lb = f2bf(b - bf2f(hb));
      ph[k] = (u32)ha | ((u32)hb << 16);
      pl[k] = (u32)la | ((u32)lb << 16);
    }
    size_t o = (size_t)(n0 + f) * Kpad + k0 + s8;
    *(uint4*)&dh[o] = make_uint4(ph[0], ph[1], ph[2], ph[3]);
    *(uint4*)&dl[o] = make_uint4(pl[0], pl[1], pl[2], pl[3]);
  }
}

// =====================================================================
// Split-bf16 MFMA GEMM (verified rounds 5-7)
// =====================================================================
template<int BIAS, int ACCUM, int RELU>
__global__ __launch_bounds__(256)
void mgemm_k(const float* __restrict__ A, const u16* __restrict__ WtH,
             const u16* __restrict__ WtL, const float* __restrict__ bias,
             float* C, int M, int K, int Kpad, int N) {
  const int t = threadIdx.x, wm = t >> 6, ln = t & 63;
  const int lg = ln >> 4, lc = ln & 15;
  const int i0 = blockIdx.x * 64, n0 = blockIdx.y * 64;
  const int arow = i0 + wm * 16 + lc;
  f32x4 acc[4];
#pragma unroll
  for (int tn = 0; tn < 4; ++tn) acc[tn] = (f32x4)0.f;

  for (int k0 = 0; k0 < K; k0 += 32) {
    float av[8];
    const float* ap = A + (size_t)arow * K + k0 + lg * 8;
    if (k0 + 32 <= K) {
#pragma unroll
      for (int q = 0; q < 4; ++q) {
        float2 v = *(const float2*)(ap + q * 2);
        av[q * 2] = v.x; av[q * 2 + 1] = v.y;
      }
    } else {
#pragma unroll
      for (int kk = 0; kk < 8; ++kk) {
        int k = k0 + lg * 8 + kk;
        av[kk] = (k < K) ? ap[kk] : 0.f;
      }
    }
    short8 ah, al;
#pragma unroll
    for (int kk = 0; kk < 8; ++kk) {
      u16 h = f2bf(av[kk]);
      ah[kk] = (short)h;
      al[kk] = (short)f2bf(av[kk] - bf2f(h));
    }
    short8 bh[4], bl[4];
#pragma unroll
    for (int tn = 0; tn < 4; ++tn) {
      size_t o = (size_t)(n0 + tn * 16 + lc) * Kpad + k0 + lg * 8;
      bh[tn] = *(const short8*)(WtH + o);
      bl[tn] = *(const short8*)(WtL + o);
    }
#pragma unroll
    for (int tn = 0; tn < 4; ++tn) {
      acc[tn] = MFMA16(ah, bh[tn], acc[tn]);
      acc[tn] = MFMA16(ah, bl[tn], acc[tn]);
      acc[tn] = MFMA16(al, bh[tn], acc[tn]);
    }
  }
#pragma unroll
  for (int tn = 0; tn < 4; ++tn)
#pragma unroll
    for (int r = 0; r < 4; ++r) {
      size_t row = (size_t)(i0 + wm * 16 + lg * 4 + r);
      float* cp = &C[row * N + n0 + tn * 16 + lc];
      float o = acc[tn][r];
      if (BIAS) o += bias[n0 + tn * 16 + lc];
      if (ACCUM) o += *cp;
      if (RELU) o = fmaxf(o, 0.f);
      *cp = o;
    }
}

// =====================================================================
// wdvec[t] = Wd[t] @ a_d[t], wsvec[t] = Ws[t] @ a_s[t]
// =====================================================================
__global__ void wvec_k(const float* __restrict__ Wd, const float* __restrict__ ad,
                       const float* __restrict__ Ws, const float* __restrict__ as_,
                       float* __restrict__ wdv, float* __restrict__ wsv) {
  int b = blockIdx.x, k = threadIdx.x;
  const float* Wm = (b < 3) ? Wd + (size_t)b * 16384 : Ws + (size_t)(b - 3) * 16384;
  const float* av = (b < 3) ? ad + b * 128 : as_ + (b - 3) * 128;
  float* o = (b < 3) ? wdv + b * 128 : wsv + (b - 3) * 128;
  float s = 0.f;
  for (int c = 0; c < 128; ++c) s = fmaf(Wm[(size_t)k * 128 + c], av[c], s);
  o[k] = s;
}

// =====================================================================
// Row stats. FRAG=0: row-major bf16 hi/lo out (Q). FRAG=1: MFMA
// fragment-major out (K): addr via kfrag_addr. al on UNnormalized row.
// =====================================================================
template<int FRAG>
__global__ __launch_bounds__(256)
void rownorm2_k(const float* __restrict__ X, u16* __restrict__ XH, u16* __restrict__ XL,
                const float* __restrict__ avecs, int navec,
                float* __restrict__ al_out, int N) {
  int lane = threadIdx.x & 63, wv = threadIdx.x >> 6;
  int i = blockIdx.x * 4 + wv;
  float x0 = X[(size_t)i * 128 + lane];
  float x1 = X[(size_t)i * 128 + 64 + lane];
  float ss = x0 * x0 + x1 * x1;
#pragma unroll
  for (int o = 1; o < 64; o <<= 1) ss += __shfl_xor(ss, o);
  float inv = 1.f / fmaxf(sqrtf(ss), 1e-12f);
  for (int v = 0; v < navec; ++v) {
    float d = x0 * avecs[v * 128 + lane] + x1 * avecs[v * 128 + 64 + lane];
#pragma unroll
    for (int o = 1; o < 64; o <<= 1) d += __shfl_xor(d, o);
    if (lane == 0) al_out[(size_t)v * N + i] = d;
  }
  float n0 = x0 * inv, n1 = x1 * inv;
  u16 h0 = f2bf(n0), h1 = f2bf(n1);
  u16 l0 = f2bf(n0 - bf2f(h0)), l1 = f2bf(n1 - bf2f(h1));
  if (FRAG) {
    size_t a0 = kfrag_addr(i, lane), a1 = kfrag_addr(i, 64 + lane);
    XH[a0] = h0; XH[a1] = h1;
    XL[a0] = l0; XL[a1] = l1;
  } else {
    XH[(size_t)i * 128 + lane]      = h0;
    XH[(size_t)i * 128 + 64 + lane] = h1;
    XL[(size_t)i * 128 + lane]      = l0;
    XL[(size_t)i * 128 + 64 + lane] = l1;
  }
}

// =====================================================================
// V fragment-convert: hs fp32 [N][128] -> vf_h/vf_l in PV B-fragment
// order: slot n=f>>4, lane=(lg=(s>>3)&3)*16 + (lc=f&15), 8 srcs contig.
// addr = ((t*8+n)*64 + lg*16 + lc)*8, t = s>>5. 64x64 LDS tile.
// =====================================================================
__global__ __launch_bounds__(256)
void vfrag_k(const float* __restrict__ src, u16* __restrict__ dh, u16* __restrict__ dl, int N) {
  __shared__ float tl[64][65];
  const int t = threadIdx.x;
  const int sb = blockIdx.x, fb = blockIdx.y;
#pragma unroll
  for (int l = 0; l < 4; ++l) {
    int i = t + l * 256; int r = i >> 4; int c4 = i & 15;
    *(float4*)&tl[r][c4 * 4] = *(const float4*)&src[(size_t)(sb * 64 + r) * 128 + fb * 64 + c4 * 4];
  }
  __syncthreads();
#pragma unroll
  for (int l = 0; l < 2; ++l) {
    int g = t + l * 256; int f = g >> 3; int s8 = (g & 7) * 8;
    u32 ph[4], pl[4];
#pragma unroll
    for (int k = 0; k < 4; ++k) {
      float a = tl[s8 + 2 * k][f], b = tl[s8 + 2 * k + 1][f];
      u16 ha = f2bf(a), hb = f2bf(b);
      u16 la = f2bf(a - bf2f(ha)), lb = f2bf(b - bf2f(hb));
      ph[k] = (u32)ha | ((u32)hb << 16);
      pl[k] = (u32)la | ((u32)lb << 16);
    }
    int gs = sb * 64 + s8;          // global src (8-aligned)
    int gf = fb * 64 + f;           // global feature
    size_t o = ((size_t)((gs >> 5) * 8 + (gf >> 4)) * 64
                + ((gs >> 3) & 3) * 16 + (gf & 15)) * 8;
    *(uint4*)&dh[o] = make_uint4(ph[0], ph[1], ph[2], ph[3]);
    *(uint4*)&dl[o] = make_uint4(pl[0], pl[1], pl[2], pl[3]);
  }
}

// =====================================================================
// MFMA flash-GAT v5: R7 structure (4-wave/32-author blocks, in-block
// j-split flash merge) + FRAGMENT-MAJOR K/V: every B-frag load is one
// contiguous 1KB wave burst (base + lane*16B) instead of a 16-row
// gather. [R7 A/B: wave count is not the lever; VMEM path is.]
// EMPIRICAL TOOLCHAIN LESSON (R4-R7): plain __launch_bounds__(256)
// -> VGPR~124, no spill. Adding ",4" -> VGPR=64 + 1.4GB spill. Never
// pass the second arg for this kernel.
// =====================================================================
struct GatP {
  const u16 *qh, *ql;          // author row-major [4096][128]
  const u16 *kfh[3], *kfl[3];  // K fragment-major
  const u16 *vfh[3], *vfl[3];  // V fragment-major
  const float *als[3];
  const float *ald;            // [3][4096]
  float *pacc;                 // [7][4096][128]
  float *pm;                   // [7][4096]
  float *pl;                   // [7][4096]
};

__global__ __launch_bounds__(256)
void gat_k(GatP P) {
  __shared__ u16 wh[4][16][40];     // per-wave P (hi), padded stride 40
  __shared__ u16 wl_[4][16][40];    // per-wave P (lo)
  __shared__ float mrg[2][16][132]; // j-half-1 acc for merge
  __shared__ float mml[2][2][16];   // j-half-1 m/l

  // XCD-contiguous remap: each XCD owns 112 consecutive work-ids
  const int b = ((blockIdx.x & 7) * 112) + (blockIdx.x >> 3);
  const int cg = b >> 7;            // 0..6
  const int rb = b & 127;           // 32-author row-block
  const int type = (cg < 4) ? 0 : (cg < 6 ? 1 : 2);
  const int chunk = cg - (type == 0 ? 0 : (type == 1 ? 4 : 6));
  const u16* KFH = P.kfh[type]; const u16* KFL = P.kfl[type];
  const u16* VFH = P.vfh[type]; const u16* VFL = P.vfl[type];
  const float* alsg = P.als[type];
  const float* ALD = P.ald + (size_t)type * 4096;
  const int i0 = rb * 32;

  const int t = threadIdx.x;
  const int wm = t >> 6;          // wave 0..3
  const int wq = wm & 1;          // author 16-group
  const int jhalf = wm >> 1;      // 0 or 1
  const int ln = t & 63;
  const int lg = ln >> 4;
  const int lc = ln & 15;
  const int arow0 = i0 + wq * 16;
  const int cj0 = chunk * 2048 + jhalf * 1024;
  const int t0 = cj0 >> 5;        // first tile index

  // Q fragments (row-major source; loaded once)
  short8 qhf[4], qlf[4];
#pragma unroll
  for (int ks = 0; ks < 4; ++ks) {
    size_t qo = (size_t)(arow0 + lc) * 128 + ks * 32 + lg * 8;
    qhf[ks] = *(const short8*)(P.qh + qo);
    qlf[ks] = *(const short8*)(P.ql + qo);
  }
  float ald_r[4], m[4], lsum[4];
#pragma unroll
  for (int r = 0; r < 4; ++r) {
    ald_r[r] = ALD[arow0 + lg * 4 + r];
    m[r] = -1e30f; lsum[r] = 0.f;
  }
  f32x4 pacc[8];
#pragma unroll
  for (int n = 0; n < 8; ++n) pacc[n] = (f32x4)0.f;

  for (int jt = 0; jt < 32; ++jt) {
    const int j0 = cj0 + jt * 32;
    const size_t tb = (size_t)(t0 + jt) * 8 * 512;   // tile base (8 slots x 512 u16)
    // ---- K B-frag loads: contiguous 1KB per instruction ----
    short8 kbh[2][4], kbl[2][4];
#pragma unroll
    for (int ks = 0; ks < 4; ++ks)
#pragma unroll
      for (int tn = 0; tn < 2; ++tn) {
        size_t ko = tb + (size_t)(ks * 2 + tn) * 512 + ln * 8;
        kbh[tn][ks] = *(const short8*)(KFH + ko);
        kbl[tn][ks] = *(const short8*)(KFL + ko);
      }
    float als0 = alsg[j0 + lc], als1 = alsg[j0 + 16 + lc];
    // ---- S = cos-sim: 3-term split-bf16 MFMA ----
    f32x4 sacc[2];
    sacc[0] = (f32x4)0.f; sacc[1] = (f32x4)0.f;
    __builtin_amdgcn_s_setprio(1);
#pragma unroll
    for (int ks = 0; ks < 4; ++ks)
#pragma unroll
      for (int tn = 0; tn < 2; ++tn) {
        sacc[tn] = MFMA16(qhf[ks], kbh[tn][ks], sacc[tn]);
        sacc[tn] = MFMA16(qhf[ks], kbl[tn][ks], sacc[tn]);
        sacc[tn] = MFMA16(qlf[ks], kbh[tn][ks], sacc[tn]);
      }
    __builtin_amdgcn_s_setprio(0);
    // ---- V B-frag loads: contiguous 1KB per instruction ----
    short8 vbh[8], vbl[8];
#pragma unroll
    for (int n = 0; n < 8; ++n) {
      size_t vo = tb + (size_t)n * 512 + ln * 8;
      vbh[n] = *(const short8*)(VFH + vo);
      vbl[n] = *(const short8*)(VFL + vo);
    }
    // ---- mask + leaky + online softmax ----
    float w0s[4], w1s[4], scl[4];
#pragma unroll
    for (int r = 0; r < 4; ++r) {
      int ag = arow0 + lg * 4 + r;
      float z0 = ald_r[r] + als0; z0 = (z0 >= 0.f) ? z0 : NSLOPE * z0;
      float z1 = ald_r[r] + als1; z1 = (z1 >= 0.f) ? z1 : NSLOPE * z1;
      bool a0 = (sacc[0][r] > THRESH) && (j0 + lc != ag);
      bool a1 = (sacc[1][r] > THRESH) && (j0 + 16 + lc != ag);
      float e0 = a0 ? z0 : -1e30f;
      float e1 = a1 ? z1 : -1e30f;
      float rm = fmaxf(e0, e1);
#pragma unroll
      for (int o = 1; o < 16; o <<= 1) rm = fmaxf(rm, __shfl_xor(rm, o));
      float mn = fmaxf(m[r], rm);
      scl[r] = __expf(m[r] - mn);
      m[r] = mn;
      float w0 = (e0 > -1e29f) ? __expf(e0 - mn) : 0.f;
      float w1 = (e1 > -1e29f) ? __expf(e1 - mn) : 0.f;
      float rs = w0 + w1;
#pragma unroll
      for (int o = 1; o < 16; o <<= 1) rs += __shfl_xor(rs, o);
      lsum[r] = lsum[r] * scl[r] + rs;
      w0s[r] = w0; w1s[r] = w1;
    }
    // ---- P transpose via per-wave LDS slice (same-wave, no barrier) ----
#pragma unroll
    for (int r = 0; r < 4; ++r) {
      u16 h0 = f2bf(w0s[r]);
      u16 h1 = f2bf(w1s[r]);
      wh[wm][lg * 4 + r][lc]      = h0;
      wh[wm][lg * 4 + r][16 + lc] = h1;
      wl_[wm][lg * 4 + r][lc]      = f2bf(w0s[r] - bf2f(h0));
      wl_[wm][lg * 4 + r][16 + lc] = f2bf(w1s[r] - bf2f(h1));
    }
#pragma unroll
    for (int n = 0; n < 8; ++n)
#pragma unroll
      for (int r = 0; r < 4; ++r) pacc[n][r] *= scl[r];
    short8 wfh = *(const short8*)&wh[wm][lc][lg * 8];
    short8 wfl = *(const short8*)&wl_[wm][lc][lg * 8];
    // ---- PV: 3-term split-bf16 MFMA ----
    __builtin_amdgcn_s_setprio(1);
#pragma unroll
    for (int n = 0; n < 8; ++n) {
      pacc[n] = MFMA16(wfh, vbh[n], pacc[n]);
      pacc[n] = MFMA16(wfh, vbl[n], pacc[n]);
      pacc[n] = MFMA16(wfl, vbh[n], pacc[n]);
    }
    __builtin_amdgcn_s_setprio(0);
  }
  // ---- in-block flash merge of the two j-halves ----
  if (jhalf == 1) {
#pragma unroll
    for (int n = 0; n < 8; ++n)
#pragma unroll
      for (int r = 0; r < 4; ++r)
        mrg[wq][lg * 4 + r][n * 16 + lc] = pacc[n][r];
    if (lc == 0) {
#pragma unroll
      for (int r = 0; r < 4; ++r) {
        mml[wq][0][lg * 4 + r] = m[r];
        mml[wq][1][lg * 4 + r] = lsum[r];
      }
    }
  }
  __syncthreads();
  if (jhalf == 0) {
#pragma unroll
    for (int r = 0; r < 4; ++r) {
      float mu = mml[wq][0][lg * 4 + r];
      float lu = mml[wq][1][lg * 4 + r];
      float M = fmaxf(m[r], mu);
      float sA = __expf(m[r] - M);
      float sB = __expf(mu - M);
      lsum[r] = lsum[r] * sA + lu * sB;
      m[r] = M;
#pragma unroll
      for (int n = 0; n < 8; ++n)
        pacc[n][r] = pacc[n][r] * sA + mrg[wq][lg * 4 + r][n * 16 + lc] * sB;
    }
#pragma unroll
    for (int n = 0; n < 8; ++n)
#pragma unroll
      for (int r = 0; r < 4; ++r) {
        size_t row = (size_t)(arow0 + lg * 4 + r);
        P.pacc[(size_t)cg * 524288 + row * 128 + n * 16 + lc] = pacc[n][r];
      }
    if (lc == 0) {
#pragma unroll
      for (int r = 0; r < 4; ++r) {
        size_t row = (size_t)(arow0 + lg * 4 + r);
        P.pm[(size_t)cg * 4096 + row] = m[r];
        P.pl[(size_t)cg * 4096 + row] = lsum[r];
      }
    }
  }
}

// =====================================================================
// Merge flash partials (7 chunks: paper 4, term 2, conf 1)
// =====================================================================
__global__ __launch_bounds__(256)
void gatmerge_k(const float* __restrict__ pacc, const float* __restrict__ pm,
                const float* __restrict__ pl, const float* __restrict__ gatb,
                float* __restrict__ out0, float* __restrict__ out1, float* __restrict__ out2) {
  int type = blockIdx.y;
  int nc = (type == 0) ? 4 : (type == 1 ? 2 : 1);
  int cb = (type == 0) ? 0 : (type == 1 ? 4 : 6);
  float* OUT = (type == 0) ? out0 : (type == 1 ? out1 : out2);
  int idx = blockIdx.x * 256 + threadIdx.x;
  int i = idx >> 7, c = idx & 127;
  float M = -1e30f;
  for (int ch = 0; ch < nc; ++ch) M = fmaxf(M, pm[(size_t)(cb + ch) * 4096 + i]);
  float num = 0.f, den = 0.f;
  for (int ch = 0; ch < nc; ++ch) {
    float sc = __expf(pm[(size_t)(cb + ch) * 4096 + i] - M);
    den += pl[(size_t)(cb + ch) * 4096 + i] * sc;
    num += pacc[(size_t)(cb + ch) * 524288 + idx] * sc;
  }
  float bv = gatb[(size_t)type * 128 + c];
  OUT[idx] = (den > 0.f) ? num / den + bv : bv;
}

// =====================================================================
// AttentionInfo + SAGE pieces
// =====================================================================
__global__ __launch_bounds__(256)
void attred_k(const float* __restrict__ satt, const float* __restrict__ atts,
              float* __restrict__ scp) {
  int v = blockIdx.y;
  const float* S = satt + (size_t)v * 262144;
  const float* av = atts + v * 64;
  float local = 0.f;
  for (int idx = blockIdx.x * 256 + threadIdx.x; idx < 262144; idx += 32 * 256) {
    float x = S[idx];
    local += av[idx & 63] / (1.f + __expf(-x));
  }
#pragma unroll
  for (int o = 1; o < 64; o <<= 1) local += __shfl_xor(local, o);
  __shared__ float red[4];
  if ((threadIdx.x & 63) == 0) red[threadIdx.x >> 6] = local;
  __syncthreads();
  if (threadIdx.x == 0) atomicAdd(&scp[v], red[0] + red[1] + red[2] + red[3]);
}

__global__ void alpha_k(const float* __restrict__ scp, float* __restrict__ alp) {
  if (threadIdx.x == 0) {
    float s0 = scp[0] * (1.f / 4096.f), s1 = scp[1] * (1.f / 4096.f);
    float s2 = scp[2] * (1.f / 4096.f), s3 = scp[3] * (1.f / 4096.f);
    float mx = fmaxf(fmaxf(s0, s1), fmaxf(s2, s3));
    float e0 = __expf(s0 - mx), e1 = __expf(s1 - mx);
    float e2 = __expf(s2 - mx), e3 = __expf(s3 - mx);
    float d = e0 + e1 + e2 + e3;
    alp[0] = e0 / d; alp[1] = e1 / d; alp[2] = e2 / d; alp[3] = e3 / d;
  }
}

__global__ __launch_bounds__(256)
void xatt_k(const float* __restrict__ h0, const float* __restrict__ h1,
            const float* __restrict__ h2, const float* __restrict__ xt,
            const float* __restrict__ alp, float* __restrict__ out) {
  int idx = blockIdx.x * 256 + threadIdx.x;
  out[idx] = alp[0] * h0[idx] + alp[1] * h1[idx] + alp[2] * h2[idx] + alp[3] * xt[idx];
}

__global__ __launch_bounds__(256)
void scatter_deg_k(const int* __restrict__ dst, float* __restrict__ deg, int E) {
  int e = blockIdx.x * 256 + threadIdx.x;
  if (e < E) atomicAdd(&deg[dst[e]], 1.0f);
}

__global__ __launch_bounds__(256)
void scatter_add_k(const float* __restrict__ H, const int* __restrict__ src,
                   const int* __restrict__ dst, float* __restrict__ agg,
                   int E, int F, int fshift) {
  int idx = blockIdx.x * 256 + threadIdx.x;
  int e = idx >> fshift;
  int f = idx & (F - 1);
  if (e < E) atomicAdd(&agg[(size_t)dst[e] * F + f], H[(size_t)src[e] * F + f]);
}

__global__ __launch_bounds__(256)
void aggnorm_k(float* __restrict__ agg, const float* __restrict__ deg) {
  int idx = blockIdx.x * 256 + threadIdx.x;
  agg[idx] *= 1.f / fmaxf(deg[idx >> 7], 1.f);
}

__global__ __launch_bounds__(256)
void finaladd_k(float* __restrict__ out, const float* __restrict__ agg2,
                const float* __restrict__ deg) {
  int idx = blockIdx.x * 256 + threadIdx.x;
  out[idx] += agg2[idx] / fmaxf(deg[idx >> 6], 1.f);
}

// =====================================================================
// Launch. Workspace ~44.1 MB (< 45.4 MB empirical bound).
// =====================================================================
extern "C" void kernel_launch(void* const* d_in, const int* in_sizes, int n_in,
                              void* d_out, int out_size, void* d_ws, size_t ws_size,
                              hipStream_t stream) {
  const float* xma = (const float*)d_in[0];
  const float* xmp = (const float*)d_in[1];
  const float* xmt = (const float*)d_in[2];
  const float* xmc = (const float*)d_in[3];
  const float* xia = (const float*)d_in[4];
  const int*   ei  = (const int*)  d_in[5];
  const float* Wla = (const float*)d_in[6];  const float* bla = (const float*)d_in[7];
  const float* Wlp = (const float*)d_in[8];  const float* blp = (const float*)d_in[9];
  const float* Wlt = (const float*)d_in[10]; const float* blt = (const float*)d_in[11];
  const float* Wlc = (const float*)d_in[12]; const float* blc = (const float*)d_in[13];
  const float* Wtg = (const float*)d_in[14]; const float* btg = (const float*)d_in[15];
  const float* gWs = (const float*)d_in[16];
  const float* gWd = (const float*)d_in[17];
  const float* gas = (const float*)d_in[18];
  const float* gad = (const float*)d_in[19];
  const float* gb  = (const float*)d_in[20];
  const float* Watt = (const float*)d_in[21];
  const float* atts = (const float*)d_in[22];
  const float* W1l = (const float*)d_in[23]; const float* b1 = (const float*)d_in[24];
  const float* W1r = (const float*)d_in[25];
  const float* W2l = (const float*)d_in[26]; const float* b2 = (const float*)d_in[27];
  const float* W2r = (const float*)d_in[28];
  (void)in_sizes; (void)n_in; (void)out_size; (void)ws_size;

  float* ws = (float*)d_ws;
  size_t off = 0;
  auto alloc = [&](size_t n) { float* p = ws + off; off += n; return p; };
  float* h_a = alloc(524288);
  float* x_t = alloc(524288);
  float* Pr  = alloc(3670016);            // multi-life region
  // early aliases
  float* h_p  = Pr;
  float* h_t  = Pr + 1048576;
  float* h_c  = Pr + 1572864;
  float* hs_p = Pr + 1835008;
  float* hs_t = Pr + 2883584;
  float* hs_c = Pr + 3407872;
  // mid alias
  float* pacc = Pr;
  // late aliases
  float* satt = Pr;
  float* h1   = Pr + 1048576;
  float* p2   = Pr + 2097152;
  float* deg  = Pr + 2359296;
  float* agg1 = Pr + 2363392;
  float* agg2 = Pr + 2887680;
  // bf16 hi/lo buffers (fragment-major K/V + row-major Q)
  u16* qn_h   = (u16*)alloc(4096 * 64);
  u16* qn_l   = (u16*)alloc(4096 * 64);
  u16* kf_p_h = (u16*)alloc(8192 * 64);
  u16* kf_p_l = (u16*)alloc(8192 * 64);
  u16* kf_t_h = (u16*)alloc(4096 * 64);
  u16* kf_t_l = (u16*)alloc(4096 * 64);
  u16* kf_c_h = (u16*)alloc(2048 * 64);
  u16* kf_c_l = (u16*)alloc(2048 * 64);
  u16* vf_p_h = (u16*)alloc(8192 * 64);
  u16* vf_p_l = (u16*)alloc(8192 * 64);
  u16* vf_t_h = (u16*)alloc(4096 * 64);
  u16* vf_t_l = (u16*)alloc(4096 * 64);
  u16* vf_c_h = (u16*)alloc(2048 * 64);
  u16* vf_c_l = (u16*)alloc(2048 * 64);
  // converted weights [N][Kpad] hi/lo
  u16* wla_h = (u16*)alloc(43008); u16* wla_l = (u16*)alloc(43008);
  u16* wlp_h = (u16*)alloc(65536); u16* wlp_l = (u16*)alloc(65536);
  u16* wlt_h = (u16*)alloc(16384); u16* wlt_l = (u16*)alloc(16384);
  u16* wlc_h = (u16*)alloc(8192);  u16* wlc_l = (u16*)alloc(8192);
  u16* wtg_h = (u16*)alloc(22528); u16* wtg_l = (u16*)alloc(22528);
  u16* wws_h = (u16*)alloc(24576); u16* wws_l = (u16*)alloc(24576);
  u16* wat_h = (u16*)alloc(4096);  u16* wat_l = (u16*)alloc(4096);
  u16* w1l_h = (u16*)alloc(16384); u16* w1l_l = (u16*)alloc(16384);
  u16* w1r_h = (u16*)alloc(16384); u16* w1r_l = (u16*)alloc(16384);
  u16* w2l_h = (u16*)alloc(8192);  u16* w2l_l = (u16*)alloc(8192);
  u16* w2r_h = (u16*)alloc(8192);  u16* w2r_l = (u16*)alloc(8192);
  float* ald   = alloc(3 * 4096);
  float* als_p = alloc(8192);
  float* als_t = alloc(4096);
  float* als_c = alloc(2048);
  float* wdv   = alloc(3 * 128);
  float* wsv   = alloc(3 * 128);
  float* het0  = alloc(524288);
  float* het1  = alloc(524288);
  float* het2  = alloc(524288);
  float* pm    = alloc(7 * 4096);
  float* pl    = alloc(7 * 4096);
  float* scp   = alloc(16);
  float* alp   = alloc(16);

  hipMemsetAsync(scp, 0, 32 * sizeof(float), stream);   // scp + alp

  dim3 blk(256);
  // ---- weight conversions ----
  wconv_k<<<dim3(11, 2), blk, 0, stream>>>(Wla, wla_h, wla_l, 668, 672, 128);
  wconv_k<<<dim3(16, 2), blk, 0, stream>>>(Wlp, wlp_h, wlp_l, 1024, 1024, 128);
  wconv_k<<<dim3(4, 2),  blk, 0, stream>>>(Wlt, wlt_h, wlt_l, 256, 256, 128);
  wconv_k<<<dim3(2, 2),  blk, 0, stream>>>(Wlc, wlc_h, wlc_l, 128, 128, 128);
  wconv_k<<<dim3(6, 2),  blk, 0, stream>>>(Wtg, wtg_h, wtg_l, 334, 352, 128);
  for (int i = 0; i < 3; ++i)
    wconv_k<<<dim3(2, 2), blk, 0, stream>>>(gWs + (size_t)i * 16384, wws_h + i * 16384, wws_l + i * 16384, 128, 128, 128);
  wconv_k<<<dim3(2, 1), blk, 0, stream>>>(Watt, wat_h, wat_l, 128, 128, 64);
  wconv_k<<<dim3(2, 4), blk, 0, stream>>>(W1l, w1l_h, w1l_l, 128, 128, 256);
  wconv_k<<<dim3(2, 4), blk, 0, stream>>>(W1r, w1r_h, w1r_l, 128, 128, 256);
  wconv_k<<<dim3(4, 1), blk, 0, stream>>>(W2l, w2l_h, w2l_l, 256, 256, 64);
  wconv_k<<<dim3(4, 1), blk, 0, stream>>>(W2r, w2r_h, w2r_l, 256, 256, 64);
  // ---- dimension transforms (MFMA) ----
  mgemm_k<1, 0, 0><<<dim3(64, 2),  blk, 0, stream>>>(xma, wla_h, wla_l, bla, h_a, 4096, 668, 672, 128);
  mgemm_k<1, 0, 0><<<dim3(128, 2), blk, 0, stream>>>(xmp, wlp_h, wlp_l, blp, h_p, 8192, 1024, 1024, 128);
  mgemm_k<1, 0, 0><<<dim3(64, 2),  blk, 0, stream>>>(xmt, wlt_h, wlt_l, blt, h_t, 4096, 256, 256, 128);
  mgemm_k<1, 0, 0><<<dim3(32, 2),  blk, 0, stream>>>(xmc, wlc_h, wlc_l, blc, h_c, 2048, 128, 128, 128);
  mgemm_k<1, 0, 0><<<dim3(64, 2),  blk, 0, stream>>>(xia, wtg_h, wtg_l, btg, x_t, 4096, 334, 352, 128);
  // ---- GAT precompute ----
  mgemm_k<0, 0, 0><<<dim3(128, 2), blk, 0, stream>>>(h_p, wws_h + 0 * 16384, wws_l + 0 * 16384, nullptr, hs_p, 8192, 128, 128, 128);
  mgemm_k<0, 0, 0><<<dim3(64, 2),  blk, 0, stream>>>(h_t, wws_h + 1 * 16384, wws_l + 1 * 16384, nullptr, hs_t, 4096, 128, 128, 128);
  mgemm_k<0, 0, 0><<<dim3(32, 2),  blk, 0, stream>>>(h_c, wws_h + 2 * 16384, wws_l + 2 * 16384, nullptr, hs_c, 2048, 128, 128, 128);
  wvec_k<<<dim3(6), dim3(128), 0, stream>>>(gWd, gad, gWs, gas, wdv, wsv);
  rownorm2_k<0><<<dim3(1024), blk, 0, stream>>>(h_a, qn_h, qn_l, wdv, 3, ald, 4096);
  rownorm2_k<1><<<dim3(2048), blk, 0, stream>>>(h_p, kf_p_h, kf_p_l, wsv + 0,   1, als_p, 8192);
  rownorm2_k<1><<<dim3(1024), blk, 0, stream>>>(h_t, kf_t_h, kf_t_l, wsv + 128, 1, als_t, 4096);
  rownorm2_k<1><<<dim3(512),  blk, 0, stream>>>(h_c, kf_c_h, kf_c_l, wsv + 256, 1, als_c, 2048);
  vfrag_k<<<dim3(128, 2), blk, 0, stream>>>(hs_p, vf_p_h, vf_p_l, 8192);
  vfrag_k<<<dim3(64, 2),  blk, 0, stream>>>(hs_t, vf_t_h, vf_t_l, 4096);
  vfrag_k<<<dim3(32, 2),  blk, 0, stream>>>(hs_c, vf_c_h, vf_c_l, 2048);
  // ---- MFMA flash-GAT + merge ----
  GatP gp;
  gp.qh = qn_h; gp.ql = qn_l;
  gp.kfh[0] = kf_p_h; gp.kfh[1] = kf_t_h; gp.kfh[2] = kf_c_h;
  gp.kfl[0] = kf_p_l; gp.kfl[1] = kf_t_l; gp.kfl[2] = kf_c_l;
  gp.vfh[0] = vf_p_h; gp.vfh[1] = vf_t_h; gp.vfh[2] = vf_c_h;
  gp.vfl[0] = vf_p_l; gp.vfl[1] = vf_t_l; gp.vfl[2] = vf_c_l;
  gp.als[0] = als_p; gp.als[1] = als_t; gp.als[2] = als_c;
  gp.ald = ald; gp.pacc = pacc; gp.pm = pm; gp.pl = pl;
  gat_k<<<dim3(896), blk, 0, stream>>>(gp);
  gatmerge_k<<<dim3(2048, 3), blk, 0, stream>>>(pacc, pm, pl, gb, het0, het1, het2);
  // pacc dead -> zero late-alias SAGE buffers (deg, agg1, agg2)
  hipMemsetAsync(deg, 0, (size_t)790528 * sizeof(float), stream);
  // ---- AttentionInfo ----
  mgemm_k<0, 0, 0><<<dim3(64, 1), blk, 0, stream>>>(het0, wat_h, wat_l, nullptr, satt + 0 * 262144, 4096, 128, 128, 64);
  mgemm_k<0, 0, 0><<<dim3(64, 1), blk, 0, stream>>>(het1, wat_h, wat_l, nullptr, satt + 1 * 262144, 4096, 128, 128, 64);
  mgemm_k<0, 0, 0><<<dim3(64, 1), blk, 0, stream>>>(het2, wat_h, wat_l, nullptr, satt + 2 * 262144, 4096, 128, 128, 64);
  mgemm_k<0, 0, 0><<<dim3(64, 1), blk, 0, stream>>>(x_t,  wat_h, wat_l, nullptr, satt + 3 * 262144, 4096, 128, 128, 64);
  attred_k<<<dim3(32, 4), blk, 0, stream>>>(satt, atts, scp);
  alpha_k<<<dim3(1), dim3(64), 0, stream>>>(scp, alp);
  xatt_k<<<dim3(2048), blk, 0, stream>>>(het0, het1, het2, x_t, alp, (float*)d_out + 262144);
  // ---- GraphSAGE ----
  const int E = 131072;
  const int* esrc = ei;
  const int* edst = ei + E;
  scatter_deg_k<<<dim3(512), blk, 0, stream>>>(edst, deg, E);
  scatter_add_k<<<dim3(65536), blk, 0, stream>>>(h_a, esrc, edst, agg1, E, 128, 7);
  aggnorm_k<<<dim3(2048), blk, 0, stream>>>(agg1, deg);
  mgemm_k<1, 0, 0><<<dim3(64, 4), blk, 0, stream>>>(agg1, w1l_h, w1l_l, b1, h1, 4096, 128, 128, 256);
  mgemm_k<0, 1, 1><<<dim3(64, 4), blk, 0, stream>>>(h_a, w1r_h, w1r_l, nullptr, h1, 4096, 128, 128, 256);
  mgemm_k<0, 0, 0><<<dim3(64, 1), blk, 0, stream>>>(h1, w2l_h, w2l_l, nullptr, p2, 4096, 256, 256, 64);
  scatter_add_k<<<dim3(32768), blk, 0, stream>>>(p2, esrc, edst, agg2, E, 64, 6);
  mgemm_k<1, 0, 0><<<dim3(64, 1), blk, 0, stream>>>(h1, w2r_h, w2r_l, b2, (float*)d_out, 4096, 256, 256, 64);
  finaladd_k<<<dim3(1024), blk, 0, stream>>>((float*)d_out, agg2, deg);
}